// Round 6
// baseline (349.228 us; speedup 1.0000x reference)
//
#include <hip/hip_runtime.h>
#include <math.h>

#define NN 65536
#define HH 128
#define DHH 16
#define NE 1048576
#define HID 256
#define LNEPS 1e-5f

typedef __attribute__((ext_vector_type(8))) short bf16x8;
typedef __attribute__((ext_vector_type(8))) unsigned short u16x8;
typedef __attribute__((ext_vector_type(4))) float f32x4;

static __device__ __forceinline__ unsigned short f2bf(float f) {
    union { float f; unsigned u; } c; c.f = f;
    unsigned r = c.u + 0x7fffu + ((c.u >> 16) & 1u);
    return (unsigned short)(r >> 16);
}
static __device__ __forceinline__ float bf2f(unsigned short u) {
    union { unsigned u; float f; } c; c.u = ((unsigned)u) << 16;
    return c.f;
}
static __device__ __forceinline__ float gelu_tanh(float x) {
    const float c = 0.7978845608028654f;
    return 0.5f * x * (1.f + tanhf(c * (x + 0.044715f * x * x * x)));
}

// ---------------- CSR build ----------------
__global__ __launch_bounds__(256) void k_count(const int* __restrict__ er, int* __restrict__ cnt) {
    int e = blockIdx.x * 256 + threadIdx.x;
    atomicAdd(&cnt[er[e]], 1);
}

__global__ __launch_bounds__(256) void k_scan1(const int* __restrict__ cnt, int* __restrict__ bsum) {
    const int t = threadIdx.x;
    int v = cnt[blockIdx.x * 256 + t];
#pragma unroll
    for (int d = 1; d < 64; d <<= 1) v += __shfl_xor(v, d);
    __shared__ int ws[4];
    if ((t & 63) == 0) ws[t >> 6] = v;
    __syncthreads();
    if (t == 0) bsum[blockIdx.x] = ws[0] + ws[1] + ws[2] + ws[3];
}

__global__ __launch_bounds__(256) void k_scan2(const int* __restrict__ cnt, const int* __restrict__ bsum,
                                               int* __restrict__ offs, int* __restrict__ cursor) {
    const int b = blockIdx.x, t = threadIdx.x;
    __shared__ int pref[256];
    __shared__ int sc2[256];
    __shared__ int base_s;
    pref[t] = bsum[t];
    __syncthreads();
    for (int d = 1; d < 256; d <<= 1) {
        int vv = (t >= d) ? pref[t - d] : 0;
        __syncthreads();
        pref[t] += vv;
        __syncthreads();
    }
    if (t == 0) base_s = (b == 0) ? 0 : pref[b - 1];
    __syncthreads();
    const int v = cnt[b * 256 + t];
    sc2[t] = v;
    __syncthreads();
    for (int d = 1; d < 256; d <<= 1) {
        int vv = (t >= d) ? sc2[t - d] : 0;
        __syncthreads();
        sc2[t] += vv;
        __syncthreads();
    }
    const int excl = base_s + sc2[t] - v;
    offs[b * 256 + t] = excl;
    cursor[b * 256 + t] = excl;
    if (b == 255 && t == 255) offs[NN] = base_s + sc2[255];
}

__global__ __launch_bounds__(256) void k_scatter(const int* __restrict__ er, const int* __restrict__ ec,
                                                 int* __restrict__ cursor, int* __restrict__ csr_col) {
    int e = blockIdx.x * 256 + threadIdx.x;
    int r = er[e];
    int p = atomicAdd(&cursor[r], 1);
    csr_col[p] = ec[e];
}

// ---------------- weight pack: fp32 W[K][N] -> bf16 Wp[(k>>3)*N + n][8] ----------------
__global__ __launch_bounds__(256) void k_pack(
    const float* __restrict__ wq, const float* __restrict__ wk, const float* __restrict__ wv,
    const float* __restrict__ wo, const float* __restrict__ w1, const float* __restrict__ w2,
    unsigned short* __restrict__ p) {
    const int b = blockIdx.x, t = threadIdx.x;
    const float* src; unsigned short* dst; int N, idx;
    if (b < 64)       { src = wq; dst = p;          N = 128; idx = b * 256 + t; }
    else if (b < 128) { src = wk; dst = p + 16384;  N = 128; idx = (b - 64) * 256 + t; }
    else if (b < 192) { src = wv; dst = p + 32768;  N = 128; idx = (b - 128) * 256 + t; }
    else if (b < 256) { src = wo; dst = p + 49152;  N = 128; idx = (b - 192) * 256 + t; }
    else if (b < 384) { src = w1; dst = p + 65536;  N = 256; idx = (b - 256) * 256 + t; }
    else              { src = w2; dst = p + 98304;  N = 128; idx = (b - 384) * 256 + t; }
    const int k = idx / N, n = idx % N;
    dst[(((k >> 3) * N + n) << 3) + (k & 7)] = f2bf(src[idx]);
}

// ---------------- K1: LN1 + QKV (MFMA bf16, 128 rows/block, wave-private, barrier-free) ----------
// outputs: q -> qb[row][128]; k,v -> kvb[row][h][16k|16v] interleaved (64B per (row,h))
__global__ __launch_bounds__(256) void k_ln_qkv(
    const float* __restrict__ x, const float* __restrict__ g, const float* __restrict__ bl,
    const unsigned short* __restrict__ wqp, const float* __restrict__ bq,
    const unsigned short* __restrict__ wkp, const float* __restrict__ bk,
    const unsigned short* __restrict__ wvp, const float* __restrict__ bv,
    unsigned short* __restrict__ qo, unsigned short* __restrict__ kvb) {
    __shared__ unsigned short aT[128 * 128];  // 32 KB
    const int t = threadIdx.x;
    const int rb = blockIdx.x * 128;
    const int w = t >> 6, l = t & 63;
    // wave-private staging: wave w owns rows w*32 .. w*32+31
    {
        const int sr0 = w * 32 + (l >> 2), qd = l & 3;
#pragma unroll 1
        for (int rr = 0; rr < 2; rr++) {
            const int row = sr0 + rr * 16;
            const float4* xr = reinterpret_cast<const float4*>(x + (size_t)(rb + row) * HH) + qd * 8;
            float xa[32]; float s = 0.f, ss = 0.f;
#pragma unroll
            for (int i = 0; i < 8; i++) {
                float4 v4 = xr[i];
                xa[i * 4 + 0] = v4.x; xa[i * 4 + 1] = v4.y; xa[i * 4 + 2] = v4.z; xa[i * 4 + 3] = v4.w;
                s += v4.x + v4.y + v4.z + v4.w;
                ss += v4.x * v4.x + v4.y * v4.y + v4.z * v4.z + v4.w * v4.w;
            }
            s += __shfl_xor(s, 1); s += __shfl_xor(s, 2);
            ss += __shfl_xor(ss, 1); ss += __shfl_xor(ss, 2);
            const float mu = s * (1.f / HH);
            const float rs = rsqrtf(ss * (1.f / HH) - mu * mu + LNEPS);
#pragma unroll
            for (int c = 0; c < 4; c++) {
                u16x8 w8;
#pragma unroll
                for (int j2 = 0; j2 < 8; j2++) {
                    const int d = qd * 32 + c * 8 + j2;
                    w8[j2] = f2bf((xa[c * 8 + j2] - mu) * rs * g[d] + bl[d]);
                }
                const int uoff = (row * 128 + qd * 32 + c * 8) ^ ((row & 7) << 3);
                *reinterpret_cast<u16x8*>(&aT[uoff]) = w8;
            }
        }
    }
    // no barrier: MFMA below reads only this wave's rows
    const int lr = l & 15, lg = l >> 4;
    const int row0 = w * 32 + lr;
    const int row1 = w * 32 + 16 + lr;
    bf16x8 a0[4], a1[4];
#pragma unroll
    for (int kc = 0; kc < 4; kc++) {
        a0[kc] = *reinterpret_cast<const bf16x8*>(&aT[(row0 * 128 + kc * 32 + lg * 8) ^ ((row0 & 7) << 3)]);
        a1[kc] = *reinterpret_cast<const bf16x8*>(&aT[(row1 * 128 + kc * 32 + lg * 8) ^ ((row1 & 7) << 3)]);
    }

#pragma unroll 1
    for (int m = 0; m < 3; m++) {
        const unsigned short* Wp = (m == 0) ? wqp : (m == 1) ? wkp : wvp;
        const float* Bb = (m == 0) ? bq : (m == 1) ? bk : bv;
        f32x4 ac0[8], ac1[8];
#pragma unroll
        for (int g8 = 0; g8 < 8; g8++) { ac0[g8] = (f32x4){0.f,0.f,0.f,0.f}; ac1[g8] = (f32x4){0.f,0.f,0.f,0.f}; }
#pragma unroll
        for (int g8 = 0; g8 < 8; g8++)
#pragma unroll
            for (int kc = 0; kc < 4; kc++) {
                const bf16x8 bfr = *reinterpret_cast<const bf16x8*>(Wp + ((((kc << 2) + lg) * 128 + g8 * 16 + lr) << 3));
                ac0[g8] = __builtin_amdgcn_mfma_f32_16x16x32_bf16(a0[kc], bfr, ac0[g8], 0, 0, 0);
                ac1[g8] = __builtin_amdgcn_mfma_f32_16x16x32_bf16(a1[kc], bfr, ac1[g8], 0, 0, 0);
            }
#pragma unroll
        for (int g8 = 0; g8 < 8; g8++) {
            const float bias = Bb[g8 * 16 + lr];
#pragma unroll
            for (int j = 0; j < 4; j++) {
                const int ra = rb + w * 32 + 4 * lg + j;
                const int rbb = ra + 16;
                const float y0 = ac0[g8][j] + bias, y1 = ac1[g8][j] + bias;
                if (m == 0) {
                    qo[(size_t)ra * HH + g8 * 16 + lr] = f2bf(y0);
                    qo[(size_t)rbb * HH + g8 * 16 + lr] = f2bf(y1);
                } else {
                    const int off = g8 * 32 + lr + ((m == 2) ? 16 : 0);
                    kvb[(size_t)ra * 256 + off] = f2bf(y0);
                    kvb[(size_t)rbb * 256 + off] = f2bf(y1);
                }
            }
        }
    }
}

// ---------------- K3: fused SDDMM + softmax + SpMM (pipelined bf16 kv gather) ----------------
__global__ __launch_bounds__(256) void k_attn(
    const unsigned short* __restrict__ q, const unsigned short* __restrict__ kv,
    const int* __restrict__ offs, const int* __restrict__ csr_col,
    unsigned short* __restrict__ agg) {
    const int wave = threadIdx.x >> 6;
    const int lane = threadIdx.x & 63;
    const int row = blockIdx.x * 4 + wave;
    const int h = lane & 7, es = lane >> 3;
    const int c0 = offs[row], cnt = offs[row + 1] - c0;

    float qf[16];
    {
        const u16x8* qp = reinterpret_cast<const u16x8*>(q + (size_t)row * HH + h * DHH);
        u16x8 q0 = qp[0], q1 = qp[1];
#pragma unroll
        for (int j = 0; j < 8; j++) { qf[j] = bf2f(q0[j]); qf[8 + j] = bf2f(q1[j]); }
    }
    float m = 0.f, den = 0.f;
    float acc[16] = {};

    // prologue: chunk 0 loads
    bool act = es < cnt;
    int col = act ? csr_col[c0 + es] : 0;
    const u16x8* p0 = reinterpret_cast<const u16x8*>(kv + (size_t)col * 256 + h * 32);
    u16x8 k0 = p0[0], k1 = p0[1], v0 = p0[2], v1 = p0[3];

    for (int base = 0; base < cnt; base += 8) {
        // issue next chunk's loads (unconditional addresses; col 0 when past end)
        const bool nact = (base + 8 + es) < cnt;
        const int ncol = nact ? csr_col[c0 + base + 8 + es] : 0;
        const u16x8* np = reinterpret_cast<const u16x8*>(kv + (size_t)ncol * 256 + h * 32);
        const u16x8 nk0 = np[0], nk1 = np[1], nv0 = np[2], nv1 = np[3];

        // compute current chunk
        float dot = 0.f;
#pragma unroll
        for (int j = 0; j < 8; j++)
            dot += qf[j] * bf2f(k0[j]) + qf[8 + j] * bf2f(k1[j]);
        float sc = act ? dot * 0.25f : -INFINITY;  // 1/sqrt(16)
        float cm = sc;
        cm = fmaxf(cm, __shfl_xor(cm, 8));
        cm = fmaxf(cm, __shfl_xor(cm, 16));
        cm = fmaxf(cm, __shfl_xor(cm, 32));
        if (base == 0) {
            m = cm;
        } else if (!__all(cm <= m + 8.f)) {   // defer-max: rescale ~never
            const float nm = fmaxf(m, cm);
            const float s8 = expf(m - nm);
            den *= s8;
#pragma unroll
            for (int i = 0; i < 16; i++) acc[i] *= s8;
            m = nm;
        }
        const float pp = act ? expf(sc - m) : 0.f;
        den += pp;
#pragma unroll
        for (int j = 0; j < 8; j++) {
            acc[j] += pp * bf2f(v0[j]);
            acc[8 + j] += pp * bf2f(v1[j]);
        }
        act = nact; k0 = nk0; k1 = nk1; v0 = nv0; v1 = nv1;
    }
#pragma unroll
    for (int d = 8; d < 64; d <<= 1) {
        den += __shfl_xor(den, d);
#pragma unroll
        for (int i = 0; i < 16; i++) acc[i] += __shfl_xor(acc[i], d);
    }
    const float inv = 1.f / (den + 1e-9f);
    if (es == 0) {
        unsigned short* ar = agg + (size_t)row * HH + h * DHH;
        u16x8 o0, o1;
#pragma unroll
        for (int j = 0; j < 8; j++) { o0[j] = f2bf(acc[j] * inv); o1[j] = f2bf(acc[8 + j] * inv); }
        reinterpret_cast<u16x8*>(ar)[0] = o0;
        reinterpret_cast<u16x8*>(ar)[1] = o1;
    }
}

// ---------------- K4: fused wo+res+LN2+MLP1+gelu+MLP2+res — wave-private, barrier-light ----------
__global__ __launch_bounds__(256) void k_tail(
    const unsigned short* __restrict__ aggb, const unsigned short* __restrict__ wop,
    const float* __restrict__ bo, const float* __restrict__ x,
    const float* __restrict__ g2, const float* __restrict__ bl2,
    const unsigned short* __restrict__ w1p, const float* __restrict__ b1,
    const unsigned short* __restrict__ w2p, const float* __restrict__ b2,
    float* __restrict__ out) {
    __shared__ unsigned short aT[64 * 128];   // agg tile, then hn tile (wave-private rows)
    __shared__ unsigned short tT[64 * 128];   // half of gelu(mlp1) tile (reused twice)
    const int t = threadIdx.x;
    const int rb = blockIdx.x * 64;
    const int w = t >> 6, l = t & 63;
    const int m0 = w * 16, lr = l & 15, lg = l >> 4;
    const int row = m0 + lr;
    // wave-private staging: wave w stages its own rows m0..m0+15
    {
        const int sr = m0 + (l >> 2), qd = l & 3;
        const u16x8* src = reinterpret_cast<const u16x8*>(aggb + (size_t)(rb + sr) * HH) + qd * 4;
#pragma unroll
        for (int c = 0; c < 4; c++) {
            const int uoff = (sr * 128 + qd * 32 + c * 8) ^ ((sr & 7) << 3);
            *reinterpret_cast<u16x8*>(&aT[uoff]) = src[c];
        }
    }
    // no barrier: all subsequent LDS access is wave-private and per-wave in-order

    // ---- agg @ wo ----
    bf16x8 a[4];
#pragma unroll
    for (int kc = 0; kc < 4; kc++)
        a[kc] = *reinterpret_cast<const bf16x8*>(&aT[(row * 128 + kc * 32 + lg * 8) ^ ((row & 7) << 3)]);
    f32x4 acc[8];
#pragma unroll
    for (int g8 = 0; g8 < 8; g8++) acc[g8] = (f32x4){0.f, 0.f, 0.f, 0.f};
#pragma unroll
    for (int g8 = 0; g8 < 8; g8++)
#pragma unroll
        for (int kc = 0; kc < 4; kc++)
            acc[g8] = __builtin_amdgcn_mfma_f32_16x16x32_bf16(
                a[kc],
                *reinterpret_cast<const bf16x8*>(wop + ((((kc << 2) + lg) * 128 + g8 * 16 + lr) << 3)),
                acc[g8], 0, 0, 0);
    // h = acc + bo + x
    float hv[8][4];
#pragma unroll
    for (int g8 = 0; g8 < 8; g8++) {
        const float bias = bo[g8 * 16 + lr];
#pragma unroll
        for (int j = 0; j < 4; j++)
            hv[g8][j] = acc[g8][j] + bias + x[(size_t)(rb + m0 + 4 * lg + j) * HH + g8 * 16 + lr];
    }
    // ---- LN2 (16-lane group reduce) ----
    float mu[4], rs[4];
#pragma unroll
    for (int j = 0; j < 4; j++) {
        float s = 0.f, ss = 0.f;
#pragma unroll
        for (int g8 = 0; g8 < 8; g8++) { const float hh = hv[g8][j]; s += hh; ss += hh * hh; }
        s += __shfl_xor(s, 1); s += __shfl_xor(s, 2); s += __shfl_xor(s, 4); s += __shfl_xor(s, 8);
        ss += __shfl_xor(ss, 1); ss += __shfl_xor(ss, 2); ss += __shfl_xor(ss, 4); ss += __shfl_xor(ss, 8);
        mu[j] = s * (1.f / HH);
        rs[j] = rsqrtf(ss * (1.f / HH) - mu[j] * mu[j] + LNEPS);
    }
    // hn -> aT (own rows; WAR after own in-order reads)
#pragma unroll
    for (int g8 = 0; g8 < 8; g8++) {
        const float gg = g2[g8 * 16 + lr], bb = bl2[g8 * 16 + lr];
#pragma unroll
        for (int j = 0; j < 4; j++) {
            const int i = m0 + 4 * lg + j;
            aT[(i * 128 + g8 * 16 + lr) ^ ((i & 7) << 3)] = f2bf((hv[g8][j] - mu[j]) * rs[j] * gg + bb);
        }
    }
    bf16x8 a2[4];
#pragma unroll
    for (int kc = 0; kc < 4; kc++)
        a2[kc] = *reinterpret_cast<const bf16x8*>(&aT[(row * 128 + kc * 32 + lg * 8) ^ ((row & 7) << 3)]);

    f32x4 acc2[8];
#pragma unroll
    for (int g8 = 0; g8 < 8; g8++) acc2[g8] = (f32x4){0.f, 0.f, 0.f, 0.f};

    // ---- two K-halves: mlp1 (8 G-tiles) -> tT, then mlp2 partial accumulate ----
#pragma unroll 1
    for (int half = 0; half < 2; half++) {
#pragma unroll 1
        for (int Gl = 0; Gl < 8; Gl++) {
            const int G = half * 8 + Gl;
            f32x4 a1 = (f32x4){0.f, 0.f, 0.f, 0.f};
#pragma unroll
            for (int kc = 0; kc < 4; kc++)
                a1 = __builtin_amdgcn_mfma_f32_16x16x32_bf16(
                    a2[kc],
                    *reinterpret_cast<const bf16x8*>(w1p + ((((kc << 2) + lg) * 256 + G * 16 + lr) << 3)),
                    a1, 0, 0, 0);
            const float bias = b1[G * 16 + lr];
#pragma unroll
            for (int j = 0; j < 4; j++) {
                const int i = m0 + 4 * lg + j;
                tT[(i * 128 + Gl * 16 + lr) ^ ((i & 7) << 3)] = f2bf(gelu_tanh(a1[j] + bias));
            }
        }
        // mlp2 partial: K-chunk = half*128 .. +128  (reads own rows of tT, in-order after writes)
        bf16x8 a3[4];
#pragma unroll
        for (int kc = 0; kc < 4; kc++)
            a3[kc] = *reinterpret_cast<const bf16x8*>(&tT[(row * 128 + kc * 32 + lg * 8) ^ ((row & 7) << 3)]);
#pragma unroll 1
        for (int g8 = 0; g8 < 8; g8++)
#pragma unroll
            for (int kc = 0; kc < 4; kc++)
                acc2[g8] = __builtin_amdgcn_mfma_f32_16x16x32_bf16(
                    a3[kc],
                    *reinterpret_cast<const bf16x8*>(w2p + (((((half << 2) + kc << 2) + lg) * 128 + g8 * 16 + lr) << 3)),
                    acc2[g8], 0, 0, 0);
    }
#pragma unroll
    for (int g8 = 0; g8 < 8; g8++) {
        const float bias = b2[g8 * 16 + lr];
#pragma unroll
        for (int j = 0; j < 4; j++)
            out[(size_t)(rb + m0 + 4 * lg + j) * HH + g8 * 16 + lr] = hv[g8][j] + acc2[g8][j] + bias;
    }
}

extern "C" void kernel_launch(void* const* d_in, const int* in_sizes, int n_in,
                              void* d_out, int out_size, void* d_ws, size_t ws_size,
                              hipStream_t stream) {
    const float* x = (const float*)d_in[0];
    const int* erow = (const int*)d_in[1];
    const int* ecol = (const int*)d_in[2];
    const float* ln1g = (const float*)d_in[3];
    const float* ln1b = (const float*)d_in[4];
    const float* wq = (const float*)d_in[5];
    const float* bq = (const float*)d_in[6];
    const float* wk = (const float*)d_in[7];
    const float* bk = (const float*)d_in[8];
    const float* wv = (const float*)d_in[9];
    const float* bv = (const float*)d_in[10];
    const float* wo = (const float*)d_in[11];
    const float* bo = (const float*)d_in[12];
    const float* ln2g = (const float*)d_in[13];
    const float* ln2b = (const float*)d_in[14];
    const float* w1 = (const float*)d_in[15];
    const float* b1 = (const float*)d_in[16];
    const float* w2 = (const float*)d_in[17];
    const float* b2 = (const float*)d_in[18];
    float* out = (float*)d_out;

    unsigned short* qb = (unsigned short*)d_ws;                 // NN*128
    unsigned short* kvb = qb + (size_t)NN * HH;                 // NN*256 (k|v interleaved)
    unsigned short* aggb = kvb + (size_t)NN * 256;              // NN*128
    unsigned short* wpack = aggb + (size_t)NN * HH;             // 131072 ushorts
    int* cnt = (int*)(wpack + 131072);
    int* offs = cnt + NN;
    int* cursor = offs + NN + 1;
    int* csr_col = cursor + NN;
    int* bsum = csr_col + NE;

    hipMemsetAsync(cnt, 0, NN * sizeof(int), stream);
    k_pack<<<512, 256, 0, stream>>>(wq, wk, wv, wo, w1, w2, wpack);
    k_count<<<NE / 256, 256, 0, stream>>>(erow, cnt);
    k_scan1<<<NN / 256, 256, 0, stream>>>(cnt, bsum);
    k_scan2<<<NN / 256, 256, 0, stream>>>(cnt, bsum, offs, cursor);
    k_scatter<<<NE / 256, 256, 0, stream>>>(erow, ecol, cursor, csr_col);
    k_ln_qkv<<<NN / 128, 256, 0, stream>>>(x, ln1g, ln1b,
                                           wpack, bq, wpack + 16384, bk, wpack + 32768, bv,
                                           qb, kvb);
    k_attn<<<NN / 4, 256, 0, stream>>>(qb, kvb, offs, csr_col, aggb);
    k_tail<<<NN / 64, 256, 0, stream>>>(aggb, wpack + 49152, bo, x, ln2g, ln2b,
                                        wpack + 65536, b1, wpack + 98304, b2, out);
}

// Round 8
// 289.515 us; speedup vs baseline: 1.2063x; 1.2063x over previous
//
#include <hip/hip_runtime.h>
#include <math.h>

#define NN 65536
#define HH 128
#define DHH 16
#define NE 1048576
#define HID 256
#define LNEPS 1e-5f

typedef __attribute__((ext_vector_type(8))) short bf16x8;
typedef __attribute__((ext_vector_type(8))) unsigned short u16x8;
typedef __attribute__((ext_vector_type(4))) float f32x4;

static __device__ __forceinline__ unsigned short f2bf(float f) {
    union { float f; unsigned u; } c; c.f = f;
    unsigned r = c.u + 0x7fffu + ((c.u >> 16) & 1u);
    return (unsigned short)(r >> 16);
}
static __device__ __forceinline__ float bf2f(unsigned short u) {
    union { unsigned u; float f; } c; c.u = ((unsigned)u) << 16;
    return c.f;
}
static __device__ __forceinline__ float gelu_tanh(float x) {
    const float c = 0.7978845608028654f;
    return 0.5f * x * (1.f + tanhf(c * (x + 0.044715f * x * x * x)));
}

// ---------------- CSR build ----------------
__global__ __launch_bounds__(256) void k_count(const int* __restrict__ er, int* __restrict__ cnt) {
    int e = blockIdx.x * 256 + threadIdx.x;
    atomicAdd(&cnt[er[e]], 1);
}

__global__ __launch_bounds__(256) void k_scan1(const int* __restrict__ cnt, int* __restrict__ bsum) {
    const int t = threadIdx.x;
    int v = cnt[blockIdx.x * 256 + t];
#pragma unroll
    for (int d = 1; d < 64; d <<= 1) v += __shfl_xor(v, d);
    __shared__ int ws[4];
    if ((t & 63) == 0) ws[t >> 6] = v;
    __syncthreads();
    if (t == 0) bsum[blockIdx.x] = ws[0] + ws[1] + ws[2] + ws[3];
}

__global__ __launch_bounds__(256) void k_scan2(const int* __restrict__ cnt, const int* __restrict__ bsum,
                                               int* __restrict__ offs, int* __restrict__ cursor) {
    const int b = blockIdx.x, t = threadIdx.x;
    __shared__ int pref[256];
    __shared__ int sc2[256];
    __shared__ int base_s;
    pref[t] = bsum[t];
    __syncthreads();
    for (int d = 1; d < 256; d <<= 1) {
        int vv = (t >= d) ? pref[t - d] : 0;
        __syncthreads();
        pref[t] += vv;
        __syncthreads();
    }
    if (t == 0) base_s = (b == 0) ? 0 : pref[b - 1];
    __syncthreads();
    const int v = cnt[b * 256 + t];
    sc2[t] = v;
    __syncthreads();
    for (int d = 1; d < 256; d <<= 1) {
        int vv = (t >= d) ? sc2[t - d] : 0;
        __syncthreads();
        sc2[t] += vv;
        __syncthreads();
    }
    const int excl = base_s + sc2[t] - v;
    offs[b * 256 + t] = excl;
    cursor[b * 256 + t] = excl;
    if (b == 255 && t == 255) offs[NN] = base_s + sc2[255];
}

__global__ __launch_bounds__(256) void k_scatter(const int* __restrict__ er, const int* __restrict__ ec,
                                                 int* __restrict__ cursor, int* __restrict__ csr_col) {
    int e = blockIdx.x * 256 + threadIdx.x;
    int r = er[e];
    int p = atomicAdd(&cursor[r], 1);
    csr_col[p] = ec[e];
}

// ---------------- weight pack: fp32 W[K][N] -> bf16 Wp[(k>>3)*N + n][8] ----------------
__global__ __launch_bounds__(256) void k_pack(
    const float* __restrict__ wq, const float* __restrict__ wk, const float* __restrict__ wv,
    const float* __restrict__ wo, const float* __restrict__ w1, const float* __restrict__ w2,
    unsigned short* __restrict__ p) {
    const int b = blockIdx.x, t = threadIdx.x;
    const float* src; unsigned short* dst; int N, idx;
    if (b < 64)       { src = wq; dst = p;          N = 128; idx = b * 256 + t; }
    else if (b < 128) { src = wk; dst = p + 16384;  N = 128; idx = (b - 64) * 256 + t; }
    else if (b < 192) { src = wv; dst = p + 32768;  N = 128; idx = (b - 128) * 256 + t; }
    else if (b < 256) { src = wo; dst = p + 49152;  N = 128; idx = (b - 192) * 256 + t; }
    else if (b < 384) { src = w1; dst = p + 65536;  N = 256; idx = (b - 256) * 256 + t; }
    else              { src = w2; dst = p + 98304;  N = 128; idx = (b - 384) * 256 + t; }
    const int k = idx / N, n = idx % N;
    dst[(((k >> 3) * N + n) << 3) + (k & 7)] = f2bf(src[idx]);
}

// ---------------- K1: LN1 + QKV (MFMA bf16, weights staged in LDS) ----------
// outputs: q -> qb[row][128]; k,v -> kvb[row][h][16k|16v] interleaved
__global__ __launch_bounds__(256) void k_ln_qkv(
    const float* __restrict__ x, const float* __restrict__ g, const float* __restrict__ bl,
    const unsigned short* __restrict__ wp /* wq|wk|wv packed, 3*16384 */,
    const float* __restrict__ bq, const float* __restrict__ bk, const float* __restrict__ bv,
    unsigned short* __restrict__ qo, unsigned short* __restrict__ kvb) {
    __shared__ unsigned short aT[128 * 128];  // 32 KB
    __shared__ unsigned short wbuf[16384];    // 32 KB
    const int t = threadIdx.x;
    const int rb = blockIdx.x * 128;
    const int w = t >> 6, l = t & 63;
    // stage LN1(x) tile (wave w owns rows w*32..w*32+31) + stage wq
    {
        const int sr0 = w * 32 + (l >> 2), qd = l & 3;
#pragma unroll 1
        for (int rr = 0; rr < 2; rr++) {
            const int row = sr0 + rr * 16;
            const float4* xr = reinterpret_cast<const float4*>(x + (size_t)(rb + row) * HH) + qd * 8;
            float xa[32]; float s = 0.f, ss = 0.f;
#pragma unroll
            for (int i = 0; i < 8; i++) {
                float4 v4 = xr[i];
                xa[i * 4 + 0] = v4.x; xa[i * 4 + 1] = v4.y; xa[i * 4 + 2] = v4.z; xa[i * 4 + 3] = v4.w;
                s += v4.x + v4.y + v4.z + v4.w;
                ss += v4.x * v4.x + v4.y * v4.y + v4.z * v4.z + v4.w * v4.w;
            }
            s += __shfl_xor(s, 1); s += __shfl_xor(s, 2);
            ss += __shfl_xor(ss, 1); ss += __shfl_xor(ss, 2);
            const float mu = s * (1.f / HH);
            const float rs = rsqrtf(ss * (1.f / HH) - mu * mu + LNEPS);
#pragma unroll
            for (int c = 0; c < 4; c++) {
                u16x8 w8;
#pragma unroll
                for (int j2 = 0; j2 < 8; j2++) {
                    const int d = qd * 32 + c * 8 + j2;
                    w8[j2] = f2bf((xa[c * 8 + j2] - mu) * rs * g[d] + bl[d]);
                }
                const int uoff = (row * 128 + qd * 32 + c * 8) ^ ((row & 7) << 3);
                *reinterpret_cast<u16x8*>(&aT[uoff]) = w8;
            }
        }
#pragma unroll
        for (int i = 0; i < 8; i++) {
            const int off = i * 2048 + t * 8;
            *reinterpret_cast<u16x8*>(&wbuf[off]) = *reinterpret_cast<const u16x8*>(wp + off);
        }
    }
    __syncthreads();
    const int lr = l & 15, lg = l >> 4;
    const int row0 = w * 32 + lr;
    const int row1 = w * 32 + 16 + lr;
    bf16x8 a0[4], a1[4];
#pragma unroll
    for (int kc = 0; kc < 4; kc++) {
        a0[kc] = *reinterpret_cast<const bf16x8*>(&aT[(row0 * 128 + kc * 32 + lg * 8) ^ ((row0 & 7) << 3)]);
        a1[kc] = *reinterpret_cast<const bf16x8*>(&aT[(row1 * 128 + kc * 32 + lg * 8) ^ ((row1 & 7) << 3)]);
    }

#pragma unroll 1
    for (int m = 0; m < 3; m++) {
        const float* Bb = (m == 0) ? bq : (m == 1) ? bk : bv;
        f32x4 ac0[8], ac1[8];
#pragma unroll
        for (int g8 = 0; g8 < 8; g8++) { ac0[g8] = (f32x4){0.f,0.f,0.f,0.f}; ac1[g8] = (f32x4){0.f,0.f,0.f,0.f}; }
#pragma unroll
        for (int g8 = 0; g8 < 8; g8++)
#pragma unroll
            for (int kc = 0; kc < 4; kc++) {
                const bf16x8 bfr = *reinterpret_cast<const bf16x8*>(&wbuf[(((kc << 2) + lg) * 128 + g8 * 16 + lr) << 3]);
                ac0[g8] = __builtin_amdgcn_mfma_f32_16x16x32_bf16(a0[kc], bfr, ac0[g8], 0, 0, 0);
                ac1[g8] = __builtin_amdgcn_mfma_f32_16x16x32_bf16(a1[kc], bfr, ac1[g8], 0, 0, 0);
            }
        // restage next weight while results are written out
        __syncthreads();
        if (m < 2) {
            const unsigned short* nsrc = wp + (m + 1) * 16384;
#pragma unroll
            for (int i = 0; i < 8; i++) {
                const int off = i * 2048 + t * 8;
                *reinterpret_cast<u16x8*>(&wbuf[off]) = *reinterpret_cast<const u16x8*>(nsrc + off);
            }
        }
#pragma unroll
        for (int g8 = 0; g8 < 8; g8++) {
            const float bias = Bb[g8 * 16 + lr];
#pragma unroll
            for (int j = 0; j < 4; j++) {
                const int ra = rb + w * 32 + 4 * lg + j;
                const int rbb = ra + 16;
                const float y0 = ac0[g8][j] + bias, y1 = ac1[g8][j] + bias;
                if (m == 0) {
                    qo[(size_t)ra * HH + g8 * 16 + lr] = f2bf(y0);
                    qo[(size_t)rbb * HH + g8 * 16 + lr] = f2bf(y1);
                } else {
                    const int off = g8 * 32 + lr + ((m == 2) ? 16 : 0);
                    kvb[(size_t)ra * 256 + off] = f2bf(y0);
                    kvb[(size_t)rbb * 256 + off] = f2bf(y1);
                }
            }
        }
        if (m < 2) __syncthreads();
    }
}

// ---------------- K3: fused SDDMM + softmax + SpMM (pipelined bf16 kv gather) ----------------
__global__ __launch_bounds__(256) void k_attn(
    const unsigned short* __restrict__ q, const unsigned short* __restrict__ kv,
    const int* __restrict__ offs, const int* __restrict__ csr_col,
    unsigned short* __restrict__ agg) {
    const int wave = threadIdx.x >> 6;
    const int lane = threadIdx.x & 63;
    const int row = blockIdx.x * 4 + wave;
    const int h = lane & 7, es = lane >> 3;
    const int c0 = offs[row], cnt = offs[row + 1] - c0;

    float qf[16];
    {
        const u16x8* qp = reinterpret_cast<const u16x8*>(q + (size_t)row * HH + h * DHH);
        u16x8 q0 = qp[0], q1 = qp[1];
#pragma unroll
        for (int j = 0; j < 8; j++) { qf[j] = bf2f(q0[j]); qf[8 + j] = bf2f(q1[j]); }
    }
    float m = 0.f, den = 0.f;
    float acc[16] = {};

    bool act = es < cnt;
    int col = act ? csr_col[c0 + es] : 0;
    const u16x8* p0 = reinterpret_cast<const u16x8*>(kv + (size_t)col * 256 + h * 32);
    u16x8 k0 = p0[0], k1 = p0[1], v0 = p0[2], v1 = p0[3];

    for (int base = 0; base < cnt; base += 8) {
        const bool nact = (base + 8 + es) < cnt;
        const int ncol = nact ? csr_col[c0 + base + 8 + es] : 0;
        const u16x8* np = reinterpret_cast<const u16x8*>(kv + (size_t)ncol * 256 + h * 32);
        const u16x8 nk0 = np[0], nk1 = np[1], nv0 = np[2], nv1 = np[3];

        float dot = 0.f;
#pragma unroll
        for (int j = 0; j < 8; j++)
            dot += qf[j] * bf2f(k0[j]) + qf[8 + j] * bf2f(k1[j]);
        float sc = act ? dot * 0.25f : -INFINITY;  // 1/sqrt(16)
        float cm = sc;
        cm = fmaxf(cm, __shfl_xor(cm, 8));
        cm = fmaxf(cm, __shfl_xor(cm, 16));
        cm = fmaxf(cm, __shfl_xor(cm, 32));
        if (base == 0) {
            m = cm;
        } else if (!__all(cm <= m + 8.f)) {   // defer-max: rescale ~never
            const float nm = fmaxf(m, cm);
            const float s8 = expf(m - nm);
            den *= s8;
#pragma unroll
            for (int i = 0; i < 16; i++) acc[i] *= s8;
            m = nm;
        }
        const float pp = act ? expf(sc - m) : 0.f;
        den += pp;
#pragma unroll
        for (int j = 0; j < 8; j++) {
            acc[j] += pp * bf2f(v0[j]);
            acc[8 + j] += pp * bf2f(v1[j]);
        }
        act = nact; k0 = nk0; k1 = nk1; v0 = nv0; v1 = nv1;
    }
#pragma unroll
    for (int d = 8; d < 64; d <<= 1) {
        den += __shfl_xor(den, d);
#pragma unroll
        for (int i = 0; i < 16; i++) acc[i] += __shfl_xor(acc[i], d);
    }
    const float inv = 1.f / (den + 1e-9f);
    if (es == 0) {
        unsigned short* ar = agg + (size_t)row * HH + h * DHH;
        u16x8 o0, o1;
#pragma unroll
        for (int j = 0; j < 8; j++) { o0[j] = f2bf(acc[j] * inv); o1[j] = f2bf(acc[8 + j] * inv); }
        reinterpret_cast<u16x8*>(ar)[0] = o0;
        reinterpret_cast<u16x8*>(ar)[1] = o1;
    }
}

// ---------------- K4: fused wo+res+LN2+MLP1+gelu+MLP2+res — weights staged in LDS ----------
__global__ __launch_bounds__(256) void k_tail(
    const unsigned short* __restrict__ aggb, const unsigned short* __restrict__ wop,
    const float* __restrict__ bo, const float* __restrict__ x,
    const float* __restrict__ g2, const float* __restrict__ bl2,
    const unsigned short* __restrict__ w1p, const float* __restrict__ b1,
    const unsigned short* __restrict__ w2p, const float* __restrict__ b2,
    float* __restrict__ out) {
    __shared__ unsigned short aT[64 * 128];   // 16 KB: agg tile, then hn tile
    __shared__ unsigned short tT[64 * 256];   // 32 KB: gelu(mlp1)
    __shared__ unsigned short wbuf[16384];    // 32 KB: current weight panel
    const int t = threadIdx.x;
    const int rb = blockIdx.x * 64;
    const int w = t >> 6, l = t & 63;
    const int m0 = w * 16, lr = l & 15, lg = l >> 4;
    const int row = m0 + lr;

    // stage agg tile + wo panel
    {
        const int r = t >> 2, qd = t & 3;
        const u16x8* src = reinterpret_cast<const u16x8*>(aggb + (size_t)(rb + r) * HH) + qd * 4;
#pragma unroll
        for (int c = 0; c < 4; c++) {
            const int uoff = (r * 128 + qd * 32 + c * 8) ^ ((r & 7) << 3);
            *reinterpret_cast<u16x8*>(&aT[uoff]) = src[c];
        }
#pragma unroll
        for (int i = 0; i < 8; i++) {
            const int off = i * 2048 + t * 8;
            *reinterpret_cast<u16x8*>(&wbuf[off]) = *reinterpret_cast<const u16x8*>(wop + off);
        }
    }
    __syncthreads();

    // ---- agg @ wo (B from LDS) ----
    bf16x8 a[4];
#pragma unroll
    for (int kc = 0; kc < 4; kc++)
        a[kc] = *reinterpret_cast<const bf16x8*>(&aT[(row * 128 + kc * 32 + lg * 8) ^ ((row & 7) << 3)]);
    f32x4 acc[8];
#pragma unroll
    for (int g8 = 0; g8 < 8; g8++) acc[g8] = (f32x4){0.f, 0.f, 0.f, 0.f};
#pragma unroll
    for (int g8 = 0; g8 < 8; g8++)
#pragma unroll
        for (int kc = 0; kc < 4; kc++)
            acc[g8] = __builtin_amdgcn_mfma_f32_16x16x32_bf16(
                a[kc],
                *reinterpret_cast<const bf16x8*>(&wbuf[(((kc << 2) + lg) * 128 + g8 * 16 + lr) << 3]),
                acc[g8], 0, 0, 0);
    // h = acc + bo + x
    float hv[8][4];
#pragma unroll
    for (int g8 = 0; g8 < 8; g8++) {
        const float bias = bo[g8 * 16 + lr];
#pragma unroll
        for (int j = 0; j < 4; j++)
            hv[g8][j] = acc[g8][j] + bias + x[(size_t)(rb + m0 + 4 * lg + j) * HH + g8 * 16 + lr];
    }
    // ---- LN2 ----
    float mu[4], rs[4];
#pragma unroll
    for (int j = 0; j < 4; j++) {
        float s = 0.f, ss = 0.f;
#pragma unroll
        for (int g8 = 0; g8 < 8; g8++) { const float hh = hv[g8][j]; s += hh; ss += hh * hh; }
        s += __shfl_xor(s, 1); s += __shfl_xor(s, 2); s += __shfl_xor(s, 4); s += __shfl_xor(s, 8);
        ss += __shfl_xor(ss, 1); ss += __shfl_xor(ss, 2); ss += __shfl_xor(ss, 4); ss += __shfl_xor(ss, 8);
        mu[j] = s * (1.f / HH);
        rs[j] = rsqrtf(ss * (1.f / HH) - mu[j] * mu[j] + LNEPS);
    }
    __syncthreads();  // all wbuf(wo)+aT(agg) reads done
    // hn -> aT (own rows) ; stage w1 half 0
#pragma unroll
    for (int g8 = 0; g8 < 8; g8++) {
        const float gg = g2[g8 * 16 + lr], bb = bl2[g8 * 16 + lr];
#pragma unroll
        for (int j = 0; j < 4; j++) {
            const int i = m0 + 4 * lg + j;
            aT[(i * 128 + g8 * 16 + lr) ^ ((i & 7) << 3)] = f2bf((hv[g8][j] - mu[j]) * rs[j] * gg + bb);
        }
    }
#pragma unroll
    for (int i = 0; i < 8; i++) {
        const int off = i * 2048 + t * 8;
        const int k8 = off >> 10, rem = off & 1023;
        *reinterpret_cast<u16x8*>(&wbuf[off]) = *reinterpret_cast<const u16x8*>(w1p + (k8 << 11) + rem);
    }
    __syncthreads();
    bf16x8 a2[4];
#pragma unroll
    for (int kc = 0; kc < 4; kc++)
        a2[kc] = *reinterpret_cast<const bf16x8*>(&aT[(row * 128 + kc * 32 + lg * 8) ^ ((row & 7) << 3)]);

    // ---- mlp1 in two N-halves ----
#pragma unroll 1
    for (int half = 0; half < 2; half++) {
#pragma unroll 1
        for (int Gl = 0; Gl < 8; Gl++) {
            const int G = half * 8 + Gl;
            f32x4 a1 = (f32x4){0.f, 0.f, 0.f, 0.f};
#pragma unroll
            for (int kc = 0; kc < 4; kc++)
                a1 = __builtin_amdgcn_mfma_f32_16x16x32_bf16(
                    a2[kc],
                    *reinterpret_cast<const bf16x8*>(&wbuf[(((kc << 2) + lg) * 128 + Gl * 16 + lr) << 3]),
                    a1, 0, 0, 0);
            const float bias = b1[G * 16 + lr];
#pragma unroll
            for (int j = 0; j < 4; j++) {
                const int i = m0 + 4 * lg + j;
                tT[(i * 256 + G * 16 + lr) ^ ((i & 7) << 3)] = f2bf(gelu_tanh(a1[j] + bias));
            }
        }
        __syncthreads();  // wbuf reads done
        if (half == 0) {
#pragma unroll
            for (int i = 0; i < 8; i++) {
                const int off = i * 2048 + t * 8;
                const int k8 = off >> 10, rem = off & 1023;
                *reinterpret_cast<u16x8*>(&wbuf[off]) = *reinterpret_cast<const u16x8*>(w1p + (k8 << 11) + 1024 + rem);
            }
        } else {
#pragma unroll
            for (int i = 0; i < 8; i++) {
                const int off = i * 2048 + t * 8;
                *reinterpret_cast<u16x8*>(&wbuf[off]) = *reinterpret_cast<const u16x8*>(w2p + off);
            }
        }
        __syncthreads();
    }
    // ---- mlp2 in two K-halves (w2 panel staged per half) ----
    f32x4 acc2[8];
#pragma unroll
    for (int g8 = 0; g8 < 8; g8++) acc2[g8] = (f32x4){0.f, 0.f, 0.f, 0.f};
#pragma unroll 1
    for (int half = 0; half < 2; half++) {
        bf16x8 a3[4];
#pragma unroll
        for (int kc = 0; kc < 4; kc++)
            a3[kc] = *reinterpret_cast<const bf16x8*>(&tT[(row * 256 + half * 128 + kc * 32 + lg * 8) ^ ((row & 7) << 3)]);
#pragma unroll 1
        for (int g8 = 0; g8 < 8; g8++)
#pragma unroll
            for (int kc = 0; kc < 4; kc++)
                acc2[g8] = __builtin_amdgcn_mfma_f32_16x16x32_bf16(
                    a3[kc],
                    *reinterpret_cast<const bf16x8*>(&wbuf[(((kc << 2) + lg) * 128 + g8 * 16 + lr) << 3]),
                    acc2[g8], 0, 0, 0);
        if (half == 0) {
            __syncthreads();
#pragma unroll
            for (int i = 0; i < 8; i++) {
                const int off = i * 2048 + t * 8;
                *reinterpret_cast<u16x8*>(&wbuf[off]) = *reinterpret_cast<const u16x8*>(w2p + 16384 + off);
            }
            __syncthreads();
        }
    }
#pragma unroll
    for (int g8 = 0; g8 < 8; g8++) {
        const float bias = b2[g8 * 16 + lr];
#pragma unroll
        for (int j = 0; j < 4; j++)
            out[(size_t)(rb + m0 + 4 * lg + j) * HH + g8 * 16 + lr] = hv[g8][j] + acc2[g8][j] + bias;
    }
}

extern "C" void kernel_launch(void* const* d_in, const int* in_sizes, int n_in,
                              void* d_out, int out_size, void* d_ws, size_t ws_size,
                              hipStream_t stream) {
    const float* x = (const float*)d_in[0];
    const int* erow = (const int*)d_in[1];
    const int* ecol = (const int*)d_in[2];
    const float* ln1g = (const float*)d_in[3];
    const float* ln1b = (const float*)d_in[4];
    const float* wq = (const float*)d_in[5];
    const float* bq = (const float*)d_in[6];
    const float* wk = (const float*)d_in[7];
    const float* bk = (const float*)d_in[8];
    const float* wv = (const float*)d_in[9];
    const float* bv = (const float*)d_in[10];
    const float* wo = (const float*)d_in[11];
    const float* bo = (const float*)d_in[12];
    const float* ln2g = (const float*)d_in[13];
    const float* ln2b = (const float*)d_in[14];
    const float* w1 = (const float*)d_in[15];
    const float* b1 = (const float*)d_in[16];
    const float* w2 = (const float*)d_in[17];
    const float* b2 = (const float*)d_in[18];
    float* out = (float*)d_out;

    unsigned short* qb = (unsigned short*)d_ws;                 // NN*128
    unsigned short* kvb = qb + (size_t)NN * HH;                 // NN*256 (k|v interleaved)
    unsigned short* aggb = kvb + (size_t)NN * 256;              // NN*128
    unsigned short* wpack = aggb + (size_t)NN * HH;             // 131072 ushorts
    int* cnt = (int*)(wpack + 131072);
    int* offs = cnt + NN;
    int* cursor = offs + NN + 1;
    int* csr_col = cursor + NN;
    int* bsum = csr_col + NE;

    hipMemsetAsync(cnt, 0, NN * sizeof(int), stream);
    k_pack<<<512, 256, 0, stream>>>(wq, wk, wv, wo, w1, w2, wpack);
    k_count<<<NE / 256, 256, 0, stream>>>(erow, cnt);
    k_scan1<<<NN / 256, 256, 0, stream>>>(cnt, bsum);
    k_scan2<<<NN / 256, 256, 0, stream>>>(cnt, bsum, offs, cursor);
    k_scatter<<<NE / 256, 256, 0, stream>>>(erow, ecol, cursor, csr_col);
    k_ln_qkv<<<NN / 128, 256, 0, stream>>>(x, ln1g, ln1b, wpack, bq, bk, bv, qb, kvb);
    k_attn<<<NN / 4, 256, 0, stream>>>(qb, kvb, offs, csr_col, aggb);
    k_tail<<<NN / 64, 256, 0, stream>>>(aggb, wpack + 49152, bo, x, ln2g, ln2b,
                                        wpack + 65536, b1, wpack + 98304, b2, out);
}

// Round 10
// 260.023 us; speedup vs baseline: 1.3431x; 1.1134x over previous
//
#include <hip/hip_runtime.h>
#include <math.h>

#define NN 65536
#define HH 128
#define DHH 16
#define NE 1048576
#define HID 256
#define LNEPS 1e-5f

typedef __attribute__((ext_vector_type(8))) short bf16x8;
typedef __attribute__((ext_vector_type(8))) unsigned short u16x8;
typedef __attribute__((ext_vector_type(4))) float f32x4;
typedef __attribute__((ext_vector_type(2))) float f32x2;

static __device__ __forceinline__ unsigned short f2bf(float f) {
    union { float f; unsigned u; } c; c.f = f;
    unsigned r = c.u + 0x7fffu + ((c.u >> 16) & 1u);
    return (unsigned short)(r >> 16);
}
static __device__ __forceinline__ float bf2f(unsigned short u) {
    union { unsigned u; float f; } c; c.u = ((unsigned)u) << 16;
    return c.f;
}
static __device__ __forceinline__ float gelu_tanh(float x) {
    const float c = 0.7978845608028654f;
    return 0.5f * x * (1.f + tanhf(c * (x + 0.044715f * x * x * x)));
}

// ---------------- CSR build ----------------
__global__ __launch_bounds__(256) void k_count(const int* __restrict__ er, int* __restrict__ cnt) {
    int e = blockIdx.x * 256 + threadIdx.x;
    atomicAdd(&cnt[er[e]], 1);
}

__global__ __launch_bounds__(256) void k_scan1(const int* __restrict__ cnt, int* __restrict__ bsum) {
    const int t = threadIdx.x;
    int v = cnt[blockIdx.x * 256 + t];
#pragma unroll
    for (int d = 1; d < 64; d <<= 1) v += __shfl_xor(v, d);
    __shared__ int ws[4];
    if ((t & 63) == 0) ws[t >> 6] = v;
    __syncthreads();
    if (t == 0) bsum[blockIdx.x] = ws[0] + ws[1] + ws[2] + ws[3];
}

__global__ __launch_bounds__(256) void k_scan2(const int* __restrict__ cnt, const int* __restrict__ bsum,
                                               int* __restrict__ offs, int* __restrict__ cursor) {
    const int b = blockIdx.x, t = threadIdx.x;
    __shared__ int pref[256];
    __shared__ int sc2[256];
    __shared__ int base_s;
    pref[t] = bsum[t];
    __syncthreads();
    for (int d = 1; d < 256; d <<= 1) {
        int vv = (t >= d) ? pref[t - d] : 0;
        __syncthreads();
        pref[t] += vv;
        __syncthreads();
    }
    if (t == 0) base_s = (b == 0) ? 0 : pref[b - 1];
    __syncthreads();
    const int v = cnt[b * 256 + t];
    sc2[t] = v;
    __syncthreads();
    for (int d = 1; d < 256; d <<= 1) {
        int vv = (t >= d) ? sc2[t - d] : 0;
        __syncthreads();
        sc2[t] += vv;
        __syncthreads();
    }
    const int excl = base_s + sc2[t] - v;
    offs[b * 256 + t] = excl;
    cursor[b * 256 + t] = excl;
    if (b == 255 && t == 255) offs[NN] = base_s + sc2[255];
}

__global__ __launch_bounds__(256) void k_scatter(const int* __restrict__ er, const int* __restrict__ ec,
                                                 int* __restrict__ cursor, int* __restrict__ csr_col) {
    int e = blockIdx.x * 256 + threadIdx.x;
    int r = er[e];
    int p = atomicAdd(&cursor[r], 1);
    csr_col[p] = ec[e];
}

// ---------------- weight pack: fp32 W[K][N] -> bf16 Wp[(k>>3)*N + n][8] ----------------
__global__ __launch_bounds__(256) void k_pack(
    const float* __restrict__ wq, const float* __restrict__ wk, const float* __restrict__ wv,
    const float* __restrict__ wo, const float* __restrict__ w1, const float* __restrict__ w2,
    unsigned short* __restrict__ p) {
    const int b = blockIdx.x, t = threadIdx.x;
    const float* src; unsigned short* dst; int N, idx;
    if (b < 64)       { src = wq; dst = p;          N = 128; idx = b * 256 + t; }
    else if (b < 128) { src = wk; dst = p + 16384;  N = 128; idx = (b - 64) * 256 + t; }
    else if (b < 192) { src = wv; dst = p + 32768;  N = 128; idx = (b - 128) * 256 + t; }
    else if (b < 256) { src = wo; dst = p + 49152;  N = 128; idx = (b - 192) * 256 + t; }
    else if (b < 384) { src = w1; dst = p + 65536;  N = 256; idx = (b - 256) * 256 + t; }
    else              { src = w2; dst = p + 98304;  N = 128; idx = (b - 384) * 256 + t; }
    const int k = idx / N, n = idx % N;
    dst[(((k >> 3) * N + n) << 3) + (k & 7)] = f2bf(src[idx]);
}

// ---------------- K1: LN1 + QKV (MFMA bf16, weights staged in LDS) ----------
// outputs: q -> qb[row][128] bf16; k,v -> kv8[row][h][16k|16v] fp8 e4m3 (32 B per (row,h))
__global__ __launch_bounds__(256) void k_ln_qkv(
    const float* __restrict__ x, const float* __restrict__ g, const float* __restrict__ bl,
    const unsigned short* __restrict__ wp /* wq|wk|wv packed, 3*16384 */,
    const float* __restrict__ bq, const float* __restrict__ bk, const float* __restrict__ bv,
    unsigned short* __restrict__ qo, unsigned char* __restrict__ kv8) {
    __shared__ unsigned short aT[128 * 128];  // 32 KB
    __shared__ unsigned short wbuf[16384];    // 32 KB
    const int t = threadIdx.x;
    const int rb = blockIdx.x * 128;
    const int w = t >> 6, l = t & 63;
    // stage LN1(x) tile (wave w owns rows w*32..w*32+31) + stage wq
    {
        const int sr0 = w * 32 + (l >> 2), qd = l & 3;
#pragma unroll 1
        for (int rr = 0; rr < 2; rr++) {
            const int row = sr0 + rr * 16;
            const float4* xr = reinterpret_cast<const float4*>(x + (size_t)(rb + row) * HH) + qd * 8;
            float xa[32]; float s = 0.f, ss = 0.f;
#pragma unroll
            for (int i = 0; i < 8; i++) {
                float4 v4 = xr[i];
                xa[i * 4 + 0] = v4.x; xa[i * 4 + 1] = v4.y; xa[i * 4 + 2] = v4.z; xa[i * 4 + 3] = v4.w;
                s += v4.x + v4.y + v4.z + v4.w;
                ss += v4.x * v4.x + v4.y * v4.y + v4.z * v4.z + v4.w * v4.w;
            }
            s += __shfl_xor(s, 1); s += __shfl_xor(s, 2);
            ss += __shfl_xor(ss, 1); ss += __shfl_xor(ss, 2);
            const float mu = s * (1.f / HH);
            const float rs = rsqrtf(ss * (1.f / HH) - mu * mu + LNEPS);
#pragma unroll
            for (int c = 0; c < 4; c++) {
                u16x8 w8;
#pragma unroll
                for (int j2 = 0; j2 < 8; j2++) {
                    const int d = qd * 32 + c * 8 + j2;
                    w8[j2] = f2bf((xa[c * 8 + j2] - mu) * rs * g[d] + bl[d]);
                }
                const int uoff = (row * 128 + qd * 32 + c * 8) ^ ((row & 7) << 3);
                *reinterpret_cast<u16x8*>(&aT[uoff]) = w8;
            }
        }
#pragma unroll
        for (int i = 0; i < 8; i++) {
            const int off = i * 2048 + t * 8;
            *reinterpret_cast<u16x8*>(&wbuf[off]) = *reinterpret_cast<const u16x8*>(wp + off);
        }
    }
    __syncthreads();
    const int lr = l & 15, lg = l >> 4;
    const int row0 = w * 32 + lr;
    const int row1 = w * 32 + 16 + lr;
    bf16x8 a0[4], a1[4];
#pragma unroll
    for (int kc = 0; kc < 4; kc++) {
        a0[kc] = *reinterpret_cast<const bf16x8*>(&aT[(row0 * 128 + kc * 32 + lg * 8) ^ ((row0 & 7) << 3)]);
        a1[kc] = *reinterpret_cast<const bf16x8*>(&aT[(row1 * 128 + kc * 32 + lg * 8) ^ ((row1 & 7) << 3)]);
    }

#pragma unroll 1
    for (int m = 0; m < 3; m++) {
        const float* Bb = (m == 0) ? bq : (m == 1) ? bk : bv;
        f32x4 ac0[8], ac1[8];
#pragma unroll
        for (int g8 = 0; g8 < 8; g8++) { ac0[g8] = (f32x4){0.f,0.f,0.f,0.f}; ac1[g8] = (f32x4){0.f,0.f,0.f,0.f}; }
#pragma unroll
        for (int g8 = 0; g8 < 8; g8++)
#pragma unroll
            for (int kc = 0; kc < 4; kc++) {
                const bf16x8 bfr = *reinterpret_cast<const bf16x8*>(&wbuf[(((kc << 2) + lg) * 128 + g8 * 16 + lr) << 3]);
                ac0[g8] = __builtin_amdgcn_mfma_f32_16x16x32_bf16(a0[kc], bfr, ac0[g8], 0, 0, 0);
                ac1[g8] = __builtin_amdgcn_mfma_f32_16x16x32_bf16(a1[kc], bfr, ac1[g8], 0, 0, 0);
            }
        // restage next weight while results are written out
        __syncthreads();
        if (m < 2) {
            const unsigned short* nsrc = wp + (m + 1) * 16384;
#pragma unroll
            for (int i = 0; i < 8; i++) {
                const int off = i * 2048 + t * 8;
                *reinterpret_cast<u16x8*>(&wbuf[off]) = *reinterpret_cast<const u16x8*>(nsrc + off);
            }
        }
#pragma unroll
        for (int g8 = 0; g8 < 8; g8++) {
            const float bias = Bb[g8 * 16 + lr];
#pragma unroll
            for (int j = 0; j < 4; j++) {
                const int ra = rb + w * 32 + 4 * lg + j;
                const int rbb = ra + 16;
                const float y0 = ac0[g8][j] + bias, y1 = ac1[g8][j] + bias;
                if (m == 0) {
                    qo[(size_t)ra * HH + g8 * 16 + lr] = f2bf(y0);
                    qo[(size_t)rbb * HH + g8 * 16 + lr] = f2bf(y1);
                } else {
                    const int off = g8 * 32 + lr + ((m == 2) ? 16 : 0);
                    const int pk0 = __builtin_amdgcn_cvt_pk_fp8_f32(y0, y0, 0, false);
                    const int pk1 = __builtin_amdgcn_cvt_pk_fp8_f32(y1, y1, 0, false);
                    kv8[(size_t)ra * 256 + off] = (unsigned char)(pk0 & 0xff);
                    kv8[(size_t)rbb * 256 + off] = (unsigned char)(pk1 & 0xff);
                }
            }
        }
        if (m < 2) __syncthreads();
    }
}

// ---------------- K3: fused SDDMM + softmax + SpMM (fp8 kv gather, 2-deep pipeline) ----------------
__global__ __launch_bounds__(256) void k_attn(
    const unsigned short* __restrict__ q, const unsigned char* __restrict__ kv,
    const int* __restrict__ offs, const int* __restrict__ csr_col,
    unsigned short* __restrict__ agg) {
    const int wave = threadIdx.x >> 6;
    const int lane = threadIdx.x & 63;
    const int row = blockIdx.x * 4 + wave;
    const int h = lane & 7, es = lane >> 3;
    const int c0 = offs[row], cnt = offs[row + 1] - c0;

    float qf[16];
    {
        const u16x8* qp = reinterpret_cast<const u16x8*>(q + (size_t)row * HH + h * DHH);
        u16x8 q0 = qp[0], q1 = qp[1];
#pragma unroll
        for (int j = 0; j < 8; j++) { qf[j] = bf2f(q0[j]); qf[8 + j] = bf2f(q1[j]); }
    }
    float m = 0.f, den = 0.f;
    float acc[16] = {};

    // 2-deep prologue: col for chunk0 and chunk1; kv loads for chunk0 in flight
    bool act0 = es < cnt;
    int col0 = act0 ? csr_col[c0 + es] : 0;
    bool act1 = (8 + es) < cnt;
    int col1 = act1 ? csr_col[c0 + 8 + es] : 0;
    const int4* p0 = reinterpret_cast<const int4*>(kv + (size_t)col0 * 256 + h * 32);
    int4 kd = p0[0], vd = p0[1];

    for (int base = 0; base < cnt; base += 8) {
        // issue next chunk's kv loads (col already resident) + col two ahead
        const int4* p1 = reinterpret_cast<const int4*>(kv + (size_t)col1 * 256 + h * 32);
        const int4 nkd = p1[0], nvd = p1[1];
        const bool act2 = (base + 16 + es) < cnt;
        const int col2 = act2 ? csr_col[c0 + base + 16 + es] : 0;

        // convert k fp8 -> f32 and dot
        float kf[16];
        {
            f32x2 r;
            r = __builtin_amdgcn_cvt_pk_f32_fp8(kd.x, false); kf[0] = r[0]; kf[1] = r[1];
            r = __builtin_amdgcn_cvt_pk_f32_fp8(kd.x, true);  kf[2] = r[0]; kf[3] = r[1];
            r = __builtin_amdgcn_cvt_pk_f32_fp8(kd.y, false); kf[4] = r[0]; kf[5] = r[1];
            r = __builtin_amdgcn_cvt_pk_f32_fp8(kd.y, true);  kf[6] = r[0]; kf[7] = r[1];
            r = __builtin_amdgcn_cvt_pk_f32_fp8(kd.z, false); kf[8] = r[0]; kf[9] = r[1];
            r = __builtin_amdgcn_cvt_pk_f32_fp8(kd.z, true);  kf[10] = r[0]; kf[11] = r[1];
            r = __builtin_amdgcn_cvt_pk_f32_fp8(kd.w, false); kf[12] = r[0]; kf[13] = r[1];
            r = __builtin_amdgcn_cvt_pk_f32_fp8(kd.w, true);  kf[14] = r[0]; kf[15] = r[1];
        }
        float dot = 0.f;
#pragma unroll
        for (int j = 0; j < 16; j++) dot += qf[j] * kf[j];
        float sc = act0 ? dot * 0.25f : -INFINITY;  // 1/sqrt(16)
        float cm = sc;
        cm = fmaxf(cm, __shfl_xor(cm, 8));
        cm = fmaxf(cm, __shfl_xor(cm, 16));
        cm = fmaxf(cm, __shfl_xor(cm, 32));
        if (base == 0) {
            m = cm;
        } else if (!__all(cm <= m + 8.f)) {   // defer-max: rescale ~never
            const float nm = fmaxf(m, cm);
            const float s8 = expf(m - nm);
            den *= s8;
#pragma unroll
            for (int i = 0; i < 16; i++) acc[i] *= s8;
            m = nm;
        }
        const float pp = act0 ? expf(sc - m) : 0.f;
        den += pp;
        {
            f32x2 r;
            r = __builtin_amdgcn_cvt_pk_f32_fp8(vd.x, false); acc[0] += pp * r[0]; acc[1] += pp * r[1];
            r = __builtin_amdgcn_cvt_pk_f32_fp8(vd.x, true);  acc[2] += pp * r[0]; acc[3] += pp * r[1];
            r = __builtin_amdgcn_cvt_pk_f32_fp8(vd.y, false); acc[4] += pp * r[0]; acc[5] += pp * r[1];
            r = __builtin_amdgcn_cvt_pk_f32_fp8(vd.y, true);  acc[6] += pp * r[0]; acc[7] += pp * r[1];
            r = __builtin_amdgcn_cvt_pk_f32_fp8(vd.z, false); acc[8] += pp * r[0]; acc[9] += pp * r[1];
            r = __builtin_amdgcn_cvt_pk_f32_fp8(vd.z, true);  acc[10] += pp * r[0]; acc[11] += pp * r[1];
            r = __builtin_amdgcn_cvt_pk_f32_fp8(vd.w, false); acc[12] += pp * r[0]; acc[13] += pp * r[1];
            r = __builtin_amdgcn_cvt_pk_f32_fp8(vd.w, true);  acc[14] += pp * r[0]; acc[15] += pp * r[1];
        }
        act0 = act1; act1 = act2; col1 = col2; kd = nkd; vd = nvd;
    }
#pragma unroll
    for (int d = 8; d < 64; d <<= 1) {
        den += __shfl_xor(den, d);
#pragma unroll
        for (int i = 0; i < 16; i++) acc[i] += __shfl_xor(acc[i], d);
    }
    const float inv = 1.f / (den + 1e-9f);
    if (es == 0) {
        unsigned short* ar = agg + (size_t)row * HH + h * DHH;
        u16x8 o0, o1;
#pragma unroll
        for (int j = 0; j < 8; j++) { o0[j] = f2bf(acc[j] * inv); o1[j] = f2bf(acc[8 + j] * inv); }
        reinterpret_cast<u16x8*>(ar)[0] = o0;
        reinterpret_cast<u16x8*>(ar)[1] = o1;
    }
}

// ---------------- K4: fused wo+res+LN2+MLP1+gelu+MLP2+res — weights staged in LDS ----------
__global__ __launch_bounds__(256) void k_tail(
    const unsigned short* __restrict__ aggb, const unsigned short* __restrict__ wop,
    const float* __restrict__ bo, const float* __restrict__ x,
    const float* __restrict__ g2, const float* __restrict__ bl2,
    const unsigned short* __restrict__ w1p, const float* __restrict__ b1,
    const unsigned short* __restrict__ w2p, const float* __restrict__ b2,
    float* __restrict__ out) {
    __shared__ unsigned short aT[64 * 128];   // 16 KB: agg tile, then hn tile
    __shared__ unsigned short tT[64 * 256];   // 32 KB: gelu(mlp1)
    __shared__ unsigned short wbuf[16384];    // 32 KB: current weight panel
    const int t = threadIdx.x;
    const int rb = blockIdx.x * 64;
    const int w = t >> 6, l = t & 63;
    const int m0 = w * 16, lr = l & 15, lg = l >> 4;
    const int row = m0 + lr;

    // stage agg tile + wo panel
    {
        const int r = t >> 2, qd = t & 3;
        const u16x8* src = reinterpret_cast<const u16x8*>(aggb + (size_t)(rb + r) * HH) + qd * 4;
#pragma unroll
        for (int c = 0; c < 4; c++) {
            const int uoff = (r * 128 + qd * 32 + c * 8) ^ ((r & 7) << 3);
            *reinterpret_cast<u16x8*>(&aT[uoff]) = src[c];
        }
#pragma unroll
        for (int i = 0; i < 8; i++) {
            const int off = i * 2048 + t * 8;
            *reinterpret_cast<u16x8*>(&wbuf[off]) = *reinterpret_cast<const u16x8*>(wop + off);
        }
    }
    __syncthreads();

    // ---- agg @ wo (B from LDS) ----
    bf16x8 a[4];
#pragma unroll
    for (int kc = 0; kc < 4; kc++)
        a[kc] = *reinterpret_cast<const bf16x8*>(&aT[(row * 128 + kc * 32 + lg * 8) ^ ((row & 7) << 3)]);
    f32x4 acc[8];
#pragma unroll
    for (int g8 = 0; g8 < 8; g8++) acc[g8] = (f32x4){0.f, 0.f, 0.f, 0.f};
#pragma unroll
    for (int g8 = 0; g8 < 8; g8++)
#pragma unroll
        for (int kc = 0; kc < 4; kc++)
            acc[g8] = __builtin_amdgcn_mfma_f32_16x16x32_bf16(
                a[kc],
                *reinterpret_cast<const bf16x8*>(&wbuf[(((kc << 2) + lg) * 128 + g8 * 16 + lr) << 3]),
                acc[g8], 0, 0, 0);
    // h = acc + bo + x
    float hv[8][4];
#pragma unroll
    for (int g8 = 0; g8 < 8; g8++) {
        const float bias = bo[g8 * 16 + lr];
#pragma unroll
        for (int j = 0; j < 4; j++)
            hv[g8][j] = acc[g8][j] + bias + x[(size_t)(rb + m0 + 4 * lg + j) * HH + g8 * 16 + lr];
    }
    // ---- LN2 ----
    float mu[4], rs[4];
#pragma unroll
    for (int j = 0; j < 4; j++) {
        float s = 0.f, ss = 0.f;
#pragma unroll
        for (int g8 = 0; g8 < 8; g8++) { const float hh = hv[g8][j]; s += hh; ss += hh * hh; }
        s += __shfl_xor(s, 1); s += __shfl_xor(s, 2); s += __shfl_xor(s, 4); s += __shfl_xor(s, 8);
        ss += __shfl_xor(ss, 1); ss += __shfl_xor(ss, 2); ss += __shfl_xor(ss, 4); ss += __shfl_xor(ss, 8);
        mu[j] = s * (1.f / HH);
        rs[j] = rsqrtf(ss * (1.f / HH) - mu[j] * mu[j] + LNEPS);
    }
    __syncthreads();  // all wbuf(wo)+aT(agg) reads done
    // hn -> aT (own rows) ; stage w1 half 0
#pragma unroll
    for (int g8 = 0; g8 < 8; g8++) {
        const float gg = g2[g8 * 16 + lr], bb = bl2[g8 * 16 + lr];
#pragma unroll
        for (int j = 0; j < 4; j++) {
            const int i = m0 + 4 * lg + j;
            aT[(i * 128 + g8 * 16 + lr) ^ ((i & 7) << 3)] = f2bf((hv[g8][j] - mu[j]) * rs[j] * gg + bb);
        }
    }
#pragma unroll
    for (int i = 0; i < 8; i++) {
        const int off = i * 2048 + t * 8;
        const int k8 = off >> 10, rem = off & 1023;
        *reinterpret_cast<u16x8*>(&wbuf[off]) = *reinterpret_cast<const u16x8*>(w1p + (k8 << 11) + rem);
    }
    __syncthreads();
    bf16x8 a2[4];
#pragma unroll
    for (int kc = 0; kc < 4; kc++)
        a2[kc] = *reinterpret_cast<const bf16x8*>(&aT[(row * 128 + kc * 32 + lg * 8) ^ ((row & 7) << 3)]);

    // ---- mlp1 in two N-halves ----
#pragma unroll 1
    for (int half = 0; half < 2; half++) {
#pragma unroll 1
        for (int Gl = 0; Gl < 8; Gl++) {
            const int G = half * 8 + Gl;
            f32x4 a1 = (f32x4){0.f, 0.f, 0.f, 0.f};
#pragma unroll
            for (int kc = 0; kc < 4; kc++)
                a1 = __builtin_amdgcn_mfma_f32_16x16x32_bf16(
                    a2[kc],
                    *reinterpret_cast<const bf16x8*>(&wbuf[(((kc << 2) + lg) * 128 + Gl * 16 + lr) << 3]),
                    a1, 0, 0, 0);
            const float bias = b1[G * 16 + lr];
#pragma unroll
            for (int j = 0; j < 4; j++) {
                const int i = m0 + 4 * lg + j;
                tT[(i * 256 + G * 16 + lr) ^ ((i & 7) << 3)] = f2bf(gelu_tanh(a1[j] + bias));
            }
        }
        __syncthreads();  // wbuf reads done
        if (half == 0) {
#pragma unroll
            for (int i = 0; i < 8; i++) {
                const int off = i * 2048 + t * 8;
                const int k8 = off >> 10, rem = off & 1023;
                *reinterpret_cast<u16x8*>(&wbuf[off]) = *reinterpret_cast<const u16x8*>(w1p + (k8 << 11) + 1024 + rem);
            }
        } else {
#pragma unroll
            for (int i = 0; i < 8; i++) {
                const int off = i * 2048 + t * 8;
                *reinterpret_cast<u16x8*>(&wbuf[off]) = *reinterpret_cast<const u16x8*>(w2p + off);
            }
        }
        __syncthreads();
    }
    // ---- mlp2 in two K-halves (w2 panel staged per half) ----
    f32x4 acc2[8];
#pragma unroll
    for (int g8 = 0; g8 < 8; g8++) acc2[g8] = (f32x4){0.f, 0.f, 0.f, 0.f};
#pragma unroll 1
    for (int half = 0; half < 2; half++) {
        bf16x8 a3[4];
#pragma unroll
        for (int kc = 0; kc < 4; kc++)
            a3[kc] = *reinterpret_cast<const bf16x8*>(&tT[(row * 256 + half * 128 + kc * 32 + lg * 8) ^ ((row & 7) << 3)]);
#pragma unroll 1
        for (int g8 = 0; g8 < 8; g8++)
#pragma unroll
            for (int kc = 0; kc < 4; kc++)
                acc2[g8] = __builtin_amdgcn_mfma_f32_16x16x32_bf16(
                    a3[kc],
                    *reinterpret_cast<const bf16x8*>(&wbuf[(((kc << 2) + lg) * 128 + g8 * 16 + lr) << 3]),
                    acc2[g8], 0, 0, 0);
        if (half == 0) {
            __syncthreads();
#pragma unroll
            for (int i = 0; i < 8; i++) {
                const int off = i * 2048 + t * 8;
                *reinterpret_cast<u16x8*>(&wbuf[off]) = *reinterpret_cast<const u16x8*>(w2p + 16384 + off);
            }
            __syncthreads();
        }
    }
#pragma unroll
    for (int g8 = 0; g8 < 8; g8++) {
        const float bias = b2[g8 * 16 + lr];
#pragma unroll
        for (int j = 0; j < 4; j++)
            out[(size_t)(rb + m0 + 4 * lg + j) * HH + g8 * 16 + lr] = hv[g8][j] + acc2[g8][j] + bias;
    }
}

extern "C" void kernel_launch(void* const* d_in, const int* in_sizes, int n_in,
                              void* d_out, int out_size, void* d_ws, size_t ws_size,
                              hipStream_t stream) {
    const float* x = (const float*)d_in[0];
    const int* erow = (const int*)d_in[1];
    const int* ecol = (const int*)d_in[2];
    const float* ln1g = (const float*)d_in[3];
    const float* ln1b = (const float*)d_in[4];
    const float* wq = (const float*)d_in[5];
    const float* bq = (const float*)d_in[6];
    const float* wk = (const float*)d_in[7];
    const float* bk = (const float*)d_in[8];
    const float* wv = (const float*)d_in[9];
    const float* bv = (const float*)d_in[10];
    const float* wo = (const float*)d_in[11];
    const float* bo = (const float*)d_in[12];
    const float* ln2g = (const float*)d_in[13];
    const float* ln2b = (const float*)d_in[14];
    const float* w1 = (const float*)d_in[15];
    const float* b1 = (const float*)d_in[16];
    const float* w2 = (const float*)d_in[17];
    const float* b2 = (const float*)d_in[18];
    float* out = (float*)d_out;

    unsigned short* qb = (unsigned short*)d_ws;                 // NN*128 ushort (16 MB)
    unsigned char* kv8 = (unsigned char*)(qb + (size_t)NN * HH);  // NN*256 bytes (16 MB)
    unsigned short* aggb = (unsigned short*)(kv8 + (size_t)NN * 256); // NN*128 ushort
    unsigned short* wpack = aggb + (size_t)NN * HH;             // 131072 ushorts
    int* cnt = (int*)(wpack + 131072);
    int* offs = cnt + NN;
    int* cursor = offs + NN + 1;
    int* csr_col = cursor + NN;
    int* bsum = csr_col + NE;

    hipMemsetAsync(cnt, 0, NN * sizeof(int), stream);
    k_pack<<<512, 256, 0, stream>>>(wq, wk, wv, wo, w1, w2, wpack);
    k_count<<<NE / 256, 256, 0, stream>>>(erow, cnt);
    k_scan1<<<NN / 256, 256, 0, stream>>>(cnt, bsum);
    k_scan2<<<NN / 256, 256, 0, stream>>>(cnt, bsum, offs, cursor);
    k_scatter<<<NE / 256, 256, 0, stream>>>(erow, ecol, cursor, csr_col);
    k_ln_qkv<<<NN / 128, 256, 0, stream>>>(x, ln1g, ln1b, wpack, bq, bk, bv, qb, kv8);
    k_attn<<<NN / 4, 256, 0, stream>>>(qb, kv8, offs, csr_col, aggb);
    k_tail<<<NN / 64, 256, 0, stream>>>(aggb, wpack + 49152, bo, x, ln2g, ln2b,
                                        wpack + 65536, b1, wpack + 98304, b2, out);
}

// Round 11
// 180.143 us; speedup vs baseline: 1.9386x; 1.4434x over previous
//
#include <hip/hip_runtime.h>
#include <math.h>

#define NN 65536
#define HH 128
#define DHH 16
#define NE 1048576
#define HID 256
#define LNEPS 1e-5f
#define NB 256      // buckets for CSR build
#define BCAP 6144   // max edges per bucket (mean 4096, sd 64 -> +32 sd)

typedef __attribute__((ext_vector_type(8))) short bf16x8;
typedef __attribute__((ext_vector_type(8))) unsigned short u16x8;
typedef __attribute__((ext_vector_type(4))) float f32x4;
typedef __attribute__((ext_vector_type(2))) float f32x2;

static __device__ __forceinline__ unsigned short f2bf(float f) {
    union { float f; unsigned u; } c; c.f = f;
    unsigned r = c.u + 0x7fffu + ((c.u >> 16) & 1u);
    return (unsigned short)(r >> 16);
}
static __device__ __forceinline__ float bf2f(unsigned short u) {
    union { unsigned u; float f; } c; c.u = ((unsigned)u) << 16;
    return c.f;
}
static __device__ __forceinline__ float gelu_tanh(float x) {
    const float c = 0.7978845608028654f;
    return 0.5f * x * (1.f + tanhf(c * (x + 0.044715f * x * x * x)));
}

// ---------------- CSR build: two-level bucket sort (no random global writes) ----------------
// pass 1: bin edges by row>>8 into fixed-stride bucket regions
__global__ __launch_bounds__(256) void k_bin(const int* __restrict__ er, const int* __restrict__ ec,
                                             int* __restrict__ gcur, unsigned long long* __restrict__ pairs) {
    __shared__ int cnt[NB];
    __shared__ int cur[NB];
    __shared__ int base[NB];
    const int t = threadIdx.x;
    const int e0 = blockIdx.x * 4096;
    cnt[t] = 0;
    __syncthreads();
    int rows[16], cols[16];
#pragma unroll
    for (int i = 0; i < 16; i++) {
        const int e = e0 + i * 256 + t;
        rows[i] = er[e];
        cols[i] = ec[e];
        atomicAdd(&cnt[rows[i] >> 8], 1);
    }
    __syncthreads();
    if (cnt[t] > 0) base[t] = atomicAdd(&gcur[t], cnt[t]);
    cur[t] = 0;
    __syncthreads();
#pragma unroll
    for (int i = 0; i < 16; i++) {
        const int b = rows[i] >> 8;
        const int slot = atomicAdd(&cur[b], 1);
        pairs[(size_t)b * BCAP + base[b] + slot] =
            ((unsigned long long)rows[i] << 32) | (unsigned)cols[i];
    }
}

// pass 2: exclusive scan of bucket totals
__global__ __launch_bounds__(256) void k_scanb(const int* __restrict__ gcur, int* __restrict__ bexcl) {
    __shared__ int sc[NB];
    const int t = threadIdx.x;
    const int v = gcur[t];
    sc[t] = v;
    __syncthreads();
    for (int d = 1; d < NB; d <<= 1) {
        int vv = (t >= d) ? sc[t - d] : 0;
        __syncthreads();
        sc[t] += vv;
        __syncthreads();
    }
    bexcl[t] = sc[t] - v;
}

// pass 3: per-bucket CSR finalize — LDS scatter, coalesced global writes
__global__ __launch_bounds__(256) void k_build(const unsigned long long* __restrict__ pairs,
                                               const int* __restrict__ gcur, const int* __restrict__ bexcl,
                                               int* __restrict__ offs, int* __restrict__ csr_col) {
    __shared__ int cnt[256];
    __shared__ int sc[256];
    __shared__ int cur[256];
    __shared__ int colbuf[BCAP];
    const int b = blockIdx.x, t = threadIdx.x;
    const int tot = gcur[b];
    const int cbase = bexcl[b];
    const unsigned long long* bp = pairs + (size_t)b * BCAP;
    cnt[t] = 0;
    __syncthreads();
    for (int i = t; i < tot; i += 256) {
        const unsigned long long u = bp[i];
        atomicAdd(&cnt[(int)(u >> 32) & 255], 1);
    }
    __syncthreads();
    sc[t] = cnt[t];
    __syncthreads();
    for (int d = 1; d < 256; d <<= 1) {
        int vv = (t >= d) ? sc[t - d] : 0;
        __syncthreads();
        sc[t] += vv;
        __syncthreads();
    }
    const int excl = sc[t] - cnt[t];
    offs[b * 256 + t] = cbase + excl;
    cur[t] = excl;
    if (b == NB - 1 && t == 255) offs[NN] = NE;
    __syncthreads();
    for (int i = t; i < tot; i += 256) {
        const unsigned long long u = bp[i];
        const int r = (int)(u >> 32) & 255;
        const int p = atomicAdd(&cur[r], 1);
        colbuf[p] = (int)(unsigned)u;
    }
    __syncthreads();
    for (int i = t; i < tot; i += 256) csr_col[cbase + i] = colbuf[i];
}

// ---------------- weight pack: fp32 W[K][N] -> bf16 Wp[(k>>3)*N + n][8] ----------------
__global__ __launch_bounds__(256) void k_pack(
    const float* __restrict__ wq, const float* __restrict__ wk, const float* __restrict__ wv,
    const float* __restrict__ wo, const float* __restrict__ w1, const float* __restrict__ w2,
    unsigned short* __restrict__ p) {
    const int b = blockIdx.x, t = threadIdx.x;
    const float* src; unsigned short* dst; int N, idx;
    if (b < 64)       { src = wq; dst = p;          N = 128; idx = b * 256 + t; }
    else if (b < 128) { src = wk; dst = p + 16384;  N = 128; idx = (b - 64) * 256 + t; }
    else if (b < 192) { src = wv; dst = p + 32768;  N = 128; idx = (b - 128) * 256 + t; }
    else if (b < 256) { src = wo; dst = p + 49152;  N = 128; idx = (b - 192) * 256 + t; }
    else if (b < 384) { src = w1; dst = p + 65536;  N = 256; idx = (b - 256) * 256 + t; }
    else              { src = w2; dst = p + 98304;  N = 128; idx = (b - 384) * 256 + t; }
    const int k = idx / N, n = idx % N;
    dst[(((k >> 3) * N + n) << 3) + (k & 7)] = f2bf(src[idx]);
}

// ---------------- K1: LN1 + QKV (MFMA bf16, weights staged in LDS) ----------
// outputs: q -> qb[row][128] bf16; k,v -> kv8[row][h][16k|16v] fp8 e4m3 (32 B per (row,h))
__global__ __launch_bounds__(256) void k_ln_qkv(
    const float* __restrict__ x, const float* __restrict__ g, const float* __restrict__ bl,
    const unsigned short* __restrict__ wp /* wq|wk|wv packed, 3*16384 */,
    const float* __restrict__ bq, const float* __restrict__ bk, const float* __restrict__ bv,
    unsigned short* __restrict__ qo, unsigned char* __restrict__ kv8) {
    __shared__ unsigned short aT[128 * 128];  // 32 KB
    __shared__ unsigned short wbuf[16384];    // 32 KB
    const int t = threadIdx.x;
    const int rb = blockIdx.x * 128;
    const int w = t >> 6, l = t & 63;
    // stage LN1(x) tile (wave w owns rows w*32..w*32+31) + stage wq
    {
        const int sr0 = w * 32 + (l >> 2), qd = l & 3;
#pragma unroll 1
        for (int rr = 0; rr < 2; rr++) {
            const int row = sr0 + rr * 16;
            const float4* xr = reinterpret_cast<const float4*>(x + (size_t)(rb + row) * HH) + qd * 8;
            float xa[32]; float s = 0.f, ss = 0.f;
#pragma unroll
            for (int i = 0; i < 8; i++) {
                float4 v4 = xr[i];
                xa[i * 4 + 0] = v4.x; xa[i * 4 + 1] = v4.y; xa[i * 4 + 2] = v4.z; xa[i * 4 + 3] = v4.w;
                s += v4.x + v4.y + v4.z + v4.w;
                ss += v4.x * v4.x + v4.y * v4.y + v4.z * v4.z + v4.w * v4.w;
            }
            s += __shfl_xor(s, 1); s += __shfl_xor(s, 2);
            ss += __shfl_xor(ss, 1); ss += __shfl_xor(ss, 2);
            const float mu = s * (1.f / HH);
            const float rs = rsqrtf(ss * (1.f / HH) - mu * mu + LNEPS);
#pragma unroll
            for (int c = 0; c < 4; c++) {
                u16x8 w8;
#pragma unroll
                for (int j2 = 0; j2 < 8; j2++) {
                    const int d = qd * 32 + c * 8 + j2;
                    w8[j2] = f2bf((xa[c * 8 + j2] - mu) * rs * g[d] + bl[d]);
                }
                const int uoff = (row * 128 + qd * 32 + c * 8) ^ ((row & 7) << 3);
                *reinterpret_cast<u16x8*>(&aT[uoff]) = w8;
            }
        }
#pragma unroll
        for (int i = 0; i < 8; i++) {
            const int off = i * 2048 + t * 8;
            *reinterpret_cast<u16x8*>(&wbuf[off]) = *reinterpret_cast<const u16x8*>(wp + off);
        }
    }
    __syncthreads();
    const int lr = l & 15, lg = l >> 4;
    const int row0 = w * 32 + lr;
    const int row1 = w * 32 + 16 + lr;
    bf16x8 a0[4], a1[4];
#pragma unroll
    for (int kc = 0; kc < 4; kc++) {
        a0[kc] = *reinterpret_cast<const bf16x8*>(&aT[(row0 * 128 + kc * 32 + lg * 8) ^ ((row0 & 7) << 3)]);
        a1[kc] = *reinterpret_cast<const bf16x8*>(&aT[(row1 * 128 + kc * 32 + lg * 8) ^ ((row1 & 7) << 3)]);
    }

#pragma unroll 1
    for (int m = 0; m < 3; m++) {
        const float* Bb = (m == 0) ? bq : (m == 1) ? bk : bv;
        f32x4 ac0[8], ac1[8];
#pragma unroll
        for (int g8 = 0; g8 < 8; g8++) { ac0[g8] = (f32x4){0.f,0.f,0.f,0.f}; ac1[g8] = (f32x4){0.f,0.f,0.f,0.f}; }
#pragma unroll
        for (int g8 = 0; g8 < 8; g8++)
#pragma unroll
            for (int kc = 0; kc < 4; kc++) {
                const bf16x8 bfr = *reinterpret_cast<const bf16x8*>(&wbuf[(((kc << 2) + lg) * 128 + g8 * 16 + lr) << 3]);
                ac0[g8] = __builtin_amdgcn_mfma_f32_16x16x32_bf16(a0[kc], bfr, ac0[g8], 0, 0, 0);
                ac1[g8] = __builtin_amdgcn_mfma_f32_16x16x32_bf16(a1[kc], bfr, ac1[g8], 0, 0, 0);
            }
        // restage next weight while results are written out
        __syncthreads();
        if (m < 2) {
            const unsigned short* nsrc = wp + (m + 1) * 16384;
#pragma unroll
            for (int i = 0; i < 8; i++) {
                const int off = i * 2048 + t * 8;
                *reinterpret_cast<u16x8*>(&wbuf[off]) = *reinterpret_cast<const u16x8*>(nsrc + off);
            }
        }
#pragma unroll
        for (int g8 = 0; g8 < 8; g8++) {
            const float bias = Bb[g8 * 16 + lr];
#pragma unroll
            for (int j = 0; j < 4; j++) {
                const int ra = rb + w * 32 + 4 * lg + j;
                const int rbb = ra + 16;
                const float y0 = ac0[g8][j] + bias, y1 = ac1[g8][j] + bias;
                if (m == 0) {
                    qo[(size_t)ra * HH + g8 * 16 + lr] = f2bf(y0);
                    qo[(size_t)rbb * HH + g8 * 16 + lr] = f2bf(y1);
                } else {
                    const int off = g8 * 32 + lr + ((m == 2) ? 16 : 0);
                    const int pk0 = __builtin_amdgcn_cvt_pk_fp8_f32(y0, y0, 0, false);
                    const int pk1 = __builtin_amdgcn_cvt_pk_fp8_f32(y1, y1, 0, false);
                    kv8[(size_t)ra * 256 + off] = (unsigned char)(pk0 & 0xff);
                    kv8[(size_t)rbb * 256 + off] = (unsigned char)(pk1 & 0xff);
                }
            }
        }
        if (m < 2) __syncthreads();
    }
}

// ---------------- K3: fused SDDMM + softmax + SpMM (fp8 kv gather, 2-deep pipeline) ----------------
__global__ __launch_bounds__(256) void k_attn(
    const unsigned short* __restrict__ q, const unsigned char* __restrict__ kv,
    const int* __restrict__ offs, const int* __restrict__ csr_col,
    unsigned short* __restrict__ agg) {
    const int wave = threadIdx.x >> 6;
    const int lane = threadIdx.x & 63;
    const int row = blockIdx.x * 4 + wave;
    const int h = lane & 7, es = lane >> 3;
    const int c0 = offs[row], cnt = offs[row + 1] - c0;

    float qf[16];
    {
        const u16x8* qp = reinterpret_cast<const u16x8*>(q + (size_t)row * HH + h * DHH);
        u16x8 q0 = qp[0], q1 = qp[1];
#pragma unroll
        for (int j = 0; j < 8; j++) { qf[j] = bf2f(q0[j]); qf[8 + j] = bf2f(q1[j]); }
    }
    float m = 0.f, den = 0.f;
    float acc[16] = {};

    // 2-deep prologue: col for chunk0 and chunk1; kv loads for chunk0 in flight
    bool act0 = es < cnt;
    int col0 = act0 ? csr_col[c0 + es] : 0;
    bool act1 = (8 + es) < cnt;
    int col1 = act1 ? csr_col[c0 + 8 + es] : 0;
    const int4* p0 = reinterpret_cast<const int4*>(kv + (size_t)col0 * 256 + h * 32);
    int4 kd = p0[0], vd = p0[1];

    for (int base = 0; base < cnt; base += 8) {
        // issue next chunk's kv loads (col already resident) + col two ahead
        const int4* p1 = reinterpret_cast<const int4*>(kv + (size_t)col1 * 256 + h * 32);
        const int4 nkd = p1[0], nvd = p1[1];
        const bool act2 = (base + 16 + es) < cnt;
        const int col2 = act2 ? csr_col[c0 + base + 16 + es] : 0;

        // convert k fp8 -> f32 and dot
        float kf[16];
        {
            f32x2 r;
            r = __builtin_amdgcn_cvt_pk_f32_fp8(kd.x, false); kf[0] = r[0]; kf[1] = r[1];
            r = __builtin_amdgcn_cvt_pk_f32_fp8(kd.x, true);  kf[2] = r[0]; kf[3] = r[1];
            r = __builtin_amdgcn_cvt_pk_f32_fp8(kd.y, false); kf[4] = r[0]; kf[5] = r[1];
            r = __builtin_amdgcn_cvt_pk_f32_fp8(kd.y, true);  kf[6] = r[0]; kf[7] = r[1];
            r = __builtin_amdgcn_cvt_pk_f32_fp8(kd.z, false); kf[8] = r[0]; kf[9] = r[1];
            r = __builtin_amdgcn_cvt_pk_f32_fp8(kd.z, true);  kf[10] = r[0]; kf[11] = r[1];
            r = __builtin_amdgcn_cvt_pk_f32_fp8(kd.w, false); kf[12] = r[0]; kf[13] = r[1];
            r = __builtin_amdgcn_cvt_pk_f32_fp8(kd.w, true);  kf[14] = r[0]; kf[15] = r[1];
        }
        float dot = 0.f;
#pragma unroll
        for (int j = 0; j < 16; j++) dot += qf[j] * kf[j];
        float sc = act0 ? dot * 0.25f : -INFINITY;  // 1/sqrt(16)
        float cm = sc;
        cm = fmaxf(cm, __shfl_xor(cm, 8));
        cm = fmaxf(cm, __shfl_xor(cm, 16));
        cm = fmaxf(cm, __shfl_xor(cm, 32));
        if (base == 0) {
            m = cm;
        } else if (!__all(cm <= m + 8.f)) {   // defer-max: rescale ~never
            const float nm = fmaxf(m, cm);
            const float s8 = expf(m - nm);
            den *= s8;
#pragma unroll
            for (int i = 0; i < 16; i++) acc[i] *= s8;
            m = nm;
        }
        const float pp = act0 ? expf(sc - m) : 0.f;
        den += pp;
        {
            f32x2 r;
            r = __builtin_amdgcn_cvt_pk_f32_fp8(vd.x, false); acc[0] += pp * r[0]; acc[1] += pp * r[1];
            r = __builtin_amdgcn_cvt_pk_f32_fp8(vd.x, true);  acc[2] += pp * r[0]; acc[3] += pp * r[1];
            r = __builtin_amdgcn_cvt_pk_f32_fp8(vd.y, false); acc[4] += pp * r[0]; acc[5] += pp * r[1];
            r = __builtin_amdgcn_cvt_pk_f32_fp8(vd.y, true);  acc[6] += pp * r[0]; acc[7] += pp * r[1];
            r = __builtin_amdgcn_cvt_pk_f32_fp8(vd.z, false); acc[8] += pp * r[0]; acc[9] += pp * r[1];
            r = __builtin_amdgcn_cvt_pk_f32_fp8(vd.z, true);  acc[10] += pp * r[0]; acc[11] += pp * r[1];
            r = __builtin_amdgcn_cvt_pk_f32_fp8(vd.w, false); acc[12] += pp * r[0]; acc[13] += pp * r[1];
            r = __builtin_amdgcn_cvt_pk_f32_fp8(vd.w, true);  acc[14] += pp * r[0]; acc[15] += pp * r[1];
        }
        act0 = act1; act1 = act2; col1 = col2; kd = nkd; vd = nvd;
    }
#pragma unroll
    for (int d = 8; d < 64; d <<= 1) {
        den += __shfl_xor(den, d);
#pragma unroll
        for (int i = 0; i < 16; i++) acc[i] += __shfl_xor(acc[i], d);
    }
    const float inv = 1.f / (den + 1e-9f);
    if (es == 0) {
        unsigned short* ar = agg + (size_t)row * HH + h * DHH;
        u16x8 o0, o1;
#pragma unroll
        for (int j = 0; j < 8; j++) { o0[j] = f2bf(acc[j] * inv); o1[j] = f2bf(acc[8 + j] * inv); }
        reinterpret_cast<u16x8*>(ar)[0] = o0;
        reinterpret_cast<u16x8*>(ar)[1] = o1;
    }
}

// ---------------- K4: fused wo+res+LN2+MLP1+gelu+MLP2+res — weights staged in LDS ----------
__global__ __launch_bounds__(256) void k_tail(
    const unsigned short* __restrict__ aggb, const unsigned short* __restrict__ wop,
    const float* __restrict__ bo, const float* __restrict__ x,
    const float* __restrict__ g2, const float* __restrict__ bl2,
    const unsigned short* __restrict__ w1p, const float* __restrict__ b1,
    const unsigned short* __restrict__ w2p, const float* __restrict__ b2,
    float* __restrict__ out) {
    __shared__ unsigned short aT[64 * 128];   // 16 KB: agg tile, then hn tile
    __shared__ unsigned short tT[64 * 256];   // 32 KB: gelu(mlp1)
    __shared__ unsigned short wbuf[16384];    // 32 KB: current weight panel
    const int t = threadIdx.x;
    const int rb = blockIdx.x * 64;
    const int w = t >> 6, l = t & 63;
    const int m0 = w * 16, lr = l & 15, lg = l >> 4;
    const int row = m0 + lr;

    // stage agg tile + wo panel
    {
        const int r = t >> 2, qd = t & 3;
        const u16x8* src = reinterpret_cast<const u16x8*>(aggb + (size_t)(rb + r) * HH) + qd * 4;
#pragma unroll
        for (int c = 0; c < 4; c++) {
            const int uoff = (r * 128 + qd * 32 + c * 8) ^ ((r & 7) << 3);
            *reinterpret_cast<u16x8*>(&aT[uoff]) = src[c];
        }
#pragma unroll
        for (int i = 0; i < 8; i++) {
            const int off = i * 2048 + t * 8;
            *reinterpret_cast<u16x8*>(&wbuf[off]) = *reinterpret_cast<const u16x8*>(wop + off);
        }
    }
    __syncthreads();

    // ---- agg @ wo (B from LDS) ----
    bf16x8 a[4];
#pragma unroll
    for (int kc = 0; kc < 4; kc++)
        a[kc] = *reinterpret_cast<const bf16x8*>(&aT[(row * 128 + kc * 32 + lg * 8) ^ ((row & 7) << 3)]);
    f32x4 acc[8];
#pragma unroll
    for (int g8 = 0; g8 < 8; g8++) acc[g8] = (f32x4){0.f, 0.f, 0.f, 0.f};
#pragma unroll
    for (int g8 = 0; g8 < 8; g8++)
#pragma unroll
        for (int kc = 0; kc < 4; kc++)
            acc[g8] = __builtin_amdgcn_mfma_f32_16x16x32_bf16(
                a[kc],
                *reinterpret_cast<const bf16x8*>(&wbuf[(((kc << 2) + lg) * 128 + g8 * 16 + lr) << 3]),
                acc[g8], 0, 0, 0);
    // h = acc + bo + x
    float hv[8][4];
#pragma unroll
    for (int g8 = 0; g8 < 8; g8++) {
        const float bias = bo[g8 * 16 + lr];
#pragma unroll
        for (int j = 0; j < 4; j++)
            hv[g8][j] = acc[g8][j] + bias + x[(size_t)(rb + m0 + 4 * lg + j) * HH + g8 * 16 + lr];
    }
    // ---- LN2 ----
    float mu[4], rs[4];
#pragma unroll
    for (int j = 0; j < 4; j++) {
        float s = 0.f, ss = 0.f;
#pragma unroll
        for (int g8 = 0; g8 < 8; g8++) { const float hh = hv[g8][j]; s += hh; ss += hh * hh; }
        s += __shfl_xor(s, 1); s += __shfl_xor(s, 2); s += __shfl_xor(s, 4); s += __shfl_xor(s, 8);
        ss += __shfl_xor(ss, 1); ss += __shfl_xor(ss, 2); ss += __shfl_xor(ss, 4); ss += __shfl_xor(ss, 8);
        mu[j] = s * (1.f / HH);
        rs[j] = rsqrtf(ss * (1.f / HH) - mu[j] * mu[j] + LNEPS);
    }
    __syncthreads();  // all wbuf(wo)+aT(agg) reads done
    // hn -> aT (own rows) ; stage w1 half 0
#pragma unroll
    for (int g8 = 0; g8 < 8; g8++) {
        const float gg = g2[g8 * 16 + lr], bb = bl2[g8 * 16 + lr];
#pragma unroll
        for (int j = 0; j < 4; j++) {
            const int i = m0 + 4 * lg + j;
            aT[(i * 128 + g8 * 16 + lr) ^ ((i & 7) << 3)] = f2bf((hv[g8][j] - mu[j]) * rs[j] * gg + bb);
        }
    }
#pragma unroll
    for (int i = 0; i < 8; i++) {
        const int off = i * 2048 + t * 8;
        const int k8 = off >> 10, rem = off & 1023;
        *reinterpret_cast<u16x8*>(&wbuf[off]) = *reinterpret_cast<const u16x8*>(w1p + (k8 << 11) + rem);
    }
    __syncthreads();
    bf16x8 a2[4];
#pragma unroll
    for (int kc = 0; kc < 4; kc++)
        a2[kc] = *reinterpret_cast<const bf16x8*>(&aT[(row * 128 + kc * 32 + lg * 8) ^ ((row & 7) << 3)]);

    // ---- mlp1 in two N-halves ----
#pragma unroll 1
    for (int half = 0; half < 2; half++) {
#pragma unroll 1
        for (int Gl = 0; Gl < 8; Gl++) {
            const int G = half * 8 + Gl;
            f32x4 a1 = (f32x4){0.f, 0.f, 0.f, 0.f};
#pragma unroll
            for (int kc = 0; kc < 4; kc++)
                a1 = __builtin_amdgcn_mfma_f32_16x16x32_bf16(
                    a2[kc],
                    *reinterpret_cast<const bf16x8*>(&wbuf[(((kc << 2) + lg) * 128 + Gl * 16 + lr) << 3]),
                    a1, 0, 0, 0);
            const float bias = b1[G * 16 + lr];
#pragma unroll
            for (int j = 0; j < 4; j++) {
                const int i = m0 + 4 * lg + j;
                tT[(i * 256 + G * 16 + lr) ^ ((i & 7) << 3)] = f2bf(gelu_tanh(a1[j] + bias));
            }
        }
        __syncthreads();  // wbuf reads done
        if (half == 0) {
#pragma unroll
            for (int i = 0; i < 8; i++) {
                const int off = i * 2048 + t * 8;
                const int k8 = off >> 10, rem = off & 1023;
                *reinterpret_cast<u16x8*>(&wbuf[off]) = *reinterpret_cast<const u16x8*>(w1p + (k8 << 11) + 1024 + rem);
            }
        } else {
#pragma unroll
            for (int i = 0; i < 8; i++) {
                const int off = i * 2048 + t * 8;
                *reinterpret_cast<u16x8*>(&wbuf[off]) = *reinterpret_cast<const u16x8*>(w2p + off);
            }
        }
        __syncthreads();
    }
    // ---- mlp2 in two K-halves (w2 panel staged per half) ----
    f32x4 acc2[8];
#pragma unroll
    for (int g8 = 0; g8 < 8; g8++) acc2[g8] = (f32x4){0.f, 0.f, 0.f, 0.f};
#pragma unroll 1
    for (int half = 0; half < 2; half++) {
        bf16x8 a3[4];
#pragma unroll
        for (int kc = 0; kc < 4; kc++)
            a3[kc] = *reinterpret_cast<const bf16x8*>(&tT[(row * 256 + half * 128 + kc * 32 + lg * 8) ^ ((row & 7) << 3)]);
#pragma unroll 1
        for (int g8 = 0; g8 < 8; g8++)
#pragma unroll
            for (int kc = 0; kc < 4; kc++)
                acc2[g8] = __builtin_amdgcn_mfma_f32_16x16x32_bf16(
                    a3[kc],
                    *reinterpret_cast<const bf16x8*>(&wbuf[(((kc << 2) + lg) * 128 + g8 * 16 + lr) << 3]),
                    acc2[g8], 0, 0, 0);
        if (half == 0) {
            __syncthreads();
#pragma unroll
            for (int i = 0; i < 8; i++) {
                const int off = i * 2048 + t * 8;
                *reinterpret_cast<u16x8*>(&wbuf[off]) = *reinterpret_cast<const u16x8*>(w2p + 16384 + off);
            }
            __syncthreads();
        }
    }
#pragma unroll
    for (int g8 = 0; g8 < 8; g8++) {
        const float bias = b2[g8 * 16 + lr];
#pragma unroll
        for (int j = 0; j < 4; j++)
            out[(size_t)(rb + m0 + 4 * lg + j) * HH + g8 * 16 + lr] = hv[g8][j] + acc2[g8][j] + bias;
    }
}

extern "C" void kernel_launch(void* const* d_in, const int* in_sizes, int n_in,
                              void* d_out, int out_size, void* d_ws, size_t ws_size,
                              hipStream_t stream) {
    const float* x = (const float*)d_in[0];
    const int* erow = (const int*)d_in[1];
    const int* ecol = (const int*)d_in[2];
    const float* ln1g = (const float*)d_in[3];
    const float* ln1b = (const float*)d_in[4];
    const float* wq = (const float*)d_in[5];
    const float* bq = (const float*)d_in[6];
    const float* wk = (const float*)d_in[7];
    const float* bk = (const float*)d_in[8];
    const float* wv = (const float*)d_in[9];
    const float* bv = (const float*)d_in[10];
    const float* wo = (const float*)d_in[11];
    const float* bo = (const float*)d_in[12];
    const float* ln2g = (const float*)d_in[13];
    const float* ln2b = (const float*)d_in[14];
    const float* w1 = (const float*)d_in[15];
    const float* b1 = (const float*)d_in[16];
    const float* w2 = (const float*)d_in[17];
    const float* b2 = (const float*)d_in[18];
    float* out = (float*)d_out;

    unsigned short* qb = (unsigned short*)d_ws;                        // NN*128 ushort (16 MB)
    unsigned char* kv8 = (unsigned char*)(qb + (size_t)NN * HH);       // NN*256 bytes (16 MB)
    unsigned short* aggb = (unsigned short*)(kv8 + (size_t)NN * 256);  // NN*128 ushort (16 MB)
    unsigned short* wpack = aggb + (size_t)NN * HH;                    // 131072 ushorts (256 KB)
    int* offs = (int*)(wpack + 131072);                                // NN+1 ints
    int* csr_col = offs + NN + 1;                                      // NE ints (4 MB)
    int* gcur = csr_col + NE;                                          // NB ints
    int* bexcl = gcur + NB;                                            // NB ints
    unsigned long long* pairs = (unsigned long long*)(bexcl + NB + 2); // NB*BCAP (12 MB)

    hipMemsetAsync(gcur, 0, NB * sizeof(int), stream);
    k_pack<<<512, 256, 0, stream>>>(wq, wk, wv, wo, w1, w2, wpack);
    k_bin<<<NE / 4096, 256, 0, stream>>>(erow, ecol, gcur, pairs);
    k_scanb<<<1, 256, 0, stream>>>(gcur, bexcl);
    k_build<<<NB, 256, 0, stream>>>(pairs, gcur, bexcl, offs, csr_col);
    k_ln_qkv<<<NN / 128, 256, 0, stream>>>(x, ln1g, ln1b, wpack, bq, bk, bv, qb, kv8);
    k_attn<<<NN / 4, 256, 0, stream>>>(qb, kv8, offs, csr_col, aggb);
    k_tail<<<NN / 64, 256, 0, stream>>>(aggb, wpack + 49152, bo, x, ln2g, ln2b,
                                        wpack + 65536, b1, wpack + 98304, b2, out);
}

// Round 12
// 168.405 us; speedup vs baseline: 2.0737x; 1.0697x over previous
//
#include <hip/hip_runtime.h>
#include <math.h>

#define NN 65536
#define HH 128
#define DHH 16
#define NE 1048576
#define HID 256
#define LNEPS 1e-5f
#define NB 256      // buckets for CSR build
#define BCAP 6144   // max edges per bucket (mean 4096, sd 64 -> +32 sd)

typedef __attribute__((ext_vector_type(8))) short bf16x8;
typedef __attribute__((ext_vector_type(8))) unsigned short u16x8;
typedef __attribute__((ext_vector_type(4))) float f32x4;
typedef __attribute__((ext_vector_type(2))) float f32x2;

static __device__ __forceinline__ unsigned short f2bf(float f) {
    union { float f; unsigned u; } c; c.f = f;
    unsigned r = c.u + 0x7fffu + ((c.u >> 16) & 1u);
    return (unsigned short)(r >> 16);
}
static __device__ __forceinline__ float bf2f(unsigned short u) {
    union { unsigned u; float f; } c; c.u = ((unsigned)u) << 16;
    return c.f;
}
// gelu_tanh(x) = 0.5x(1+tanh(c(x+0.044715x^3))) == x*sigmoid(2c(x+0.044715x^3))
//             = x * rcp(1 + exp2(-2*log2e*c*(x+0.044715x^3)))   [exact identity]
static __device__ __forceinline__ float gelu_tanh(float x) {
    const float a = -2.302225282f;  // -2*log2(e)*0.7978845608
    const float u = a * (x + 0.044715f * x * x * x);
    const float e = __builtin_amdgcn_exp2f(u);
    return x * __builtin_amdgcn_rcpf(1.f + e);
}

// ---------------- CSR build: two-level bucket sort (no random global writes) ----------------
__global__ __launch_bounds__(256) void k_bin(const int* __restrict__ er, const int* __restrict__ ec,
                                             int* __restrict__ gcur, unsigned long long* __restrict__ pairs) {
    __shared__ int cnt[NB];
    __shared__ int cur[NB];
    __shared__ int base[NB];
    const int t = threadIdx.x;
    const int e0 = blockIdx.x * 4096;
    cnt[t] = 0;
    __syncthreads();
    int rows[16], cols[16];
#pragma unroll
    for (int i = 0; i < 16; i++) {
        const int e = e0 + i * 256 + t;
        rows[i] = er[e];
        cols[i] = ec[e];
        atomicAdd(&cnt[rows[i] >> 8], 1);
    }
    __syncthreads();
    if (cnt[t] > 0) base[t] = atomicAdd(&gcur[t], cnt[t]);
    cur[t] = 0;
    __syncthreads();
#pragma unroll
    for (int i = 0; i < 16; i++) {
        const int b = rows[i] >> 8;
        const int slot = atomicAdd(&cur[b], 1);
        pairs[(size_t)b * BCAP + base[b] + slot] =
            ((unsigned long long)rows[i] << 32) | (unsigned)cols[i];
    }
}

__global__ __launch_bounds__(256) void k_scanb(const int* __restrict__ gcur, int* __restrict__ bexcl) {
    __shared__ int sc[NB];
    const int t = threadIdx.x;
    const int v = gcur[t];
    sc[t] = v;
    __syncthreads();
    for (int d = 1; d < NB; d <<= 1) {
        int vv = (t >= d) ? sc[t - d] : 0;
        __syncthreads();
        sc[t] += vv;
        __syncthreads();
    }
    bexcl[t] = sc[t] - v;
}

__global__ __launch_bounds__(256) void k_build(const unsigned long long* __restrict__ pairs,
                                               const int* __restrict__ gcur, const int* __restrict__ bexcl,
                                               int* __restrict__ offs, int* __restrict__ csr_col) {
    __shared__ int cnt[256];
    __shared__ int sc[256];
    __shared__ int cur[256];
    __shared__ int colbuf[BCAP];
    const int b = blockIdx.x, t = threadIdx.x;
    const int tot = gcur[b];
    const int cbase = bexcl[b];
    const unsigned long long* bp = pairs + (size_t)b * BCAP;
    cnt[t] = 0;
    __syncthreads();
    for (int i = t; i < tot; i += 256) {
        const unsigned long long u = bp[i];
        atomicAdd(&cnt[(int)(u >> 32) & 255], 1);
    }
    __syncthreads();
    sc[t] = cnt[t];
    __syncthreads();
    for (int d = 1; d < 256; d <<= 1) {
        int vv = (t >= d) ? sc[t - d] : 0;
        __syncthreads();
        sc[t] += vv;
        __syncthreads();
    }
    const int excl = sc[t] - cnt[t];
    offs[b * 256 + t] = cbase + excl;
    cur[t] = excl;
    if (b == NB - 1 && t == 255) offs[NN] = NE;
    __syncthreads();
    for (int i = t; i < tot; i += 256) {
        const unsigned long long u = bp[i];
        const int r = (int)(u >> 32) & 255;
        const int p = atomicAdd(&cur[r], 1);
        colbuf[p] = (int)(unsigned)u;
    }
    __syncthreads();
    for (int i = t; i < tot; i += 256) csr_col[cbase + i] = colbuf[i];
}

// ---------------- weight pack: fp32 W[K][N] -> bf16 Wp[(k>>3)*N + n][8] ----------------
__global__ __launch_bounds__(256) void k_pack(
    const float* __restrict__ wq, const float* __restrict__ wk, const float* __restrict__ wv,
    const float* __restrict__ wo, const float* __restrict__ w1, const float* __restrict__ w2,
    unsigned short* __restrict__ p) {
    const int b = blockIdx.x, t = threadIdx.x;
    const float* src; unsigned short* dst; int N, idx;
    if (b < 64)       { src = wq; dst = p;          N = 128; idx = b * 256 + t; }
    else if (b < 128) { src = wk; dst = p + 16384;  N = 128; idx = (b - 64) * 256 + t; }
    else if (b < 192) { src = wv; dst = p + 32768;  N = 128; idx = (b - 128) * 256 + t; }
    else if (b < 256) { src = wo; dst = p + 49152;  N = 128; idx = (b - 192) * 256 + t; }
    else if (b < 384) { src = w1; dst = p + 65536;  N = 256; idx = (b - 256) * 256 + t; }
    else              { src = w2; dst = p + 98304;  N = 128; idx = (b - 384) * 256 + t; }
    const int k = idx / N, n = idx % N;
    dst[(((k >> 3) * N + n) << 3) + (k & 7)] = f2bf(src[idx]);
}

// ---------------- K1: LN1 + QKV (MFMA bf16, weights staged in LDS) ----------
__global__ __launch_bounds__(256) void k_ln_qkv(
    const float* __restrict__ x, const float* __restrict__ g, const float* __restrict__ bl,
    const unsigned short* __restrict__ wp /* wq|wk|wv packed, 3*16384 */,
    const float* __restrict__ bq, const float* __restrict__ bk, const float* __restrict__ bv,
    unsigned short* __restrict__ qo, unsigned char* __restrict__ kv8) {
    __shared__ unsigned short aT[128 * 128];  // 32 KB
    __shared__ unsigned short wbuf[16384];    // 32 KB
    const int t = threadIdx.x;
    const int rb = blockIdx.x * 128;
    const int w = t >> 6, l = t & 63;
    {
        const int sr0 = w * 32 + (l >> 2), qd = l & 3;
#pragma unroll 1
        for (int rr = 0; rr < 2; rr++) {
            const int row = sr0 + rr * 16;
            const float4* xr = reinterpret_cast<const float4*>(x + (size_t)(rb + row) * HH) + qd * 8;
            float xa[32]; float s = 0.f, ss = 0.f;
#pragma unroll
            for (int i = 0; i < 8; i++) {
                float4 v4 = xr[i];
                xa[i * 4 + 0] = v4.x; xa[i * 4 + 1] = v4.y; xa[i * 4 + 2] = v4.z; xa[i * 4 + 3] = v4.w;
                s += v4.x + v4.y + v4.z + v4.w;
                ss += v4.x * v4.x + v4.y * v4.y + v4.z * v4.z + v4.w * v4.w;
            }
            s += __shfl_xor(s, 1); s += __shfl_xor(s, 2);
            ss += __shfl_xor(ss, 1); ss += __shfl_xor(ss, 2);
            const float mu = s * (1.f / HH);
            const float rs = rsqrtf(ss * (1.f / HH) - mu * mu + LNEPS);
#pragma unroll
            for (int c = 0; c < 4; c++) {
                u16x8 w8;
#pragma unroll
                for (int j2 = 0; j2 < 8; j2++) {
                    const int d = qd * 32 + c * 8 + j2;
                    w8[j2] = f2bf((xa[c * 8 + j2] - mu) * rs * g[d] + bl[d]);
                }
                const int uoff = (row * 128 + qd * 32 + c * 8) ^ ((row & 7) << 3);
                *reinterpret_cast<u16x8*>(&aT[uoff]) = w8;
            }
        }
#pragma unroll
        for (int i = 0; i < 8; i++) {
            const int off = i * 2048 + t * 8;
            *reinterpret_cast<u16x8*>(&wbuf[off]) = *reinterpret_cast<const u16x8*>(wp + off);
        }
    }
    __syncthreads();
    const int lr = l & 15, lg = l >> 4;
    const int row0 = w * 32 + lr;
    const int row1 = w * 32 + 16 + lr;
    bf16x8 a0[4], a1[4];
#pragma unroll
    for (int kc = 0; kc < 4; kc++) {
        a0[kc] = *reinterpret_cast<const bf16x8*>(&aT[(row0 * 128 + kc * 32 + lg * 8) ^ ((row0 & 7) << 3)]);
        a1[kc] = *reinterpret_cast<const bf16x8*>(&aT[(row1 * 128 + kc * 32 + lg * 8) ^ ((row1 & 7) << 3)]);
    }

#pragma unroll 1
    for (int m = 0; m < 3; m++) {
        const float* Bb = (m == 0) ? bq : (m == 1) ? bk : bv;
        f32x4 ac0[8], ac1[8];
#pragma unroll
        for (int g8 = 0; g8 < 8; g8++) { ac0[g8] = (f32x4){0.f,0.f,0.f,0.f}; ac1[g8] = (f32x4){0.f,0.f,0.f,0.f}; }
#pragma unroll
        for (int g8 = 0; g8 < 8; g8++)
#pragma unroll
            for (int kc = 0; kc < 4; kc++) {
                const bf16x8 bfr = *reinterpret_cast<const bf16x8*>(&wbuf[(((kc << 2) + lg) * 128 + g8 * 16 + lr) << 3]);
                ac0[g8] = __builtin_amdgcn_mfma_f32_16x16x32_bf16(a0[kc], bfr, ac0[g8], 0, 0, 0);
                ac1[g8] = __builtin_amdgcn_mfma_f32_16x16x32_bf16(a1[kc], bfr, ac1[g8], 0, 0, 0);
            }
        __syncthreads();
        if (m < 2) {
            const unsigned short* nsrc = wp + (m + 1) * 16384;
#pragma unroll
            for (int i = 0; i < 8; i++) {
                const int off = i * 2048 + t * 8;
                *reinterpret_cast<u16x8*>(&wbuf[off]) = *reinterpret_cast<const u16x8*>(nsrc + off);
            }
        }
#pragma unroll
        for (int g8 = 0; g8 < 8; g8++) {
            const float bias = Bb[g8 * 16 + lr];
#pragma unroll
            for (int j = 0; j < 4; j++) {
                const int ra = rb + w * 32 + 4 * lg + j;
                const int rbb = ra + 16;
                const float y0 = ac0[g8][j] + bias, y1 = ac1[g8][j] + bias;
                if (m == 0) {
                    qo[(size_t)ra * HH + g8 * 16 + lr] = f2bf(y0);
                    qo[(size_t)rbb * HH + g8 * 16 + lr] = f2bf(y1);
                } else {
                    const int off = g8 * 32 + lr + ((m == 2) ? 16 : 0);
                    const int pk0 = __builtin_amdgcn_cvt_pk_fp8_f32(y0, y0, 0, false);
                    const int pk1 = __builtin_amdgcn_cvt_pk_fp8_f32(y1, y1, 0, false);
                    kv8[(size_t)ra * 256 + off] = (unsigned char)(pk0 & 0xff);
                    kv8[(size_t)rbb * 256 + off] = (unsigned char)(pk1 & 0xff);
                }
            }
        }
        if (m < 2) __syncthreads();
    }
}

// ---------------- K3: fused SDDMM + softmax + SpMM (fp8 kv gather, 2-deep pipeline) ----------------
__global__ __launch_bounds__(256) void k_attn(
    const unsigned short* __restrict__ q, const unsigned char* __restrict__ kv,
    const int* __restrict__ offs, const int* __restrict__ csr_col,
    unsigned short* __restrict__ agg) {
    const int wave = threadIdx.x >> 6;
    const int lane = threadIdx.x & 63;
    const int row = blockIdx.x * 4 + wave;
    const int h = lane & 7, es = lane >> 3;
    const int c0 = offs[row], cnt = offs[row + 1] - c0;

    float qf[16];
    {
        const u16x8* qp = reinterpret_cast<const u16x8*>(q + (size_t)row * HH + h * DHH);
        u16x8 q0 = qp[0], q1 = qp[1];
#pragma unroll
        for (int j = 0; j < 8; j++) { qf[j] = bf2f(q0[j]); qf[8 + j] = bf2f(q1[j]); }
    }
    float m = 0.f, den = 0.f;
    float acc[16] = {};

    bool act0 = es < cnt;
    int col0 = act0 ? csr_col[c0 + es] : 0;
    bool act1 = (8 + es) < cnt;
    int col1 = act1 ? csr_col[c0 + 8 + es] : 0;
    const int4* p0 = reinterpret_cast<const int4*>(kv + (size_t)col0 * 256 + h * 32);
    int4 kd = p0[0], vd = p0[1];

    for (int base = 0; base < cnt; base += 8) {
        const int4* p1 = reinterpret_cast<const int4*>(kv + (size_t)col1 * 256 + h * 32);
        const int4 nkd = p1[0], nvd = p1[1];
        const bool act2 = (base + 16 + es) < cnt;
        const int col2 = act2 ? csr_col[c0 + base + 16 + es] : 0;

        float kf[16];
        {
            f32x2 r;
            r = __builtin_amdgcn_cvt_pk_f32_fp8(kd.x, false); kf[0] = r[0]; kf[1] = r[1];
            r = __builtin_amdgcn_cvt_pk_f32_fp8(kd.x, true);  kf[2] = r[0]; kf[3] = r[1];
            r = __builtin_amdgcn_cvt_pk_f32_fp8(kd.y, false); kf[4] = r[0]; kf[5] = r[1];
            r = __builtin_amdgcn_cvt_pk_f32_fp8(kd.y, true);  kf[6] = r[0]; kf[7] = r[1];
            r = __builtin_amdgcn_cvt_pk_f32_fp8(kd.z, false); kf[8] = r[0]; kf[9] = r[1];
            r = __builtin_amdgcn_cvt_pk_f32_fp8(kd.z, true);  kf[10] = r[0]; kf[11] = r[1];
            r = __builtin_amdgcn_cvt_pk_f32_fp8(kd.w, false); kf[12] = r[0]; kf[13] = r[1];
            r = __builtin_amdgcn_cvt_pk_f32_fp8(kd.w, true);  kf[14] = r[0]; kf[15] = r[1];
        }
        float dot = 0.f;
#pragma unroll
        for (int j = 0; j < 16; j++) dot += qf[j] * kf[j];
        float sc = act0 ? dot * 0.25f : -INFINITY;  // 1/sqrt(16)
        float cm = sc;
        cm = fmaxf(cm, __shfl_xor(cm, 8));
        cm = fmaxf(cm, __shfl_xor(cm, 16));
        cm = fmaxf(cm, __shfl_xor(cm, 32));
        if (base == 0) {
            m = cm;
        } else if (!__all(cm <= m + 8.f)) {   // defer-max: rescale ~never
            const float nm = fmaxf(m, cm);
            const float s8 = __expf(m - nm);
            den *= s8;
#pragma unroll
            for (int i = 0; i < 16; i++) acc[i] *= s8;
            m = nm;
        }
        const float pp = act0 ? __expf(sc - m) : 0.f;
        den += pp;
        {
            f32x2 r;
            r = __builtin_amdgcn_cvt_pk_f32_fp8(vd.x, false); acc[0] += pp * r[0]; acc[1] += pp * r[1];
            r = __builtin_amdgcn_cvt_pk_f32_fp8(vd.x, true);  acc[2] += pp * r[0]; acc[3] += pp * r[1];
            r = __builtin_amdgcn_cvt_pk_f32_fp8(vd.y, false); acc[4] += pp * r[0]; acc[5] += pp * r[1];
            r = __builtin_amdgcn_cvt_pk_f32_fp8(vd.y, true);  acc[6] += pp * r[0]; acc[7] += pp * r[1];
            r = __builtin_amdgcn_cvt_pk_f32_fp8(vd.z, false); acc[8] += pp * r[0]; acc[9] += pp * r[1];
            r = __builtin_amdgcn_cvt_pk_f32_fp8(vd.z, true);  acc[10] += pp * r[0]; acc[11] += pp * r[1];
            r = __builtin_amdgcn_cvt_pk_f32_fp8(vd.w, false); acc[12] += pp * r[0]; acc[13] += pp * r[1];
            r = __builtin_amdgcn_cvt_pk_f32_fp8(vd.w, true);  acc[14] += pp * r[0]; acc[15] += pp * r[1];
        }
        act0 = act1; act1 = act2; col1 = col2; kd = nkd; vd = nvd;
    }
#pragma unroll
    for (int d = 8; d < 64; d <<= 1) {
        den += __shfl_xor(den, d);
#pragma unroll
        for (int i = 0; i < 16; i++) acc[i] += __shfl_xor(acc[i], d);
    }
    const float inv = 1.f / (den + 1e-9f);
    if (es == 0) {
        unsigned short* ar = agg + (size_t)row * HH + h * DHH;
        u16x8 o0, o1;
#pragma unroll
        for (int j = 0; j < 8; j++) { o0[j] = f2bf(acc[j] * inv); o1[j] = f2bf(acc[8 + j] * inv); }
        reinterpret_cast<u16x8*>(ar)[0] = o0;
        reinterpret_cast<u16x8*>(ar)[1] = o1;
    }
}

// ---------------- K4: fused wo+res+LN2+MLP1+gelu+MLP2+res — weights staged in LDS ----------
__global__ __launch_bounds__(256) void k_tail(
    const unsigned short* __restrict__ aggb, const unsigned short* __restrict__ wop,
    const float* __restrict__ bo, const float* __restrict__ x,
    const float* __restrict__ g2, const float* __restrict__ bl2,
    const unsigned short* __restrict__ w1p, const float* __restrict__ b1,
    const unsigned short* __restrict__ w2p, const float* __restrict__ b2,
    float* __restrict__ out) {
    __shared__ unsigned short aT[64 * 128];   // 16 KB: agg tile, then hn tile
    __shared__ unsigned short tT[64 * 256];   // 32 KB: gelu(mlp1)
    __shared__ unsigned short wbuf[16384];    // 32 KB: current weight panel
    const int t = threadIdx.x;
    const int rb = blockIdx.x * 64;
    const int w = t >> 6, l = t & 63;
    const int m0 = w * 16, lr = l & 15, lg = l >> 4;
    const int row = m0 + lr;

    {
        const int r = t >> 2, qd = t & 3;
        const u16x8* src = reinterpret_cast<const u16x8*>(aggb + (size_t)(rb + r) * HH) + qd * 4;
#pragma unroll
        for (int c = 0; c < 4; c++) {
            const int uoff = (r * 128 + qd * 32 + c * 8) ^ ((r & 7) << 3);
            *reinterpret_cast<u16x8*>(&aT[uoff]) = src[c];
        }
#pragma unroll
        for (int i = 0; i < 8; i++) {
            const int off = i * 2048 + t * 8;
            *reinterpret_cast<u16x8*>(&wbuf[off]) = *reinterpret_cast<const u16x8*>(wop + off);
        }
    }
    __syncthreads();

    // ---- agg @ wo (B from LDS) ----
    bf16x8 a[4];
#pragma unroll
    for (int kc = 0; kc < 4; kc++)
        a[kc] = *reinterpret_cast<const bf16x8*>(&aT[(row * 128 + kc * 32 + lg * 8) ^ ((row & 7) << 3)]);
    f32x4 acc[8];
#pragma unroll
    for (int g8 = 0; g8 < 8; g8++) acc[g8] = (f32x4){0.f, 0.f, 0.f, 0.f};
#pragma unroll
    for (int g8 = 0; g8 < 8; g8++)
#pragma unroll
        for (int kc = 0; kc < 4; kc++)
            acc[g8] = __builtin_amdgcn_mfma_f32_16x16x32_bf16(
                a[kc],
                *reinterpret_cast<const bf16x8*>(&wbuf[(((kc << 2) + lg) * 128 + g8 * 16 + lr) << 3]),
                acc[g8], 0, 0, 0);
    float hv[8][4];
#pragma unroll
    for (int g8 = 0; g8 < 8; g8++) {
        const float bias = bo[g8 * 16 + lr];
#pragma unroll
        for (int j = 0; j < 4; j++)
            hv[g8][j] = acc[g8][j] + bias + x[(size_t)(rb + m0 + 4 * lg + j) * HH + g8 * 16 + lr];
    }
    // ---- LN2 ----
    float mu[4], rs[4];
#pragma unroll
    for (int j = 0; j < 4; j++) {
        float s = 0.f, ss = 0.f;
#pragma unroll
        for (int g8 = 0; g8 < 8; g8++) { const float hh = hv[g8][j]; s += hh; ss += hh * hh; }
        s += __shfl_xor(s, 1); s += __shfl_xor(s, 2); s += __shfl_xor(s, 4); s += __shfl_xor(s, 8);
        ss += __shfl_xor(ss, 1); ss += __shfl_xor(ss, 2); ss += __shfl_xor(ss, 4); ss += __shfl_xor(ss, 8);
        mu[j] = s * (1.f / HH);
        rs[j] = rsqrtf(ss * (1.f / HH) - mu[j] * mu[j] + LNEPS);
    }
    __syncthreads();
#pragma unroll
    for (int g8 = 0; g8 < 8; g8++) {
        const float gg = g2[g8 * 16 + lr], bb = bl2[g8 * 16 + lr];
#pragma unroll
        for (int j = 0; j < 4; j++) {
            const int i = m0 + 4 * lg + j;
            aT[(i * 128 + g8 * 16 + lr) ^ ((i & 7) << 3)] = f2bf((hv[g8][j] - mu[j]) * rs[j] * gg + bb);
        }
    }
#pragma unroll
    for (int i = 0; i < 8; i++) {
        const int off = i * 2048 + t * 8;
        const int k8 = off >> 10, rem = off & 1023;
        *reinterpret_cast<u16x8*>(&wbuf[off]) = *reinterpret_cast<const u16x8*>(w1p + (k8 << 11) + rem);
    }
    __syncthreads();
    bf16x8 a2[4];
#pragma unroll
    for (int kc = 0; kc < 4; kc++)
        a2[kc] = *reinterpret_cast<const bf16x8*>(&aT[(row * 128 + kc * 32 + lg * 8) ^ ((row & 7) << 3)]);

    // ---- mlp1 in two N-halves ----
#pragma unroll 1
    for (int half = 0; half < 2; half++) {
#pragma unroll 1
        for (int Gl = 0; Gl < 8; Gl++) {
            const int G = half * 8 + Gl;
            f32x4 a1 = (f32x4){0.f, 0.f, 0.f, 0.f};
#pragma unroll
            for (int kc = 0; kc < 4; kc++)
                a1 = __builtin_amdgcn_mfma_f32_16x16x32_bf16(
                    a2[kc],
                    *reinterpret_cast<const bf16x8*>(&wbuf[(((kc << 2) + lg) * 128 + Gl * 16 + lr) << 3]),
                    a1, 0, 0, 0);
            const float bias = b1[G * 16 + lr];
#pragma unroll
            for (int j = 0; j < 4; j++) {
                const int i = m0 + 4 * lg + j;
                tT[(i * 256 + G * 16 + lr) ^ ((i & 7) << 3)] = f2bf(gelu_tanh(a1[j] + bias));
            }
        }
        __syncthreads();
        if (half == 0) {
#pragma unroll
            for (int i = 0; i < 8; i++) {
                const int off = i * 2048 + t * 8;
                const int k8 = off >> 10, rem = off & 1023;
                *reinterpret_cast<u16x8*>(&wbuf[off]) = *reinterpret_cast<const u16x8*>(w1p + (k8 << 11) + 1024 + rem);
            }
        } else {
#pragma unroll
            for (int i = 0; i < 8; i++) {
                const int off = i * 2048 + t * 8;
                *reinterpret_cast<u16x8*>(&wbuf[off]) = *reinterpret_cast<const u16x8*>(w2p + off);
            }
        }
        __syncthreads();
    }
    // ---- mlp2 in two K-halves ----
    f32x4 acc2[8];
#pragma unroll
    for (int g8 = 0; g8 < 8; g8++) acc2[g8] = (f32x4){0.f, 0.f, 0.f, 0.f};
#pragma unroll 1
    for (int half = 0; half < 2; half++) {
        bf16x8 a3[4];
#pragma unroll
        for (int kc = 0; kc < 4; kc++)
            a3[kc] = *reinterpret_cast<const bf16x8*>(&tT[(row * 256 + half * 128 + kc * 32 + lg * 8) ^ ((row & 7) << 3)]);
#pragma unroll 1
        for (int g8 = 0; g8 < 8; g8++)
#pragma unroll
            for (int kc = 0; kc < 4; kc++)
                acc2[g8] = __builtin_amdgcn_mfma_f32_16x16x32_bf16(
                    a3[kc],
                    *reinterpret_cast<const bf16x8*>(&wbuf[(((kc << 2) + lg) * 128 + g8 * 16 + lr) << 3]),
                    acc2[g8], 0, 0, 0);
        if (half == 0) {
            __syncthreads();
#pragma unroll
            for (int i = 0; i < 8; i++) {
                const int off = i * 2048 + t * 8;
                *reinterpret_cast<u16x8*>(&wbuf[off]) = *reinterpret_cast<const u16x8*>(w2p + 16384 + off);
            }
            __syncthreads();
        }
    }
#pragma unroll
    for (int g8 = 0; g8 < 8; g8++) {
        const float bias = b2[g8 * 16 + lr];
#pragma unroll
        for (int j = 0; j < 4; j++)
            out[(size_t)(rb + m0 + 4 * lg + j) * HH + g8 * 16 + lr] = hv[g8][j] + acc2[g8][j] + bias;
    }
}

extern "C" void kernel_launch(void* const* d_in, const int* in_sizes, int n_in,
                              void* d_out, int out_size, void* d_ws, size_t ws_size,
                              hipStream_t stream) {
    const float* x = (const float*)d_in[0];
    const int* erow = (const int*)d_in[1];
    const int* ecol = (const int*)d_in[2];
    const float* ln1g = (const float*)d_in[3];
    const float* ln1b = (const float*)d_in[4];
    const float* wq = (const float*)d_in[5];
    const float* bq = (const float*)d_in[6];
    const float* wk = (const float*)d_in[7];
    const float* bk = (const float*)d_in[8];
    const float* wv = (const float*)d_in[9];
    const float* bv = (const float*)d_in[10];
    const float* wo = (const float*)d_in[11];
    const float* bo = (const float*)d_in[12];
    const float* ln2g = (const float*)d_in[13];
    const float* ln2b = (const float*)d_in[14];
    const float* w1 = (const float*)d_in[15];
    const float* b1 = (const float*)d_in[16];
    const float* w2 = (const float*)d_in[17];
    const float* b2 = (const float*)d_in[18];
    float* out = (float*)d_out;

    unsigned short* qb = (unsigned short*)d_ws;                        // NN*128 ushort (16 MB)
    unsigned char* kv8 = (unsigned char*)(qb + (size_t)NN * HH);       // NN*256 bytes (16 MB)
    unsigned short* aggb = (unsigned short*)(kv8 + (size_t)NN * 256);  // NN*128 ushort (16 MB)
    unsigned short* wpack = aggb + (size_t)NN * HH;                    // 131072 ushorts (256 KB)
    int* offs = (int*)(wpack + 131072);                                // NN+1 ints
    int* csr_col = offs + NN + 1;                                      // NE ints (4 MB)
    int* gcur = csr_col + NE;                                          // NB ints
    int* bexcl = gcur + NB;                                            // NB ints
    unsigned long long* pairs = (unsigned long long*)(bexcl + NB + 2); // NB*BCAP (12 MB)

    hipMemsetAsync(gcur, 0, NB * sizeof(int), stream);
    k_pack<<<512, 256, 0, stream>>>(wq, wk, wv, wo, w1, w2, wpack);
    k_bin<<<NE / 4096, 256, 0, stream>>>(erow, ecol, gcur, pairs);
    k_scanb<<<1, 256, 0, stream>>>(gcur, bexcl);
    k_build<<<NB, 256, 0, stream>>>(pairs, gcur, bexcl, offs, csr_col);
    k_ln_qkv<<<NN / 128, 256, 0, stream>>>(x, ln1g, ln1b, wpack, bq, bk, bv, qb, kv8);
    k_attn<<<NN / 4, 256, 0, stream>>>(qb, kv8, offs, csr_col, aggb);
    k_tail<<<NN / 64, 256, 0, stream>>>(aggb, wpack + 49152, bo, x, ln2g, ln2b,
                                        wpack + 65536, b1, wpack + 98304, b2, out);
}

// Round 13
// 158.050 us; speedup vs baseline: 2.2096x; 1.0655x over previous
//
#include <hip/hip_runtime.h>
#include <math.h>

#define NN 65536
#define HH 128
#define DHH 16
#define NE 1048576
#define HID 256
#define LNEPS 1e-5f
#define NB 256      // buckets for CSR build
#define BCAP 6144   // max edges per bucket (mean 4096, sd 64 -> +32 sd)

typedef __attribute__((ext_vector_type(8))) short bf16x8;
typedef __attribute__((ext_vector_type(8))) unsigned short u16x8;
typedef __attribute__((ext_vector_type(4))) float f32x4;
typedef __attribute__((ext_vector_type(2))) float f32x2;

static __device__ __forceinline__ unsigned short f2bf(float f) {
    union { float f; unsigned u; } c; c.f = f;
    unsigned r = c.u + 0x7fffu + ((c.u >> 16) & 1u);
    return (unsigned short)(r >> 16);
}
static __device__ __forceinline__ float bf2f(unsigned short u) {
    union { unsigned u; float f; } c; c.u = ((unsigned)u) << 16;
    return c.f;
}
// gelu_tanh(x) = 0.5x(1+tanh(c(x+0.044715x^3))) == x*sigmoid(2c(x+0.044715x^3))
static __device__ __forceinline__ float gelu_tanh(float x) {
    const float a = -2.302225282f;  // -2*log2(e)*0.7978845608
    const float u = a * (x + 0.044715f * x * x * x);
    const float e = __builtin_amdgcn_exp2f(u);
    return x * __builtin_amdgcn_rcpf(1.f + e);
}

// ---------------- CSR build: two-level bucket sort (no random global writes) ----------------
__global__ __launch_bounds__(256) void k_bin(const int* __restrict__ er, const int* __restrict__ ec,
                                             int* __restrict__ gcur, unsigned long long* __restrict__ pairs) {
    __shared__ int cnt[NB];
    __shared__ int cur[NB];
    __shared__ int base[NB];
    const int t = threadIdx.x;
    const int e0 = blockIdx.x * 4096;
    cnt[t] = 0;
    __syncthreads();
    int rows[16], cols[16];
#pragma unroll
    for (int i = 0; i < 16; i++) {
        const int e = e0 + i * 256 + t;
        rows[i] = er[e];
        cols[i] = ec[e];
        atomicAdd(&cnt[rows[i] >> 8], 1);
    }
    __syncthreads();
    if (cnt[t] > 0) base[t] = atomicAdd(&gcur[t], cnt[t]);
    cur[t] = 0;
    __syncthreads();
#pragma unroll
    for (int i = 0; i < 16; i++) {
        const int b = rows[i] >> 8;
        const int slot = atomicAdd(&cur[b], 1);
        pairs[(size_t)b * BCAP + base[b] + slot] =
            ((unsigned long long)rows[i] << 32) | (unsigned)cols[i];
    }
}

__global__ __launch_bounds__(256) void k_scanb(const int* __restrict__ gcur, int* __restrict__ bexcl) {
    __shared__ int sc[NB];
    const int t = threadIdx.x;
    const int v = gcur[t];
    sc[t] = v;
    __syncthreads();
    for (int d = 1; d < NB; d <<= 1) {
        int vv = (t >= d) ? sc[t - d] : 0;
        __syncthreads();
        sc[t] += vv;
        __syncthreads();
    }
    bexcl[t] = sc[t] - v;
}

__global__ __launch_bounds__(256) void k_build(const unsigned long long* __restrict__ pairs,
                                               const int* __restrict__ gcur, const int* __restrict__ bexcl,
                                               int* __restrict__ offs, int* __restrict__ csr_col) {
    __shared__ int cnt[256];
    __shared__ int sc[256];
    __shared__ int cur[256];
    __shared__ int colbuf[BCAP];
    const int b = blockIdx.x, t = threadIdx.x;
    const int tot = gcur[b];
    const int cbase = bexcl[b];
    const unsigned long long* bp = pairs + (size_t)b * BCAP;
    cnt[t] = 0;
    __syncthreads();
    for (int i = t; i < tot; i += 256) {
        const unsigned long long u = bp[i];
        atomicAdd(&cnt[(int)(u >> 32) & 255], 1);
    }
    __syncthreads();
    sc[t] = cnt[t];
    __syncthreads();
    for (int d = 1; d < 256; d <<= 1) {
        int vv = (t >= d) ? sc[t - d] : 0;
        __syncthreads();
        sc[t] += vv;
        __syncthreads();
    }
    const int excl = sc[t] - cnt[t];
    offs[b * 256 + t] = cbase + excl;
    cur[t] = excl;
    if (b == NB - 1 && t == 255) offs[NN] = NE;
    __syncthreads();
    for (int i = t; i < tot; i += 256) {
        const unsigned long long u = bp[i];
        const int r = (int)(u >> 32) & 255;
        const int p = atomicAdd(&cur[r], 1);
        colbuf[p] = (int)(unsigned)u;
    }
    __syncthreads();
    for (int i = t; i < tot; i += 256) csr_col[cbase + i] = colbuf[i];
}

// ---------------- weight pack: fp32 W[K][N] -> bf16 Wp[(k>>3)*N + n][8] ----------------
__global__ __launch_bounds__(256) void k_pack(
    const float* __restrict__ wq, const float* __restrict__ wk, const float* __restrict__ wv,
    const float* __restrict__ wo, const float* __restrict__ w1, const float* __restrict__ w2,
    unsigned short* __restrict__ p) {
    const int b = blockIdx.x, t = threadIdx.x;
    const float* src; unsigned short* dst; int N, idx;
    if (b < 64)       { src = wq; dst = p;          N = 128; idx = b * 256 + t; }
    else if (b < 128) { src = wk; dst = p + 16384;  N = 128; idx = (b - 64) * 256 + t; }
    else if (b < 192) { src = wv; dst = p + 32768;  N = 128; idx = (b - 128) * 256 + t; }
    else if (b < 256) { src = wo; dst = p + 49152;  N = 128; idx = (b - 192) * 256 + t; }
    else if (b < 384) { src = w1; dst = p + 65536;  N = 256; idx = (b - 256) * 256 + t; }
    else              { src = w2; dst = p + 98304;  N = 128; idx = (b - 384) * 256 + t; }
    const int k = idx / N, n = idx % N;
    dst[(((k >> 3) * N + n) << 3) + (k & 7)] = f2bf(src[idx]);
}

// ---------------- K1: LN1 + QKV (MFMA bf16, weights staged in LDS) ----------
__global__ __launch_bounds__(256) void k_ln_qkv(
    const float* __restrict__ x, const float* __restrict__ g, const float* __restrict__ bl,
    const unsigned short* __restrict__ wp /* wq|wk|wv packed, 3*16384 */,
    const float* __restrict__ bq, const float* __restrict__ bk, const float* __restrict__ bv,
    unsigned short* __restrict__ qo, unsigned char* __restrict__ kv8) {
    __shared__ unsigned short aT[128 * 128];  // 32 KB
    __shared__ unsigned short wbuf[16384];    // 32 KB
    const int t = threadIdx.x;
    const int rb = blockIdx.x * 128;
    const int w = t >> 6, l = t & 63;
    {
        const int sr0 = w * 32 + (l >> 2), qd = l & 3;
#pragma unroll 1
        for (int rr = 0; rr < 2; rr++) {
            const int row = sr0 + rr * 16;
            const float4* xr = reinterpret_cast<const float4*>(x + (size_t)(rb + row) * HH) + qd * 8;
            float xa[32]; float s = 0.f, ss = 0.f;
#pragma unroll
            for (int i = 0; i < 8; i++) {
                float4 v4 = xr[i];
                xa[i * 4 + 0] = v4.x; xa[i * 4 + 1] = v4.y; xa[i * 4 + 2] = v4.z; xa[i * 4 + 3] = v4.w;
                s += v4.x + v4.y + v4.z + v4.w;
                ss += v4.x * v4.x + v4.y * v4.y + v4.z * v4.z + v4.w * v4.w;
            }
            s += __shfl_xor(s, 1); s += __shfl_xor(s, 2);
            ss += __shfl_xor(ss, 1); ss += __shfl_xor(ss, 2);
            const float mu = s * (1.f / HH);
            const float rs = rsqrtf(ss * (1.f / HH) - mu * mu + LNEPS);
#pragma unroll
            for (int c = 0; c < 4; c++) {
                u16x8 w8;
#pragma unroll
                for (int j2 = 0; j2 < 8; j2++) {
                    const int d = qd * 32 + c * 8 + j2;
                    w8[j2] = f2bf((xa[c * 8 + j2] - mu) * rs * g[d] + bl[d]);
                }
                const int uoff = (row * 128 + qd * 32 + c * 8) ^ ((row & 7) << 3);
                *reinterpret_cast<u16x8*>(&aT[uoff]) = w8;
            }
        }
#pragma unroll
        for (int i = 0; i < 8; i++) {
            const int off = i * 2048 + t * 8;
            *reinterpret_cast<u16x8*>(&wbuf[off]) = *reinterpret_cast<const u16x8*>(wp + off);
        }
    }
    __syncthreads();
    const int lr = l & 15, lg = l >> 4;
    const int row0 = w * 32 + lr;
    const int row1 = w * 32 + 16 + lr;
    bf16x8 a0[4], a1[4];
#pragma unroll
    for (int kc = 0; kc < 4; kc++) {
        a0[kc] = *reinterpret_cast<const bf16x8*>(&aT[(row0 * 128 + kc * 32 + lg * 8) ^ ((row0 & 7) << 3)]);
        a1[kc] = *reinterpret_cast<const bf16x8*>(&aT[(row1 * 128 + kc * 32 + lg * 8) ^ ((row1 & 7) << 3)]);
    }

#pragma unroll 1
    for (int m = 0; m < 3; m++) {
        const float* Bb = (m == 0) ? bq : (m == 1) ? bk : bv;
        f32x4 ac0[8], ac1[8];
#pragma unroll
        for (int g8 = 0; g8 < 8; g8++) { ac0[g8] = (f32x4){0.f,0.f,0.f,0.f}; ac1[g8] = (f32x4){0.f,0.f,0.f,0.f}; }
#pragma unroll
        for (int g8 = 0; g8 < 8; g8++)
#pragma unroll
            for (int kc = 0; kc < 4; kc++) {
                const bf16x8 bfr = *reinterpret_cast<const bf16x8*>(&wbuf[(((kc << 2) + lg) * 128 + g8 * 16 + lr) << 3]);
                ac0[g8] = __builtin_amdgcn_mfma_f32_16x16x32_bf16(a0[kc], bfr, ac0[g8], 0, 0, 0);
                ac1[g8] = __builtin_amdgcn_mfma_f32_16x16x32_bf16(a1[kc], bfr, ac1[g8], 0, 0, 0);
            }
        __syncthreads();
        if (m < 2) {
            const unsigned short* nsrc = wp + (m + 1) * 16384;
#pragma unroll
            for (int i = 0; i < 8; i++) {
                const int off = i * 2048 + t * 8;
                *reinterpret_cast<u16x8*>(&wbuf[off]) = *reinterpret_cast<const u16x8*>(nsrc + off);
            }
        }
#pragma unroll
        for (int g8 = 0; g8 < 8; g8++) {
            const float bias = Bb[g8 * 16 + lr];
#pragma unroll
            for (int j = 0; j < 4; j++) {
                const int ra = rb + w * 32 + 4 * lg + j;
                const int rbb = ra + 16;
                const float y0 = ac0[g8][j] + bias, y1 = ac1[g8][j] + bias;
                if (m == 0) {
                    qo[(size_t)ra * HH + g8 * 16 + lr] = f2bf(y0);
                    qo[(size_t)rbb * HH + g8 * 16 + lr] = f2bf(y1);
                } else {
                    const int off = g8 * 32 + lr + ((m == 2) ? 16 : 0);
                    const int pk0 = __builtin_amdgcn_cvt_pk_fp8_f32(y0, y0, 0, false);
                    const int pk1 = __builtin_amdgcn_cvt_pk_fp8_f32(y1, y1, 0, false);
                    kv8[(size_t)ra * 256 + off] = (unsigned char)(pk0 & 0xff);
                    kv8[(size_t)rbb * 256 + off] = (unsigned char)(pk1 & 0xff);
                }
            }
        }
        if (m < 2) __syncthreads();
    }
}

// ---------------- K3: fused SDDMM + softmax + SpMM ----------------
// 8 lanes per row (lane = r8*8 + h): lane-local online softmax — zero shuffles.
// Per edge: 8 lanes read one contiguous 256B kv line; epilogue fully coalesced.
__global__ __launch_bounds__(256) void k_attn(
    const unsigned short* __restrict__ q, const unsigned char* __restrict__ kv,
    const int* __restrict__ offs, const int* __restrict__ csr_col,
    unsigned short* __restrict__ agg) {
    const int wave = threadIdx.x >> 6;
    const int lane = threadIdx.x & 63;
    const int r8 = lane >> 3, h = lane & 7;
    const int row = blockIdx.x * 32 + wave * 8 + r8;
    const int c0 = offs[row];
    const int cnt = offs[row + 1] - c0;

    // wave-max iteration count (one-time, 3 shuffles)
    int mx = cnt;
#pragma unroll
    for (int d = 8; d < 64; d <<= 1) mx = max(mx, __shfl_xor(mx, d));

    float qf[16];
    {
        const u16x8* qp = reinterpret_cast<const u16x8*>(q + (size_t)row * HH + h * DHH);
        u16x8 q0 = qp[0], q1 = qp[1];
#pragma unroll
        for (int j = 0; j < 8; j++) { qf[j] = bf2f(q0[j]); qf[8 + j] = bf2f(q1[j]); }
    }
    float m = 0.f, den = 0.f;
    float acc[16] = {};

    // 2-deep prologue
    bool a0 = 0 < cnt;
    int col0 = a0 ? csr_col[c0] : 0;
    int col1 = (1 < cnt) ? csr_col[c0 + 1] : 0;
    const int4* p0 = reinterpret_cast<const int4*>(kv + (size_t)col0 * 256 + h * 32);
    int4 kd = p0[0], vd = p0[1];

    for (int e = 0; e < mx; e++) {
        // prefetch: kv for edge e+1 (col resident), col for edge e+2
        const int4* p1 = reinterpret_cast<const int4*>(kv + (size_t)col1 * 256 + h * 32);
        const int4 nkd = p1[0], nvd = p1[1];
        const int col2 = ((e + 2) < cnt) ? csr_col[c0 + e + 2] : 0;

        const bool act = e < cnt;
        float kf[16];
        {
            f32x2 r;
            r = __builtin_amdgcn_cvt_pk_f32_fp8(kd.x, false); kf[0] = r[0]; kf[1] = r[1];
            r = __builtin_amdgcn_cvt_pk_f32_fp8(kd.x, true);  kf[2] = r[0]; kf[3] = r[1];
            r = __builtin_amdgcn_cvt_pk_f32_fp8(kd.y, false); kf[4] = r[0]; kf[5] = r[1];
            r = __builtin_amdgcn_cvt_pk_f32_fp8(kd.y, true);  kf[6] = r[0]; kf[7] = r[1];
            r = __builtin_amdgcn_cvt_pk_f32_fp8(kd.z, false); kf[8] = r[0]; kf[9] = r[1];
            r = __builtin_amdgcn_cvt_pk_f32_fp8(kd.z, true);  kf[10] = r[0]; kf[11] = r[1];
            r = __builtin_amdgcn_cvt_pk_f32_fp8(kd.w, false); kf[12] = r[0]; kf[13] = r[1];
            r = __builtin_amdgcn_cvt_pk_f32_fp8(kd.w, true);  kf[14] = r[0]; kf[15] = r[1];
        }
        float dot = 0.f;
#pragma unroll
        for (int j = 0; j < 16; j++) dot += qf[j] * kf[j];
        const float sc = act ? dot * 0.25f : -1e30f;  // finite sentinel (no NaN paths)
        if (e == 0) {
            m = sc;
        } else if (!__all(sc <= m + 8.f)) {   // defer-max: rescale ~never
            const float nm = fmaxf(m, sc);
            const float s8 = __expf(m - nm);
            den *= s8;
#pragma unroll
            for (int i = 0; i < 16; i++) acc[i] *= s8;
            m = nm;
        }
        const float pp = act ? __expf(sc - m) : 0.f;
        den += pp;
        {
            f32x2 r;
            r = __builtin_amdgcn_cvt_pk_f32_fp8(vd.x, false); acc[0] += pp * r[0]; acc[1] += pp * r[1];
            r = __builtin_amdgcn_cvt_pk_f32_fp8(vd.x, true);  acc[2] += pp * r[0]; acc[3] += pp * r[1];
            r = __builtin_amdgcn_cvt_pk_f32_fp8(vd.y, false); acc[4] += pp * r[0]; acc[5] += pp * r[1];
            r = __builtin_amdgcn_cvt_pk_f32_fp8(vd.y, true);  acc[6] += pp * r[0]; acc[7] += pp * r[1];
            r = __builtin_amdgcn_cvt_pk_f32_fp8(vd.z, false); acc[8] += pp * r[0]; acc[9] += pp * r[1];
            r = __builtin_amdgcn_cvt_pk_f32_fp8(vd.z, true);  acc[10] += pp * r[0]; acc[11] += pp * r[1];
            r = __builtin_amdgcn_cvt_pk_f32_fp8(vd.w, false); acc[12] += pp * r[0]; acc[13] += pp * r[1];
            r = __builtin_amdgcn_cvt_pk_f32_fp8(vd.w, true);  acc[14] += pp * r[0]; acc[15] += pp * r[1];
        }
        col1 = col2; kd = nkd; vd = nvd;
    }
    const float inv = 1.f / (den + 1e-9f);
    unsigned short* ar = agg + (size_t)row * HH + h * DHH;
    u16x8 o0, o1;
#pragma unroll
    for (int j = 0; j < 8; j++) { o0[j] = f2bf(acc[j] * inv); o1[j] = f2bf(acc[8 + j] * inv); }
    reinterpret_cast<u16x8*>(ar)[0] = o0;
    reinterpret_cast<u16x8*>(ar)[1] = o1;
}

// ---------------- K4: fused wo+res+LN2+MLP1+gelu+MLP2+res — weights staged in LDS ----------
__global__ __launch_bounds__(256) void k_tail(
    const unsigned short* __restrict__ aggb, const unsigned short* __restrict__ wop,
    const float* __restrict__ bo, const float* __restrict__ x,
    const float* __restrict__ g2, const float* __restrict__ bl2,
    const unsigned short* __restrict__ w1p, const float* __restrict__ b1,
    const unsigned short* __restrict__ w2p, const float* __restrict__ b2,
    float* __restrict__ out) {
    __shared__ unsigned short aT[64 * 128];   // 16 KB: agg tile, then hn tile
    __shared__ unsigned short tT[64 * 256];   // 32 KB: gelu(mlp1)
    __shared__ unsigned short wbuf[16384];    // 32 KB: current weight panel
    const int t = threadIdx.x;
    const int rb = blockIdx.x * 64;
    const int w = t >> 6, l = t & 63;
    const int m0 = w * 16, lr = l & 15, lg = l >> 4;
    const int row = m0 + lr;

    {
        const int r = t >> 2, qd = t & 3;
        const u16x8* src = reinterpret_cast<const u16x8*>(aggb + (size_t)(rb + r) * HH) + qd * 4;
#pragma unroll
        for (int c = 0; c < 4; c++) {
            const int uoff = (r * 128 + qd * 32 + c * 8) ^ ((r & 7) << 3);
            *reinterpret_cast<u16x8*>(&aT[uoff]) = src[c];
        }
#pragma unroll
        for (int i = 0; i < 8; i++) {
            const int off = i * 2048 + t * 8;
            *reinterpret_cast<u16x8*>(&wbuf[off]) = *reinterpret_cast<const u16x8*>(wop + off);
        }
    }
    __syncthreads();

    // ---- agg @ wo (B from LDS) ----
    bf16x8 a[4];
#pragma unroll
    for (int kc = 0; kc < 4; kc++)
        a[kc] = *reinterpret_cast<const bf16x8*>(&aT[(row * 128 + kc * 32 + lg * 8) ^ ((row & 7) << 3)]);
    f32x4 acc[8];
#pragma unroll
    for (int g8 = 0; g8 < 8; g8++) acc[g8] = (f32x4){0.f, 0.f, 0.f, 0.f};
#pragma unroll
    for (int g8 = 0; g8 < 8; g8++)
#pragma unroll
        for (int kc = 0; kc < 4; kc++)
            acc[g8] = __builtin_amdgcn_mfma_f32_16x16x32_bf16(
                a[kc],
                *reinterpret_cast<const bf16x8*>(&wbuf[(((kc << 2) + lg) * 128 + g8 * 16 + lr) << 3]),
                acc[g8], 0, 0, 0);
    float hv[8][4];
#pragma unroll
    for (int g8 = 0; g8 < 8; g8++) {
        const float bias = bo[g8 * 16 + lr];
#pragma unroll
        for (int j = 0; j < 4; j++)
            hv[g8][j] = acc[g8][j] + bias + x[(size_t)(rb + m0 + 4 * lg + j) * HH + g8 * 16 + lr];
    }
    // ---- LN2 ----
    float mu[4], rs[4];
#pragma unroll
    for (int j = 0; j < 4; j++) {
        float s = 0.f, ss = 0.f;
#pragma unroll
        for (int g8 = 0; g8 < 8; g8++) { const float hh = hv[g8][j]; s += hh; ss += hh * hh; }
        s += __shfl_xor(s, 1); s += __shfl_xor(s, 2); s += __shfl_xor(s, 4); s += __shfl_xor(s, 8);
        ss += __shfl_xor(ss, 1); ss += __shfl_xor(ss, 2); ss += __shfl_xor(ss, 4); ss += __shfl_xor(ss, 8);
        mu[j] = s * (1.f / HH);
        rs[j] = rsqrtf(ss * (1.f / HH) - mu[j] * mu[j] + LNEPS);
    }
    __syncthreads();
#pragma unroll
    for (int g8 = 0; g8 < 8; g8++) {
        const float gg = g2[g8 * 16 + lr], bb = bl2[g8 * 16 + lr];
#pragma unroll
        for (int j = 0; j < 4; j++) {
            const int i = m0 + 4 * lg + j;
            aT[(i * 128 + g8 * 16 + lr) ^ ((i & 7) << 3)] = f2bf((hv[g8][j] - mu[j]) * rs[j] * gg + bb);
        }
    }
#pragma unroll
    for (int i = 0; i < 8; i++) {
        const int off = i * 2048 + t * 8;
        const int k8 = off >> 10, rem = off & 1023;
        *reinterpret_cast<u16x8*>(&wbuf[off]) = *reinterpret_cast<const u16x8*>(w1p + (k8 << 11) + rem);
    }
    __syncthreads();
    bf16x8 a2[4];
#pragma unroll
    for (int kc = 0; kc < 4; kc++)
        a2[kc] = *reinterpret_cast<const bf16x8*>(&aT[(row * 128 + kc * 32 + lg * 8) ^ ((row & 7) << 3)]);

    // ---- mlp1 in two N-halves ----
#pragma unroll 1
    for (int half = 0; half < 2; half++) {
#pragma unroll 1
        for (int Gl = 0; Gl < 8; Gl++) {
            const int G = half * 8 + Gl;
            f32x4 a1 = (f32x4){0.f, 0.f, 0.f, 0.f};
#pragma unroll
            for (int kc = 0; kc < 4; kc++)
                a1 = __builtin_amdgcn_mfma_f32_16x16x32_bf16(
                    a2[kc],
                    *reinterpret_cast<const bf16x8*>(&wbuf[(((kc << 2) + lg) * 128 + Gl * 16 + lr) << 3]),
                    a1, 0, 0, 0);
            const float bias = b1[G * 16 + lr];
#pragma unroll
            for (int j = 0; j < 4; j++) {
                const int i = m0 + 4 * lg + j;
                tT[(i * 256 + G * 16 + lr) ^ ((i & 7) << 3)] = f2bf(gelu_tanh(a1[j] + bias));
            }
        }
        __syncthreads();
        if (half == 0) {
#pragma unroll
            for (int i = 0; i < 8; i++) {
                const int off = i * 2048 + t * 8;
                const int k8 = off >> 10, rem = off & 1023;
                *reinterpret_cast<u16x8*>(&wbuf[off]) = *reinterpret_cast<const u16x8*>(w1p + (k8 << 11) + 1024 + rem);
            }
        } else {
#pragma unroll
            for (int i = 0; i < 8; i++) {
                const int off = i * 2048 + t * 8;
                *reinterpret_cast<u16x8*>(&wbuf[off]) = *reinterpret_cast<const u16x8*>(w2p + off);
            }
        }
        __syncthreads();
    }
    // ---- mlp2 in two K-halves ----
    f32x4 acc2[8];
#pragma unroll
    for (int g8 = 0; g8 < 8; g8++) acc2[g8] = (f32x4){0.f, 0.f, 0.f, 0.f};
#pragma unroll 1
    for (int half = 0; half < 2; half++) {
        bf16x8 a3[4];
#pragma unroll
        for (int kc = 0; kc < 4; kc++)
            a3[kc] = *reinterpret_cast<const bf16x8*>(&tT[(row * 256 + half * 128 + kc * 32 + lg * 8) ^ ((row & 7) << 3)]);
#pragma unroll 1
        for (int g8 = 0; g8 < 8; g8++)
#pragma unroll
            for (int kc = 0; kc < 4; kc++)
                acc2[g8] = __builtin_amdgcn_mfma_f32_16x16x32_bf16(
                    a3[kc],
                    *reinterpret_cast<const bf16x8*>(&wbuf[(((kc << 2) + lg) * 128 + g8 * 16 + lr) << 3]),
                    acc2[g8], 0, 0, 0);
        if (half == 0) {
            __syncthreads();
#pragma unroll
            for (int i = 0; i < 8; i++) {
                const int off = i * 2048 + t * 8;
                *reinterpret_cast<u16x8*>(&wbuf[off]) = *reinterpret_cast<const u16x8*>(w2p + 16384 + off);
            }
            __syncthreads();
        }
    }
#pragma unroll
    for (int g8 = 0; g8 < 8; g8++) {
        const float bias = b2[g8 * 16 + lr];
#pragma unroll
        for (int j = 0; j < 4; j++)
            out[(size_t)(rb + m0 + 4 * lg + j) * HH + g8 * 16 + lr] = hv[g8][j] + acc2[g8][j] + bias;
    }
}

extern "C" void kernel_launch(void* const* d_in, const int* in_sizes, int n_in,
                              void* d_out, int out_size, void* d_ws, size_t ws_size,
                              hipStream_t stream) {
    const float* x = (const float*)d_in[0];
    const int* erow = (const int*)d_in[1];
    const int* ecol = (const int*)d_in[2];
    const float* ln1g = (const float*)d_in[3];
    const float* ln1b = (const float*)d_in[4];
    const float* wq = (const float*)d_in[5];
    const float* bq = (const float*)d_in[6];
    const float* wk = (const float*)d_in[7];
    const float* bk = (const float*)d_in[8];
    const float* wv = (const float*)d_in[9];
    const float* bv = (const float*)d_in[10];
    const float* wo = (const float*)d_in[11];
    const float* bo = (const float*)d_in[12];
    const float* ln2g = (const float*)d_in[13];
    const float* ln2b = (const float*)d_in[14];
    const float* w1 = (const float*)d_in[15];
    const float* b1 = (const float*)d_in[16];
    const float* w2 = (const float*)d_in[17];
    const float* b2 = (const float*)d_in[18];
    float* out = (float*)d_out;

    unsigned short* qb = (unsigned short*)d_ws;                        // NN*128 ushort (16 MB)
    unsigned char* kv8 = (unsigned char*)(qb + (size_t)NN * HH);       // NN*256 bytes (16 MB)
    unsigned short* aggb = (unsigned short*)(kv8 + (size_t)NN * 256);  // NN*128 ushort (16 MB)
    unsigned short* wpack = aggb + (size_t)NN * HH;                    // 131072 ushorts (256 KB)
    int* offs = (int*)(wpack + 131072);                                // NN+1 ints
    int* csr_col = offs + NN + 1;                                      // NE ints (4 MB)
    int* gcur = csr_col + NE;                                          // NB ints
    int* bexcl = gcur + NB;                                            // NB ints
    unsigned long long* pairs = (unsigned long long*)(bexcl + NB + 2); // NB*BCAP (12 MB)

    hipMemsetAsync(gcur, 0, NB * sizeof(int), stream);
    k_pack<<<512, 256, 0, stream>>>(wq, wk, wv, wo, w1, w2, wpack);
    k_bin<<<NE / 4096, 256, 0, stream>>>(erow, ecol, gcur, pairs);
    k_scanb<<<1, 256, 0, stream>>>(gcur, bexcl);
    k_build<<<NB, 256, 0, stream>>>(pairs, gcur, bexcl, offs, csr_col);
    k_ln_qkv<<<NN / 128, 256, 0, stream>>>(x, ln1g, ln1b, wpack, bq, bk, bv, qb, kv8);
    k_attn<<<NN / 32, 256, 0, stream>>>(qb, kv8, offs, csr_col, aggb);
    k_tail<<<NN / 64, 256, 0, stream>>>(aggb, wpack + 49152, bo, x, ln2g, ln2b,
                                        wpack + 65536, b1, wpack + 98304, b2, out);
}

// Round 14
// 144.587 us; speedup vs baseline: 2.4154x; 1.0931x over previous
//
#include <hip/hip_runtime.h>
#include <math.h>

#define NN 65536
#define HH 128
#define DHH 16
#define NE 1048576
#define HID 256
#define LNEPS 1e-5f
#define NB 256      // buckets for CSR build
#define BCAP 6144   // max edges per bucket (mean 4096, sd 64 -> +32 sd)

typedef __attribute__((ext_vector_type(8))) short bf16x8;
typedef __attribute__((ext_vector_type(8))) unsigned short u16x8;
typedef __attribute__((ext_vector_type(4))) float f32x4;
typedef __attribute__((ext_vector_type(2))) float f32x2;

static __device__ __forceinline__ unsigned short f2bf(float f) {
    union { float f; unsigned u; } c; c.f = f;
    unsigned r = c.u + 0x7fffu + ((c.u >> 16) & 1u);
    return (unsigned short)(r >> 16);
}
static __device__ __forceinline__ float bf2f(unsigned short u) {
    union { unsigned u; float f; } c; c.u = ((unsigned)u) << 16;
    return c.f;
}
// gelu_tanh(x) == x*sigmoid(2c(x+0.044715x^3))  [exact identity]
static __device__ __forceinline__ float gelu_tanh(float x) {
    const float a = -2.302225282f;  // -2*log2(e)*0.7978845608
    const float u = a * (x + 0.044715f * x * x * x);
    const float e = __builtin_amdgcn_exp2f(u);
    return x * __builtin_amdgcn_rcpf(1.f + e);
}

// ---------------- K_FRONT: weight pack (blocks 0..511) ∥ edge binning (blocks 512..767) ----------
__global__ __launch_bounds__(256) void k_front(
    const float* __restrict__ wq, const float* __restrict__ wk, const float* __restrict__ wv,
    const float* __restrict__ wo, const float* __restrict__ w1, const float* __restrict__ w2,
    unsigned short* __restrict__ p,
    const int* __restrict__ er, const int* __restrict__ ec,
    int* __restrict__ gcur, unsigned long long* __restrict__ pairs) {
    __shared__ int cnt[NB];
    __shared__ int cur[NB];
    __shared__ int base[NB];
    const int t = threadIdx.x;
    if (blockIdx.x < 512) {
        // ---- pack path ----
        const int b = blockIdx.x;
        const float* src; unsigned short* dst; int N, idx;
        if (b < 64)       { src = wq; dst = p;          N = 128; idx = b * 256 + t; }
        else if (b < 128) { src = wk; dst = p + 16384;  N = 128; idx = (b - 64) * 256 + t; }
        else if (b < 192) { src = wv; dst = p + 32768;  N = 128; idx = (b - 128) * 256 + t; }
        else if (b < 256) { src = wo; dst = p + 49152;  N = 128; idx = (b - 192) * 256 + t; }
        else if (b < 384) { src = w1; dst = p + 65536;  N = 256; idx = (b - 256) * 256 + t; }
        else              { src = w2; dst = p + 98304;  N = 128; idx = (b - 384) * 256 + t; }
        const int k = idx / N, n = idx % N;
        dst[(((k >> 3) * N + n) << 3) + (k & 7)] = f2bf(src[idx]);
    } else {
        // ---- bin path ----
        const int e0 = (blockIdx.x - 512) * 4096;
        cnt[t] = 0;
        __syncthreads();
        int rows[16], cols[16];
#pragma unroll
        for (int i = 0; i < 16; i++) {
            const int e = e0 + i * 256 + t;
            rows[i] = er[e];
            cols[i] = ec[e];
            atomicAdd(&cnt[rows[i] >> 8], 1);
        }
        __syncthreads();
        if (cnt[t] > 0) base[t] = atomicAdd(&gcur[t], cnt[t]);
        cur[t] = 0;
        __syncthreads();
#pragma unroll
        for (int i = 0; i < 16; i++) {
            const int b = rows[i] >> 8;
            const int slot = atomicAdd(&cur[b], 1);
            pairs[(size_t)b * BCAP + base[b] + slot] =
                ((unsigned long long)rows[i] << 32) | (unsigned)cols[i];
        }
    }
}

// ---------------- K_MID: LN1+QKV (blocks 0..511) ∥ CSR finalize w/ inline scan (512..767) -------
__global__ __launch_bounds__(256) void k_mid(
    const float* __restrict__ x, const float* __restrict__ g, const float* __restrict__ bl,
    const unsigned short* __restrict__ wp,
    const float* __restrict__ bq, const float* __restrict__ bk, const float* __restrict__ bv,
    unsigned short* __restrict__ qo, unsigned char* __restrict__ kv8,
    const unsigned long long* __restrict__ pairs, const int* __restrict__ gcur,
    int* __restrict__ offs, int* __restrict__ csr_col) {
    __shared__ int smem4[16384];  // 64 KB arena, overlaid per path
    const int t = threadIdx.x;
    if (blockIdx.x < 512) {
        // ---- LN1 + QKV path ----
        unsigned short* aT = (unsigned short*)smem4;            // 128*128 u16 = 32 KB
        unsigned short* wbuf = (unsigned short*)smem4 + 16384;  // 16384 u16 = 32 KB
        const int rb = blockIdx.x * 128;
        const int w = t >> 6, l = t & 63;
        {
            const int sr0 = w * 32 + (l >> 2), qd = l & 3;
#pragma unroll 1
            for (int rr = 0; rr < 2; rr++) {
                const int row = sr0 + rr * 16;
                const float4* xr = reinterpret_cast<const float4*>(x + (size_t)(rb + row) * HH) + qd * 8;
                float xa[32]; float s = 0.f, ss = 0.f;
#pragma unroll
                for (int i = 0; i < 8; i++) {
                    float4 v4 = xr[i];
                    xa[i * 4 + 0] = v4.x; xa[i * 4 + 1] = v4.y; xa[i * 4 + 2] = v4.z; xa[i * 4 + 3] = v4.w;
                    s += v4.x + v4.y + v4.z + v4.w;
                    ss += v4.x * v4.x + v4.y * v4.y + v4.z * v4.z + v4.w * v4.w;
                }
                s += __shfl_xor(s, 1); s += __shfl_xor(s, 2);
                ss += __shfl_xor(ss, 1); ss += __shfl_xor(ss, 2);
                const float mu = s * (1.f / HH);
                const float rs = rsqrtf(ss * (1.f / HH) - mu * mu + LNEPS);
#pragma unroll
                for (int c = 0; c < 4; c++) {
                    u16x8 w8;
#pragma unroll
                    for (int j2 = 0; j2 < 8; j2++) {
                        const int d = qd * 32 + c * 8 + j2;
                        w8[j2] = f2bf((xa[c * 8 + j2] - mu) * rs * g[d] + bl[d]);
                    }
                    const int uoff = (row * 128 + qd * 32 + c * 8) ^ ((row & 7) << 3);
                    *reinterpret_cast<u16x8*>(&aT[uoff]) = w8;
                }
            }
#pragma unroll
            for (int i = 0; i < 8; i++) {
                const int off = i * 2048 + t * 8;
                *reinterpret_cast<u16x8*>(&wbuf[off]) = *reinterpret_cast<const u16x8*>(wp + off);
            }
        }
        __syncthreads();
        const int lr = l & 15, lg = l >> 4;
        const int row0 = w * 32 + lr;
        const int row1 = w * 32 + 16 + lr;
        bf16x8 a0[4], a1[4];
#pragma unroll
        for (int kc = 0; kc < 4; kc++) {
            a0[kc] = *reinterpret_cast<const bf16x8*>(&aT[(row0 * 128 + kc * 32 + lg * 8) ^ ((row0 & 7) << 3)]);
            a1[kc] = *reinterpret_cast<const bf16x8*>(&aT[(row1 * 128 + kc * 32 + lg * 8) ^ ((row1 & 7) << 3)]);
        }
#pragma unroll 1
        for (int m = 0; m < 3; m++) {
            const float* Bb = (m == 0) ? bq : (m == 1) ? bk : bv;
            f32x4 ac0[8], ac1[8];
#pragma unroll
            for (int g8 = 0; g8 < 8; g8++) { ac0[g8] = (f32x4){0.f,0.f,0.f,0.f}; ac1[g8] = (f32x4){0.f,0.f,0.f,0.f}; }
#pragma unroll
            for (int g8 = 0; g8 < 8; g8++)
#pragma unroll
                for (int kc = 0; kc < 4; kc++) {
                    const bf16x8 bfr = *reinterpret_cast<const bf16x8*>(&wbuf[(((kc << 2) + lg) * 128 + g8 * 16 + lr) << 3]);
                    ac0[g8] = __builtin_amdgcn_mfma_f32_16x16x32_bf16(a0[kc], bfr, ac0[g8], 0, 0, 0);
                    ac1[g8] = __builtin_amdgcn_mfma_f32_16x16x32_bf16(a1[kc], bfr, ac1[g8], 0, 0, 0);
                }
            __syncthreads();
            if (m < 2) {
                const unsigned short* nsrc = wp + (m + 1) * 16384;
#pragma unroll
                for (int i = 0; i < 8; i++) {
                    const int off = i * 2048 + t * 8;
                    *reinterpret_cast<u16x8*>(&wbuf[off]) = *reinterpret_cast<const u16x8*>(nsrc + off);
                }
            }
#pragma unroll
            for (int g8 = 0; g8 < 8; g8++) {
                const float bias = Bb[g8 * 16 + lr];
#pragma unroll
                for (int j = 0; j < 4; j++) {
                    const int ra = rb + w * 32 + 4 * lg + j;
                    const int rbb = ra + 16;
                    const float y0 = ac0[g8][j] + bias, y1 = ac1[g8][j] + bias;
                    if (m == 0) {
                        qo[(size_t)ra * HH + g8 * 16 + lr] = f2bf(y0);
                        qo[(size_t)rbb * HH + g8 * 16 + lr] = f2bf(y1);
                    } else {
                        const int off = g8 * 32 + lr + ((m == 2) ? 16 : 0);
                        const int pk0 = __builtin_amdgcn_cvt_pk_fp8_f32(y0, y0, 0, false);
                        const int pk1 = __builtin_amdgcn_cvt_pk_fp8_f32(y1, y1, 0, false);
                        kv8[(size_t)ra * 256 + off] = (unsigned char)(pk0 & 0xff);
                        kv8[(size_t)rbb * 256 + off] = (unsigned char)(pk1 & 0xff);
                    }
                }
            }
            if (m < 2) __syncthreads();
        }
    } else {
        // ---- CSR finalize path (inline bucket-total scan) ----
        int* cnt = smem4;
        int* sc = smem4 + 256;
        int* cur = smem4 + 512;
        int* colbuf = smem4 + 768;  // BCAP ints = 24 KB
        const int b = blockIdx.x - 512;
        // inline exclusive-prefix of bucket totals
        sc[t] = gcur[t];
        __syncthreads();
        for (int d = 1; d < NB; d <<= 1) {
            int vv = (t >= d) ? sc[t - d] : 0;
            __syncthreads();
            sc[t] += vv;
            __syncthreads();
        }
        const int cbase = (b == 0) ? 0 : sc[b - 1];
        const int tot = gcur[b];
        __syncthreads();
        const unsigned long long* bp = pairs + (size_t)b * BCAP;
        cnt[t] = 0;
        __syncthreads();
        for (int i = t; i < tot; i += 256) {
            const unsigned long long u = bp[i];
            atomicAdd(&cnt[(int)(u >> 32) & 255], 1);
        }
        __syncthreads();
        sc[t] = cnt[t];
        __syncthreads();
        for (int d = 1; d < 256; d <<= 1) {
            int vv = (t >= d) ? sc[t - d] : 0;
            __syncthreads();
            sc[t] += vv;
            __syncthreads();
        }
        const int excl = sc[t] - cnt[t];
        offs[b * 256 + t] = cbase + excl;
        cur[t] = excl;
        if (b == NB - 1 && t == 255) offs[NN] = NE;
        __syncthreads();
        for (int i = t; i < tot; i += 256) {
            const unsigned long long u = bp[i];
            const int r = (int)(u >> 32) & 255;
            const int p = atomicAdd(&cur[r], 1);
            colbuf[p] = (int)(unsigned)u;
        }
        __syncthreads();
        for (int i = t; i < tot; i += 256) csr_col[cbase + i] = colbuf[i];
    }
}

// ---------------- K3: fused SDDMM + softmax + SpMM — lane-local softmax, 2-edge-wide pipeline ----
__global__ __launch_bounds__(256) void k_attn(
    const unsigned short* __restrict__ q, const unsigned char* __restrict__ kv,
    const int* __restrict__ offs, const int* __restrict__ csr_col,
    unsigned short* __restrict__ agg) {
    const int wave = threadIdx.x >> 6;
    const int lane = threadIdx.x & 63;
    const int r8 = lane >> 3, h = lane & 7;
    const int row = blockIdx.x * 32 + wave * 8 + r8;
    const int c0 = offs[row];
    const int cnt = offs[row + 1] - c0;

    int mx = cnt;
#pragma unroll
    for (int d = 8; d < 64; d <<= 1) mx = max(mx, __shfl_xor(mx, d));
    mx = (mx + 1) & ~1;  // even

    float qf[16];
    {
        const u16x8* qp = reinterpret_cast<const u16x8*>(q + (size_t)row * HH + h * DHH);
        u16x8 q0 = qp[0], q1 = qp[1];
#pragma unroll
        for (int j = 0; j < 8; j++) { qf[j] = bf2f(q0[j]); qf[8 + j] = bf2f(q1[j]); }
    }
    float m = 0.f, den = 0.f;
    float acc[16] = {};

    // prologue: kv for edges 0,1; cols for edges 2,3
    int colA = (0 < cnt) ? csr_col[c0] : 0;
    int colB = (1 < cnt) ? csr_col[c0 + 1] : 0;
    const int4* pA = reinterpret_cast<const int4*>(kv + (size_t)colA * 256 + h * 32);
    const int4* pB = reinterpret_cast<const int4*>(kv + (size_t)colB * 256 + h * 32);
    int4 kdA = pA[0], vdA = pA[1];
    int4 kdB = pB[0], vdB = pB[1];
    int colC = (2 < cnt) ? csr_col[c0 + 2] : 0;
    int colD = (3 < cnt) ? csr_col[c0 + 3] : 0;

    for (int e = 0; e < mx; e += 2) {
        // issue next pair's kv + cols two pairs ahead
        const int4* pC = reinterpret_cast<const int4*>(kv + (size_t)colC * 256 + h * 32);
        const int4* pD = reinterpret_cast<const int4*>(kv + (size_t)colD * 256 + h * 32);
        const int4 nkdA = pC[0], nvdA = pC[1];
        const int4 nkdB = pD[0], nvdB = pD[1];
        const int ncolC = ((e + 4) < cnt) ? csr_col[c0 + e + 4] : 0;
        const int ncolD = ((e + 5) < cnt) ? csr_col[c0 + e + 5] : 0;

        const bool act0 = e < cnt, act1 = (e + 1) < cnt;
        float kfA[16], kfB[16];
        {
            f32x2 r;
            r = __builtin_amdgcn_cvt_pk_f32_fp8(kdA.x, false); kfA[0] = r[0]; kfA[1] = r[1];
            r = __builtin_amdgcn_cvt_pk_f32_fp8(kdA.x, true);  kfA[2] = r[0]; kfA[3] = r[1];
            r = __builtin_amdgcn_cvt_pk_f32_fp8(kdA.y, false); kfA[4] = r[0]; kfA[5] = r[1];
            r = __builtin_amdgcn_cvt_pk_f32_fp8(kdA.y, true);  kfA[6] = r[0]; kfA[7] = r[1];
            r = __builtin_amdgcn_cvt_pk_f32_fp8(kdA.z, false); kfA[8] = r[0]; kfA[9] = r[1];
            r = __builtin_amdgcn_cvt_pk_f32_fp8(kdA.z, true);  kfA[10] = r[0]; kfA[11] = r[1];
            r = __builtin_amdgcn_cvt_pk_f32_fp8(kdA.w, false); kfA[12] = r[0]; kfA[13] = r[1];
            r = __builtin_amdgcn_cvt_pk_f32_fp8(kdA.w, true);  kfA[14] = r[0]; kfA[15] = r[1];
            r = __builtin_amdgcn_cvt_pk_f32_fp8(kdB.x, false); kfB[0] = r[0]; kfB[1] = r[1];
            r = __builtin_amdgcn_cvt_pk_f32_fp8(kdB.x, true);  kfB[2] = r[0]; kfB[3] = r[1];
            r = __builtin_amdgcn_cvt_pk_f32_fp8(kdB.y, false); kfB[4] = r[0]; kfB[5] = r[1];
            r = __builtin_amdgcn_cvt_pk_f32_fp8(kdB.y, true);  kfB[6] = r[0]; kfB[7] = r[1];
            r = __builtin_amdgcn_cvt_pk_f32_fp8(kdB.z, false); kfB[8] = r[0]; kfB[9] = r[1];
            r = __builtin_amdgcn_cvt_pk_f32_fp8(kdB.z, true);  kfB[10] = r[0]; kfB[11] = r[1];
            r = __builtin_amdgcn_cvt_pk_f32_fp8(kdB.w, false); kfB[12] = r[0]; kfB[13] = r[1];
            r = __builtin_amdgcn_cvt_pk_f32_fp8(kdB.w, true);  kfB[14] = r[0]; kfB[15] = r[1];
        }
        float dot0 = 0.f, dot1 = 0.f;
#pragma unroll
        for (int j = 0; j < 16; j++) { dot0 += qf[j] * kfA[j]; dot1 += qf[j] * kfB[j]; }
        const float sc0 = act0 ? dot0 * 0.25f : -1e30f;
        const float sc1 = act1 ? dot1 * 0.25f : -1e30f;
        const float cm = fmaxf(sc0, sc1);
        if (e == 0) {
            m = cm;
        } else if (!__all(cm <= m + 8.f)) {   // defer-max: rescale ~never
            const float nm = fmaxf(m, cm);
            const float s8 = __expf(m - nm);
            den *= s8;
#pragma unroll
            for (int i = 0; i < 16; i++) acc[i] *= s8;
            m = nm;
        }
        const float pp0 = act0 ? __expf(sc0 - m) : 0.f;
        const float pp1 = act1 ? __expf(sc1 - m) : 0.f;
        den += pp0 + pp1;
        {
            f32x2 r;
            r = __builtin_amdgcn_cvt_pk_f32_fp8(vdA.x, false); acc[0] += pp0 * r[0]; acc[1] += pp0 * r[1];
            r = __builtin_amdgcn_cvt_pk_f32_fp8(vdA.x, true);  acc[2] += pp0 * r[0]; acc[3] += pp0 * r[1];
            r = __builtin_amdgcn_cvt_pk_f32_fp8(vdA.y, false); acc[4] += pp0 * r[0]; acc[5] += pp0 * r[1];
            r = __builtin_amdgcn_cvt_pk_f32_fp8(vdA.y, true);  acc[6] += pp0 * r[0]; acc[7] += pp0 * r[1];
            r = __builtin_amdgcn_cvt_pk_f32_fp8(vdA.z, false); acc[8] += pp0 * r[0]; acc[9] += pp0 * r[1];
            r = __builtin_amdgcn_cvt_pk_f32_fp8(vdA.z, true);  acc[10] += pp0 * r[0]; acc[11] += pp0 * r[1];
            r = __builtin_amdgcn_cvt_pk_f32_fp8(vdA.w, false); acc[12] += pp0 * r[0]; acc[13] += pp0 * r[1];
            r = __builtin_amdgcn_cvt_pk_f32_fp8(vdA.w, true);  acc[14] += pp0 * r[0]; acc[15] += pp0 * r[1];
            r = __builtin_amdgcn_cvt_pk_f32_fp8(vdB.x, false); acc[0] += pp1 * r[0]; acc[1] += pp1 * r[1];
            r = __builtin_amdgcn_cvt_pk_f32_fp8(vdB.x, true);  acc[2] += pp1 * r[0]; acc[3] += pp1 * r[1];
            r = __builtin_amdgcn_cvt_pk_f32_fp8(vdB.y, false); acc[4] += pp1 * r[0]; acc[5] += pp1 * r[1];
            r = __builtin_amdgcn_cvt_pk_f32_fp8(vdB.y, true);  acc[6] += pp1 * r[0]; acc[7] += pp1 * r[1];
            r = __builtin_amdgcn_cvt_pk_f32_fp8(vdB.z, false); acc[8] += pp1 * r[0]; acc[9] += pp1 * r[1];
            r = __builtin_amdgcn_cvt_pk_f32_fp8(vdB.z, true);  acc[10] += pp1 * r[0]; acc[11] += pp1 * r[1];
            r = __builtin_amdgcn_cvt_pk_f32_fp8(vdB.w, false); acc[12] += pp1 * r[0]; acc[13] += pp1 * r[1];
            r = __builtin_amdgcn_cvt_pk_f32_fp8(vdB.w, true);  acc[14] += pp1 * r[0]; acc[15] += pp1 * r[1];
        }
        colC = ncolC; colD = ncolD;
        kdA = nkdA; vdA = nvdA; kdB = nkdB; vdB = nvdB;
    }
    const float inv = 1.f / (den + 1e-9f);
    unsigned short* ar = agg + (size_t)row * HH + h * DHH;
    u16x8 o0, o1;
#pragma unroll
    for (int j = 0; j < 8; j++) { o0[j] = f2bf(acc[j] * inv); o1[j] = f2bf(acc[8 + j] * inv); }
    reinterpret_cast<u16x8*>(ar)[0] = o0;
    reinterpret_cast<u16x8*>(ar)[1] = o1;
}

// ---------------- K4: fused tail — T14 async weight staging (issue early, ds_write late) --------
__global__ __launch_bounds__(256) void k_tail(
    const unsigned short* __restrict__ aggb, const unsigned short* __restrict__ wop,
    const float* __restrict__ bo, const float* __restrict__ x,
    const float* __restrict__ g2, const float* __restrict__ bl2,
    const unsigned short* __restrict__ w1p, const float* __restrict__ b1,
    const unsigned short* __restrict__ w2p, const float* __restrict__ b2,
    float* __restrict__ out) {
    __shared__ unsigned short aT[64 * 128];   // 16 KB
    __shared__ unsigned short tT[64 * 256];   // 32 KB
    __shared__ unsigned short wbuf[16384];    // 32 KB
    const int t = threadIdx.x;
    const int rb = blockIdx.x * 64;
    const int w = t >> 6, l = t & 63;
    const int m0 = w * 16, lr = l & 15, lg = l >> 4;
    const int row = m0 + lr;

    // P0: stage agg tile + wo panel (direct); prefetch w1 half0 into regs
    {
        const int r = t >> 2, qd = t & 3;
        const u16x8* src = reinterpret_cast<const u16x8*>(aggb + (size_t)(rb + r) * HH) + qd * 4;
#pragma unroll
        for (int c = 0; c < 4; c++) {
            const int uoff = (r * 128 + qd * 32 + c * 8) ^ ((r & 7) << 3);
            *reinterpret_cast<u16x8*>(&aT[uoff]) = src[c];
        }
#pragma unroll
        for (int i = 0; i < 8; i++) {
            const int off = i * 2048 + t * 8;
            *reinterpret_cast<u16x8*>(&wbuf[off]) = *reinterpret_cast<const u16x8*>(wop + off);
        }
    }
    u16x8 wst[8];
#pragma unroll
    for (int i = 0; i < 8; i++) {
        const int off = i * 2048 + t * 8;
        const int k8 = off >> 10, rem = off & 1023;
        wst[i] = *reinterpret_cast<const u16x8*>(w1p + (k8 << 11) + rem);  // w1 half0, in flight
    }
    __syncthreads();

    // P1: agg @ wo + residual + LN2
    bf16x8 a[4];
#pragma unroll
    for (int kc = 0; kc < 4; kc++)
        a[kc] = *reinterpret_cast<const bf16x8*>(&aT[(row * 128 + kc * 32 + lg * 8) ^ ((row & 7) << 3)]);
    f32x4 acc[8];
#pragma unroll
    for (int g8 = 0; g8 < 8; g8++) acc[g8] = (f32x4){0.f, 0.f, 0.f, 0.f};
#pragma unroll
    for (int g8 = 0; g8 < 8; g8++)
#pragma unroll
        for (int kc = 0; kc < 4; kc++)
            acc[g8] = __builtin_amdgcn_mfma_f32_16x16x32_bf16(
                a[kc],
                *reinterpret_cast<const bf16x8*>(&wbuf[(((kc << 2) + lg) * 128 + g8 * 16 + lr) << 3]),
                acc[g8], 0, 0, 0);
    float hv[8][4];
#pragma unroll
    for (int g8 = 0; g8 < 8; g8++) {
        const float bias = bo[g8 * 16 + lr];
#pragma unroll
        for (int j = 0; j < 4; j++)
            hv[g8][j] = acc[g8][j] + bias + x[(size_t)(rb + m0 + 4 * lg + j) * HH + g8 * 16 + lr];
    }
    float mu[4], rs[4];
#pragma unroll
    for (int j = 0; j < 4; j++) {
        float s = 0.f, ss = 0.f;
#pragma unroll
        for (int g8 = 0; g8 < 8; g8++) { const float hh = hv[g8][j]; s += hh; ss += hh * hh; }
        s += __shfl_xor(s, 1); s += __shfl_xor(s, 2); s += __shfl_xor(s, 4); s += __shfl_xor(s, 8);
        ss += __shfl_xor(ss, 1); ss += __shfl_xor(ss, 2); ss += __shfl_xor(ss, 4); ss += __shfl_xor(ss, 8);
        mu[j] = s * (1.f / HH);
        rs[j] = rsqrtf(ss * (1.f / HH) - mu[j] * mu[j] + LNEPS);
    }
    __syncthreads();  // aT(agg) + wbuf(wo) reads complete

    // P2: hn -> aT ; ds_write w1h0 from regs ; prefetch w1h1
#pragma unroll
    for (int g8 = 0; g8 < 8; g8++) {
        const float gg = g2[g8 * 16 + lr], bb = bl2[g8 * 16 + lr];
#pragma unroll
        for (int j = 0; j < 4; j++) {
            const int i = m0 + 4 * lg + j;
            aT[(i * 128 + g8 * 16 + lr) ^ ((i & 7) << 3)] = f2bf((hv[g8][j] - mu[j]) * rs[j] * gg + bb);
        }
    }
#pragma unroll
    for (int i = 0; i < 8; i++) {
        const int off = i * 2048 + t * 8;
        *reinterpret_cast<u16x8*>(&wbuf[off]) = wst[i];
    }
#pragma unroll
    for (int i = 0; i < 8; i++) {
        const int off = i * 2048 + t * 8;
        const int k8 = off >> 10, rem = off & 1023;
        wst[i] = *reinterpret_cast<const u16x8*>(w1p + (k8 << 11) + 1024 + rem);  // w1 half1
    }
    __syncthreads();

    bf16x8 a2[4];
#pragma unroll
    for (int kc = 0; kc < 4; kc++)
        a2[kc] = *reinterpret_cast<const bf16x8*>(&aT[(row * 128 + kc * 32 + lg * 8) ^ ((row & 7) << 3)]);

    // P3: mlp1 half0 -> tT
#pragma unroll 1
    for (int Gl = 0; Gl < 8; Gl++) {
        f32x4 a1 = (f32x4){0.f, 0.f, 0.f, 0.f};
#pragma unroll
        for (int kc = 0; kc < 4; kc++)
            a1 = __builtin_amdgcn_mfma_f32_16x16x32_bf16(
                a2[kc],
                *reinterpret_cast<const bf16x8*>(&wbuf[(((kc << 2) + lg) * 128 + Gl * 16 + lr) << 3]),
                a1, 0, 0, 0);
        const float bias = b1[Gl * 16 + lr];
#pragma unroll
        for (int j = 0; j < 4; j++) {
            const int i = m0 + 4 * lg + j;
            tT[(i * 256 + Gl * 16 + lr) ^ ((i & 7) << 3)] = f2bf(gelu_tanh(a1[j] + bias));
        }
    }
    __syncthreads();

    // P4: ds_write w1h1 ; prefetch w2h0
#pragma unroll
    for (int i = 0; i < 8; i++) {
        const int off = i * 2048 + t * 8;
        *reinterpret_cast<u16x8*>(&wbuf[off]) = wst[i];
    }
#pragma unroll
    for (int i = 0; i < 8; i++) {
        const int off = i * 2048 + t * 8;
        wst[i] = *reinterpret_cast<const u16x8*>(w2p + off);  // w2 K-half0
    }
    __syncthreads();

    // P5: mlp1 half1 -> tT
#pragma unroll 1
    for (int Gl = 0; Gl < 8; Gl++) {
        const int G = 8 + Gl;
        f32x4 a1 = (f32x4){0.f, 0.f, 0.f, 0.f};
#pragma unroll
        for (int kc = 0; kc < 4; kc++)
            a1 = __builtin_amdgcn_mfma_f32_16x16x32_bf16(
                a2[kc],
                *reinterpret_cast<const bf16x8*>(&wbuf[(((kc << 2) + lg) * 128 + Gl * 16 + lr) << 3]),
                a1, 0, 0, 0);
        const float bias = b1[G * 16 + lr];
#pragma unroll
        for (int j = 0; j < 4; j++) {
            const int i = m0 + 4 * lg + j;
            tT[(i * 256 + G * 16 + lr) ^ ((i & 7) << 3)] = f2bf(gelu_tanh(a1[j] + bias));
        }
    }
    __syncthreads();

    // P6: ds_write w2h0 ; prefetch w2h1
#pragma unroll
    for (int i = 0; i < 8; i++) {
        const int off = i * 2048 + t * 8;
        *reinterpret_cast<u16x8*>(&wbuf[off]) = wst[i];
    }
#pragma unroll
    for (int i = 0; i < 8; i++) {
        const int off = i * 2048 + t * 8;
        wst[i] = *reinterpret_cast<const u16x8*>(w2p + 16384 + off);  // w2 K-half1
    }
    __syncthreads();

    // P7: mlp2 K-half0
    f32x4 acc2[8];
#pragma unroll
    for (int g8 = 0; g8 < 8; g8++) acc2[g8] = (f32x4){0.f, 0.f, 0.f, 0.f};
    {
        bf16x8 a3[4];
#pragma unroll
        for (int kc = 0; kc < 4; kc++)
            a3[kc] = *reinterpret_cast<const bf16x8*>(&tT[(row * 256 + kc * 32 + lg * 8) ^ ((row & 7) << 3)]);
#pragma unroll 1
        for (int g8 = 0; g8 < 8; g8++)
#pragma unroll
            for (int kc = 0; kc < 4; kc++)
                acc2[g8] = __builtin_amdgcn_mfma_f32_16x16x32_bf16(
                    a3[kc],
                    *reinterpret_cast<const bf16x8*>(&wbuf[(((kc << 2) + lg) * 128 + g8 * 16 + lr) << 3]),
                    acc2[g8], 0, 0, 0);
    }
    __syncthreads();

    // P8: ds_write w2h1
#pragma unroll
    for (int i = 0; i < 8; i++) {
        const int off = i * 2048 + t * 8;
        *reinterpret_cast<u16x8*>(&wbuf[off]) = wst[i];
    }
    __syncthreads();

    // P9: mlp2 K-half1 + epilogue
    {
        bf16x8 a3[4];
#pragma unroll
        for (int kc = 0; kc < 4; kc++)
            a3[kc] = *reinterpret_cast<const bf16x8*>(&tT[(row * 256 + 128 + kc * 32 + lg * 8) ^ ((row & 7) << 3)]);
#pragma unroll 1
        for (int g8 = 0; g8 < 8; g8++)
#pragma unroll
            for (int kc = 0; kc < 4; kc++)
                acc2[g8] = __builtin_amdgcn_mfma_f32_16x16x32_bf16(
                    a3[kc],
                    *reinterpret_cast<const bf16x8*>(&wbuf[(((kc << 2) + lg) * 128 + g8 * 16 + lr) << 3]),
                    acc2[g8], 0, 0, 0);
    }
#pragma unroll
    for (int g8 = 0; g8 < 8; g8++) {
        const float bias = b2[g8 * 16 + lr];
#pragma unroll
        for (int j = 0; j < 4; j++)
            out[(size_t)(rb + m0 + 4 * lg + j) * HH + g8 * 16 + lr] = hv[g8][j] + acc2[g8][j] + bias;
    }
}

extern "C" void kernel_launch(void* const* d_in, const int* in_sizes, int n_in,
                              void* d_out, int out_size, void* d_ws, size_t ws_size,
                              hipStream_t stream) {
    const float* x = (const float*)d_in[0];
    const int* erow = (const int*)d_in[1];
    const int* ecol = (const int*)d_in[2];
    const float* ln1g = (const float*)d_in[3];
    const float* ln1b = (const float*)d_in[4];
    const float* wq = (const float*)d_in[5];
    const float* bq = (const float*)d_in[6];
    const float* wk = (const float*)d_in[7];
    const float* bk = (const float*)d_in[8];
    const float* wv = (const float*)d_in[9];
    const float* bv = (const float*)d_in[10];
    const float* wo = (const float*)d_in[11];
    const float* bo = (const float*)d_in[12];
    const float* ln2g = (const float*)d_in[13];
    const float* ln2b = (const float*)d_in[14];
    const float* w1 = (const float*)d_in[15];
    const float* b1 = (const float*)d_in[16];
    const float* w2 = (const float*)d_in[17];
    const float* b2 = (const float*)d_in[18];
    float* out = (float*)d_out;

    unsigned short* qb = (unsigned short*)d_ws;                        // NN*128 ushort (16 MB)
    unsigned char* kv8 = (unsigned char*)(qb + (size_t)NN * HH);       // NN*256 bytes (16 MB)
    unsigned short* aggb = (unsigned short*)(kv8 + (size_t)NN * 256);  // NN*128 ushort (16 MB)
    unsigned short* wpack = aggb + (size_t)NN * HH;                    // 131072 ushorts (256 KB)
    int* offs = (int*)(wpack + 131072);                                // NN+1 ints
    int* csr_col = offs + NN + 1;                                      // NE ints (4 MB)
    int* gcur = csr_col + NE;                                          // NB ints
    unsigned long long* pairs = (unsigned long long*)(gcur + NB + 2);  // NB*BCAP (12 MB)

    hipMemsetAsync(gcur, 0, NB * sizeof(int), stream);
    k_front<<<768, 256, 0, stream>>>(wq, wk, wv, wo, w1, w2, wpack, erow, ecol, gcur, pairs);
    k_mid<<<768, 256, 0, stream>>>(x, ln1g, ln1b, wpack, bq, bk, bv, qb, kv8,
                                   pairs, gcur, offs, csr_col);
    k_attn<<<NN / 32, 256, 0, stream>>>(qb, kv8, offs, csr_col, aggb);
    k_tail<<<NN / 64, 256, 0, stream>>>(aggb, wpack + 49152, bo, x, ln2g, ln2b,
                                        wpack + 65536, b1, wpack + 98304, b2, out);
}

// Round 16
// 141.166 us; speedup vs baseline: 2.4739x; 1.0242x over previous
//
#include <hip/hip_runtime.h>
#include <math.h>

#define NN 65536
#define HH 128
#define DHH 16
#define NE 1048576
#define HID 256
#define LNEPS 1e-5f
#define NB 256      // buckets for CSR build
#define BCAP 6144   // max edges per bucket (mean 4096, sd 64 -> +32 sd)

typedef __attribute__((ext_vector_type(8))) short bf16x8;
typedef __attribute__((ext_vector_type(8))) unsigned short u16x8;
typedef __attribute__((ext_vector_type(4))) float f32x4;
typedef __attribute__((ext_vector_type(2))) float f32x2;

static __device__ __forceinline__ unsigned short f2bf(float f) {
    union { float f; unsigned u; } c; c.f = f;
    unsigned r = c.u + 0x7fffu + ((c.u >> 16) & 1u);
    return (unsigned short)(r >> 16);
}
static __device__ __forceinline__ float bf2f(unsigned short u) {
    union { unsigned u; float f; } c; c.u = ((unsigned)u) << 16;
    return c.f;
}
// gelu_tanh(x) == x*sigmoid(2c(x+0.044715x^3))  [exact identity]
static __device__ __forceinline__ float gelu_tanh(float x) {
    const float a = -2.302225282f;  // -2*log2(e)*0.7978845608
    const float u = a * (x + 0.044715f * x * x * x);
    const float e = __builtin_amdgcn_exp2f(u);
    return x * __builtin_amdgcn_rcpf(1.f + e);
}

// ---------------- K_FRONT: weight pack (blocks 0..511) ∥ edge binning (blocks 512..767) ----------
__global__ __launch_bounds__(256) void k_front(
    const float* __restrict__ wq, const float* __restrict__ wk, const float* __restrict__ wv,
    const float* __restrict__ wo, const float* __restrict__ w1, const float* __restrict__ w2,
    unsigned short* __restrict__ p,
    const int* __restrict__ er, const int* __restrict__ ec,
    int* __restrict__ gcur, unsigned long long* __restrict__ pairs) {
    __shared__ int cnt[NB];
    __shared__ int cur[NB];
    __shared__ int base[NB];
    const int t = threadIdx.x;
    if (blockIdx.x < 512) {
        const int b = blockIdx.x;
        const float* src; unsigned short* dst; int N, idx;
        if (b < 64)       { src = wq; dst = p;          N = 128; idx = b * 256 + t; }
        else if (b < 128) { src = wk; dst = p + 16384;  N = 128; idx = (b - 64) * 256 + t; }
        else if (b < 192) { src = wv; dst = p + 32768;  N = 128; idx = (b - 128) * 256 + t; }
        else if (b < 256) { src = wo; dst = p + 49152;  N = 128; idx = (b - 192) * 256 + t; }
        else if (b < 384) { src = w1; dst = p + 65536;  N = 256; idx = (b - 256) * 256 + t; }
        else              { src = w2; dst = p + 98304;  N = 128; idx = (b - 384) * 256 + t; }
        const int k = idx / N, n = idx % N;
        dst[(((k >> 3) * N + n) << 3) + (k & 7)] = f2bf(src[idx]);
    } else {
        const int e0 = (blockIdx.x - 512) * 4096;
        cnt[t] = 0;
        __syncthreads();
        int rows[16], cols[16];
#pragma unroll
        for (int i = 0; i < 16; i++) {
            const int e = e0 + i * 256 + t;
            rows[i] = er[e];
            cols[i] = ec[e];
            atomicAdd(&cnt[rows[i] >> 8], 1);
        }
        __syncthreads();
        if (cnt[t] > 0) base[t] = atomicAdd(&gcur[t], cnt[t]);
        cur[t] = 0;
        __syncthreads();
#pragma unroll
        for (int i = 0; i < 16; i++) {
            const int b = rows[i] >> 8;
            const int slot = atomicAdd(&cur[b], 1);
            pairs[(size_t)b * BCAP + base[b] + slot] =
                ((unsigned long long)rows[i] << 32) | (unsigned)cols[i];
        }
    }
}

// ---------------- K_MID: LN1+QKV (blocks 0..511) ∥ CSR finalize w/ inline scan (512..767) -------
__global__ __launch_bounds__(256) void k_mid(
    const float* __restrict__ x, const float* __restrict__ g, const float* __restrict__ bl,
    const unsigned short* __restrict__ wp,
    const float* __restrict__ bq, const float* __restrict__ bk, const float* __restrict__ bv,
    unsigned short* __restrict__ qo, unsigned char* __restrict__ kv8,
    const unsigned long long* __restrict__ pairs, const int* __restrict__ gcur,
    int* __restrict__ offs, int* __restrict__ csr_col) {
    __shared__ int smem4[16384];  // 64 KB arena
    const int t = threadIdx.x;
    if (blockIdx.x < 512) {
        unsigned short* aT = (unsigned short*)smem4;
        unsigned short* wbuf = (unsigned short*)smem4 + 16384;
        const int rb = blockIdx.x * 128;
        const int w = t >> 6, l = t & 63;
        {
            const int sr0 = w * 32 + (l >> 2), qd = l & 3;
#pragma unroll 1
            for (int rr = 0; rr < 2; rr++) {
                const int row = sr0 + rr * 16;
                const float4* xr = reinterpret_cast<const float4*>(x + (size_t)(rb + row) * HH) + qd * 8;
                float xa[32]; float s = 0.f, ss = 0.f;
#pragma unroll
                for (int i = 0; i < 8; i++) {
                    float4 v4 = xr[i];
                    xa[i * 4 + 0] = v4.x; xa[i * 4 + 1] = v4.y; xa[i * 4 + 2] = v4.z; xa[i * 4 + 3] = v4.w;
                    s += v4.x + v4.y + v4.z + v4.w;
                    ss += v4.x * v4.x + v4.y * v4.y + v4.z * v4.z + v4.w * v4.w;
                }
                s += __shfl_xor(s, 1); s += __shfl_xor(s, 2);
                ss += __shfl_xor(ss, 1); ss += __shfl_xor(ss, 2);
                const float mu = s * (1.f / HH);
                const float rs = rsqrtf(ss * (1.f / HH) - mu * mu + LNEPS);
#pragma unroll
                for (int c = 0; c < 4; c++) {
                    u16x8 w8;
#pragma unroll
                    for (int j2 = 0; j2 < 8; j2++) {
                        const int d = qd * 32 + c * 8 + j2;
                        w8[j2] = f2bf((xa[c * 8 + j2] - mu) * rs * g[d] + bl[d]);
                    }
                    const int uoff = (row * 128 + qd * 32 + c * 8) ^ ((row & 7) << 3);
                    *reinterpret_cast<u16x8*>(&aT[uoff]) = w8;
                }
            }
#pragma unroll
            for (int i = 0; i < 8; i++) {
                const int off = i * 2048 + t * 8;
                *reinterpret_cast<u16x8*>(&wbuf[off]) = *reinterpret_cast<const u16x8*>(wp + off);
            }
        }
        __syncthreads();
        const int lr = l & 15, lg = l >> 4;
        const int row0 = w * 32 + lr;
        const int row1 = w * 32 + 16 + lr;
        bf16x8 a0[4], a1[4];
#pragma unroll
        for (int kc = 0; kc < 4; kc++) {
            a0[kc] = *reinterpret_cast<const bf16x8*>(&aT[(row0 * 128 + kc * 32 + lg * 8) ^ ((row0 & 7) << 3)]);
            a1[kc] = *reinterpret_cast<const bf16x8*>(&aT[(row1 * 128 + kc * 32 + lg * 8) ^ ((row1 & 7) << 3)]);
        }
#pragma unroll 1
        for (int m = 0; m < 3; m++) {
            const float* Bb = (m == 0) ? bq : (m == 1) ? bk : bv;
            f32x4 ac0[8], ac1[8];
#pragma unroll
            for (int g8 = 0; g8 < 8; g8++) { ac0[g8] = (f32x4){0.f,0.f,0.f,0.f}; ac1[g8] = (f32x4){0.f,0.f,0.f,0.f}; }
#pragma unroll
            for (int g8 = 0; g8 < 8; g8++)
#pragma unroll
                for (int kc = 0; kc < 4; kc++) {
                    const bf16x8 bfr = *reinterpret_cast<const bf16x8*>(&wbuf[(((kc << 2) + lg) * 128 + g8 * 16 + lr) << 3]);
                    ac0[g8] = __builtin_amdgcn_mfma_f32_16x16x32_bf16(a0[kc], bfr, ac0[g8], 0, 0, 0);
                    ac1[g8] = __builtin_amdgcn_mfma_f32_16x16x32_bf16(a1[kc], bfr, ac1[g8], 0, 0, 0);
                }
            __syncthreads();
            if (m < 2) {
                const unsigned short* nsrc = wp + (m + 1) * 16384;
#pragma unroll
                for (int i = 0; i < 8; i++) {
                    const int off = i * 2048 + t * 8;
                    *reinterpret_cast<u16x8*>(&wbuf[off]) = *reinterpret_cast<const u16x8*>(nsrc + off);
                }
            }
#pragma unroll
            for (int g8 = 0; g8 < 8; g8++) {
                const float bias = Bb[g8 * 16 + lr];
#pragma unroll
                for (int j = 0; j < 4; j++) {
                    const int ra = rb + w * 32 + 4 * lg + j;
                    const int rbb = ra + 16;
                    const float y0 = ac0[g8][j] + bias, y1 = ac1[g8][j] + bias;
                    if (m == 0) {
                        qo[(size_t)ra * HH + g8 * 16 + lr] = f2bf(y0);
                        qo[(size_t)rbb * HH + g8 * 16 + lr] = f2bf(y1);
                    } else {
                        const int off = g8 * 32 + lr + ((m == 2) ? 16 : 0);
                        const int pk0 = __builtin_amdgcn_cvt_pk_fp8_f32(y0, y0, 0, false);
                        const int pk1 = __builtin_amdgcn_cvt_pk_fp8_f32(y1, y1, 0, false);
                        kv8[(size_t)ra * 256 + off] = (unsigned char)(pk0 & 0xff);
                        kv8[(size_t)rbb * 256 + off] = (unsigned char)(pk1 & 0xff);
                    }
                }
            }
            if (m < 2) __syncthreads();
        }
    } else {
        int* cnt = smem4;
        int* sc = smem4 + 256;
        int* cur = smem4 + 512;
        int* colbuf = smem4 + 768;
        const int b = blockIdx.x - 512;
        sc[t] = gcur[t];
        __syncthreads();
        for (int d = 1; d < NB; d <<= 1) {
            int vv = (t >= d) ? sc[t - d] : 0;
            __syncthreads();
            sc[t] += vv;
            __syncthreads();
        }
        const int cbase = (b == 0) ? 0 : sc[b - 1];
        const int tot = gcur[b];
        __syncthreads();
        const unsigned long long* bp = pairs + (size_t)b * BCAP;
        cnt[t] = 0;
        __syncthreads();
        for (int i = t; i < tot; i += 256) {
            const unsigned long long u = bp[i];
            atomicAdd(&cnt[(int)(u >> 32) & 255], 1);
        }
        __syncthreads();
        sc[t] = cnt[t];
        __syncthreads();
        for (int d = 1; d < 256; d <<= 1) {
            int vv = (t >= d) ? sc[t - d] : 0;
            __syncthreads();
            sc[t] += vv;
            __syncthreads();
        }
        const int excl = sc[t] - cnt[t];
        offs[b * 256 + t] = cbase + excl;
        cur[t] = excl;
        if (b == NB - 1 && t == 255) offs[NN] = NE;
        __syncthreads();
        for (int i = t; i < tot; i += 256) {
            const unsigned long long u = bp[i];
            const int r = (int)(u >> 32) & 255;
            const int p = atomicAdd(&cur[r], 1);
            colbuf[p] = (int)(unsigned)u;
        }
        __syncthreads();
        for (int i = t; i < tot; i += 256) csr_col[cbase + i] = colbuf[i];
    }
}

// ---------------- K_AT: fused attention + wo + res + LN2 + MLP (agg never leaves the block) ----
__global__ __launch_bounds__(256) void k_at(
    const unsigned short* __restrict__ q, const unsigned char* __restrict__ kv,
    const int* __restrict__ offs, const int* __restrict__ csr_col,
    const unsigned short* __restrict__ wop, const float* __restrict__ bo,
    const float* __restrict__ x, const float* __restrict__ g2, const float* __restrict__ bl2,
    const unsigned short* __restrict__ w1p, const float* __restrict__ b1,
    const unsigned short* __restrict__ w2p, const float* __restrict__ b2,
    float* __restrict__ out) {
    __shared__ unsigned short aT[64 * 128];   // 16 KB: agg tile, then hn tile
    __shared__ unsigned short tT[64 * 256];   // 32 KB
    __shared__ unsigned short wbuf[16384];    // 32 KB
    const int t = threadIdx.x;
    const int rb = blockIdx.x * 64;
    const int w = t >> 6, l = t & 63;
    const int m0 = w * 16, lr = l & 15, lg = l >> 4;
    const int row = m0 + lr;

    // stage wo panel up-front (direct)
#pragma unroll
    for (int i = 0; i < 8; i++) {
        const int off = i * 2048 + t * 8;
        *reinterpret_cast<u16x8*>(&wbuf[off]) = *reinterpret_cast<const u16x8*>(wop + off);
    }

    // ---- attention: 2 (row,head) units per thread, results -> aT (swizzled bf16) ----
#pragma unroll 1
    for (int u = 0; u < 2; u++) {
        const int rl = (t >> 3) + u * 32;        // local row 0..63
        const int arow = rb + rl;
        const int h = t & 7;
        const int c0 = offs[arow];
        const int cnt = offs[arow + 1] - c0;
        int mx = cnt;
#pragma unroll
        for (int d = 8; d < 64; d <<= 1) mx = max(mx, __shfl_xor(mx, d));
        mx = (mx + 1) & ~1;

        float qf[16];
        {
            const u16x8* qp = reinterpret_cast<const u16x8*>(q + (size_t)arow * HH + h * DHH);
            u16x8 q0 = qp[0], q1 = qp[1];
#pragma unroll
            for (int j = 0; j < 8; j++) { qf[j] = bf2f(q0[j]); qf[8 + j] = bf2f(q1[j]); }
        }
        float m = 0.f, den = 0.f;
        float acc[16] = {};

        int colA = (0 < cnt) ? csr_col[c0] : 0;
        int colB = (1 < cnt) ? csr_col[c0 + 1] : 0;
        const int4* pA = reinterpret_cast<const int4*>(kv + (size_t)colA * 256 + h * 32);
        const int4* pB = reinterpret_cast<const int4*>(kv + (size_t)colB * 256 + h * 32);
        int4 kdA = pA[0], vdA = pA[1];
        int4 kdB = pB[0], vdB = pB[1];
        int colC = (2 < cnt) ? csr_col[c0 + 2] : 0;
        int colD = (3 < cnt) ? csr_col[c0 + 3] : 0;

        for (int e = 0; e < mx; e += 2) {
            const int4* pC = reinterpret_cast<const int4*>(kv + (size_t)colC * 256 + h * 32);
            const int4* pD = reinterpret_cast<const int4*>(kv + (size_t)colD * 256 + h * 32);
            const int4 nkdA = pC[0], nvdA = pC[1];
            const int4 nkdB = pD[0], nvdB = pD[1];
            const int ncolC = ((e + 4) < cnt) ? csr_col[c0 + e + 4] : 0;
            const int ncolD = ((e + 5) < cnt) ? csr_col[c0 + e + 5] : 0;

            const bool act0 = e < cnt, act1 = (e + 1) < cnt;
            float kfA[16], kfB[16];
            {
                f32x2 r;
                r = __builtin_amdgcn_cvt_pk_f32_fp8(kdA.x, false); kfA[0] = r[0]; kfA[1] = r[1];
                r = __builtin_amdgcn_cvt_pk_f32_fp8(kdA.x, true);  kfA[2] = r[0]; kfA[3] = r[1];
                r = __builtin_amdgcn_cvt_pk_f32_fp8(kdA.y, false); kfA[4] = r[0]; kfA[5] = r[1];
                r = __builtin_amdgcn_cvt_pk_f32_fp8(kdA.y, true);  kfA[6] = r[0]; kfA[7] = r[1];
                r = __builtin_amdgcn_cvt_pk_f32_fp8(kdA.z, false); kfA[8] = r[0]; kfA[9] = r[1];
                r = __builtin_amdgcn_cvt_pk_f32_fp8(kdA.z, true);  kfA[10] = r[0]; kfA[11] = r[1];
                r = __builtin_amdgcn_cvt_pk_f32_fp8(kdA.w, false); kfA[12] = r[0]; kfA[13] = r[1];
                r = __builtin_amdgcn_cvt_pk_f32_fp8(kdA.w, true);  kfA[14] = r[0]; kfA[15] = r[1];
                r = __builtin_amdgcn_cvt_pk_f32_fp8(kdB.x, false); kfB[0] = r[0]; kfB[1] = r[1];
                r = __builtin_amdgcn_cvt_pk_f32_fp8(kdB.x, true);  kfB[2] = r[0]; kfB[3] = r[1];
                r = __builtin_amdgcn_cvt_pk_f32_fp8(kdB.y, false); kfB[4] = r[0]; kfB[5] = r[1];
                r = __builtin_amdgcn_cvt_pk_f32_fp8(kdB.y, true);  kfB[6] = r[0]; kfB[7] = r[1];
                r = __builtin_amdgcn_cvt_pk_f32_fp8(kdB.z, false); kfB[8] = r[0]; kfB[9] = r[1];
                r = __builtin_amdgcn_cvt_pk_f32_fp8(kdB.z, true);  kfB[10] = r[0]; kfB[11] = r[1];
                r = __builtin_amdgcn_cvt_pk_f32_fp8(kdB.w, false); kfB[12] = r[0]; kfB[13] = r[1];
                r = __builtin_amdgcn_cvt_pk_f32_fp8(kdB.w, true);  kfB[14] = r[0]; kfB[15] = r[1];
            }
            float dot0 = 0.f, dot1 = 0.f;
#pragma unroll
            for (int j = 0; j < 16; j++) { dot0 += qf[j] * kfA[j]; dot1 += qf[j] * kfB[j]; }
            const float sc0 = act0 ? dot0 * 0.25f : -1e30f;
            const float sc1 = act1 ? dot1 * 0.25f : -1e30f;
            const float cm = fmaxf(sc0, sc1);
            if (e == 0) {
                m = cm;
            } else if (!__all(cm <= m + 8.f)) {
                const float nm = fmaxf(m, cm);
                const float s8 = __expf(m - nm);
                den *= s8;
#pragma unroll
                for (int i = 0; i < 16; i++) acc[i] *= s8;
                m = nm;
            }
            const float pp0 = act0 ? __expf(sc0 - m) : 0.f;
            const float pp1 = act1 ? __expf(sc1 - m) : 0.f;
            den += pp0 + pp1;
            {
                f32x2 r;
                r = __builtin_amdgcn_cvt_pk_f32_fp8(vdA.x, false); acc[0] += pp0 * r[0]; acc[1] += pp0 * r[1];
                r = __builtin_amdgcn_cvt_pk_f32_fp8(vdA.x, true);  acc[2] += pp0 * r[0]; acc[3] += pp0 * r[1];
                r = __builtin_amdgcn_cvt_pk_f32_fp8(vdA.y, false); acc[4] += pp0 * r[0]; acc[5] += pp0 * r[1];
                r = __builtin_amdgcn_cvt_pk_f32_fp8(vdA.y, true);  acc[6] += pp0 * r[0]; acc[7] += pp0 * r[1];
                r = __builtin_amdgcn_cvt_pk_f32_fp8(vdA.z, false); acc[8] += pp0 * r[0]; acc[9] += pp0 * r[1];
                r = __builtin_amdgcn_cvt_pk_f32_fp8(vdA.z, true);  acc[10] += pp0 * r[0]; acc[11] += pp0 * r[1];
                r = __builtin_amdgcn_cvt_pk_f32_fp8(vdA.w, false); acc[12] += pp0 * r[0]; acc[13] += pp0 * r[1];
                r = __builtin_amdgcn_cvt_pk_f32_fp8(vdA.w, true);  acc[14] += pp0 * r[0]; acc[15] += pp0 * r[1];
                r = __builtin_amdgcn_cvt_pk_f32_fp8(vdB.x, false); acc[0] += pp1 * r[0]; acc[1] += pp1 * r[1];
                r = __builtin_amdgcn_cvt_pk_f32_fp8(vdB.x, true);  acc[2] += pp1 * r[0]; acc[3] += pp1 * r[1];
                r = __builtin_amdgcn_cvt_pk_f32_fp8(vdB.y, false); acc[4] += pp1 * r[0]; acc[5] += pp1 * r[1];
                r = __builtin_amdgcn_cvt_pk_f32_fp8(vdB.y, true);  acc[6] += pp1 * r[0]; acc[7] += pp1 * r[1];
                r = __builtin_amdgcn_cvt_pk_f32_fp8(vdB.z, false); acc[8] += pp1 * r[0]; acc[9] += pp1 * r[1];
                r = __builtin_amdgcn_cvt_pk_f32_fp8(vdB.z, true);  acc[10] += pp1 * r[0]; acc[11] += pp1 * r[1];
                r = __builtin_amdgcn_cvt_pk_f32_fp8(vdB.w, false); acc[12] += pp1 * r[0]; acc[13] += pp1 * r[1];
                r = __builtin_amdgcn_cvt_pk_f32_fp8(vdB.w, true);  acc[14] += pp1 * r[0]; acc[15] += pp1 * r[1];
            }
            colC = ncolC; colD = ncolD;
            kdA = nkdA; vdA = nvdA; kdB = nkdB; vdB = nvdB;
        }
        const float inv = 1.f / (den + 1e-9f);
        u16x8 o0, o1;
#pragma unroll
        for (int j = 0; j < 8; j++) { o0[j] = f2bf(acc[j] * inv); o1[j] = f2bf(acc[8 + j] * inv); }
        const int base16 = rl * 128 + h * 16;
        *reinterpret_cast<u16x8*>(&aT[(base16) ^ ((rl & 7) << 3)]) = o0;
        *reinterpret_cast<u16x8*>(&aT[(base16 + 8) ^ ((rl & 7) << 3)]) = o1;
    }
    // prefetch w1 half0 into regs (T14)
    u16x8 wst[8];
#pragma unroll
    for (int i = 0; i < 8; i++) {
        const int off = i * 2048 + t * 8;
        const int k8 = off >> 10, rem = off & 1023;
        wst[i] = *reinterpret_cast<const u16x8*>(w1p + (k8 << 11) + rem);
    }
    __syncthreads();

    // P1: agg @ wo + residual + LN2
    bf16x8 a[4];
#pragma unroll
    for (int kc = 0; kc < 4; kc++)
        a[kc] = *reinterpret_cast<const bf16x8*>(&aT[(row * 128 + kc * 32 + lg * 8) ^ ((row & 7) << 3)]);
    f32x4 acc[8];
#pragma unroll
    for (int g8 = 0; g8 < 8; g8++) acc[g8] = (f32x4){0.f, 0.f, 0.f, 0.f};
#pragma unroll
    for (int g8 = 0; g8 < 8; g8++)
#pragma unroll
        for (int kc = 0; kc < 4; kc++)
            acc[g8] = __builtin_amdgcn_mfma_f32_16x16x32_bf16(
                a[kc],
                *reinterpret_cast<const bf16x8*>(&wbuf[(((kc << 2) + lg) * 128 + g8 * 16 + lr) << 3]),
                acc[g8], 0, 0, 0);
    float hv[8][4];
#pragma unroll
    for (int g8 = 0; g8 < 8; g8++) {
        const float bias = bo[g8 * 16 + lr];
#pragma unroll
        for (int j = 0; j < 4; j++)
            hv[g8][j] = acc[g8][j] + bias + x[(size_t)(rb + m0 + 4 * lg + j) * HH + g8 * 16 + lr];
    }
    float mu[4], rs[4];
#pragma unroll
    for (int j = 0; j < 4; j++) {
        float s = 0.f, ss = 0.f;
#pragma unroll
        for (int g8 = 0; g8 < 8; g8++) { const float hh = hv[g8][j]; s += hh; ss += hh * hh; }
        s += __shfl_xor(s, 1); s += __shfl_xor(s, 2); s += __shfl_xor(s, 4); s += __shfl_xor(s, 8);
        ss += __shfl_xor(ss, 1); ss += __shfl_xor(ss, 2); ss += __shfl_xor(ss, 4); ss += __shfl_xor(ss, 8);
        mu[j] = s * (1.f / HH);
        rs[j] = rsqrtf(ss * (1.f / HH) - mu[j] * mu[j] + LNEPS);
    }
    __syncthreads();  // aT(agg) + wbuf(wo) reads complete

    // P2: hn -> aT ; ds_write w1h0 ; prefetch w1h1
#pragma unroll
    for (int g8 = 0; g8 < 8; g8++) {
        const float gg = g2[g8 * 16 + lr], bb = bl2[g8 * 16 + lr];
#pragma unroll
        for (int j = 0; j < 4; j++) {
            const int i = m0 + 4 * lg + j;
            aT[(i * 128 + g8 * 16 + lr) ^ ((i & 7) << 3)] = f2bf((hv[g8][j] - mu[j]) * rs[j] * gg + bb);
        }
    }
#pragma unroll
    for (int i = 0; i < 8; i++) {
        const int off = i * 2048 + t * 8;
        *reinterpret_cast<u16x8*>(&wbuf[off]) = wst[i];
    }
#pragma unroll
    for (int i = 0; i < 8; i++) {
        const int off = i * 2048 + t * 8;
        const int k8 = off >> 10, rem = off & 1023;
        wst[i] = *reinterpret_cast<const u16x8*>(w1p + (k8 << 11) + 1024 + rem);
    }
    __syncthreads();

    bf16x8 a2[4];
#pragma unroll
    for (int kc = 0; kc < 4; kc++)
        a2[kc] = *reinterpret_cast<const bf16x8*>(&aT[(row * 128 + kc * 32 + lg * 8) ^ ((row & 7) << 3)]);

    // P3: mlp1 half0 -> tT
#pragma unroll 1
    for (int Gl = 0; Gl < 8; Gl++) {
        f32x4 a1 = (f32x4){0.f, 0.f, 0.f, 0.f};
#pragma unroll
        for (int kc = 0; kc < 4; kc++)
            a1 = __builtin_amdgcn_mfma_f32_16x16x32_bf16(
                a2[kc],
                *reinterpret_cast<const bf16x8*>(&wbuf[(((kc << 2) + lg) * 128 + Gl * 16 + lr) << 3]),
                a1, 0, 0, 0);
        const float bias = b1[Gl * 16 + lr];
#pragma unroll
        for (int j = 0; j < 4; j++) {
            const int i = m0 + 4 * lg + j;
            tT[(i * 256 + Gl * 16 + lr) ^ ((i & 7) << 3)] = f2bf(gelu_tanh(a1[j] + bias));
        }
    }
    __syncthreads();

    // P4: ds_write w1h1 ; prefetch w2h0
#pragma unroll
    for (int i = 0; i < 8; i++) {
        const int off = i * 2048 + t * 8;
        *reinterpret_cast<u16x8*>(&wbuf[off]) = wst[i];
    }
#pragma unroll
    for (int i = 0; i < 8; i++) {
        const int off = i * 2048 + t * 8;
        wst[i] = *reinterpret_cast<const u16x8*>(w2p + off);
    }
    __syncthreads();

    // P5: mlp1 half1 -> tT
#pragma unroll 1
    for (int Gl = 0; Gl < 8; Gl++) {
        const int G = 8 + Gl;
        f32x4 a1 = (f32x4){0.f, 0.f, 0.f, 0.f};
#pragma unroll
        for (int kc = 0; kc < 4; kc++)
            a1 = __builtin_amdgcn_mfma_f32_16x16x32_bf16(
                a2[kc],
                *reinterpret_cast<const bf16x8*>(&wbuf[(((kc << 2) + lg) * 128 + Gl * 16 + lr) << 3]),
                a1, 0, 0, 0);
        const float bias = b1[G * 16 + lr];
#pragma unroll
        for (int j = 0; j < 4; j++) {
            const int i = m0 + 4 * lg + j;
            tT[(i * 256 + G * 16 + lr) ^ ((i & 7) << 3)] = f2bf(gelu_tanh(a1[j] + bias));
        }
    }
    __syncthreads();

    // P6: ds_write w2h0 ; prefetch w2h1
#pragma unroll
    for (int i = 0; i < 8; i++) {
        const int off = i * 2048 + t * 8;
        *reinterpret_cast<u16x8*>(&wbuf[off]) = wst[i];
    }
#pragma unroll
    for (int i = 0; i < 8; i++) {
        const int off = i * 2048 + t * 8;
        wst[i] = *reinterpret_cast<const u16x8*>(w2p + 16384 + off);
    }
    __syncthreads();

    // P7: mlp2 K-half0
    f32x4 acc2[8];
#pragma unroll
    for (int g8 = 0; g8 < 8; g8++) acc2[g8] = (f32x4){0.f, 0.f, 0.f, 0.f};
    {
        bf16x8 a3[4];
#pragma unroll
        for (int kc = 0; kc < 4; kc++)
            a3[kc] = *reinterpret_cast<const bf16x8*>(&tT[(row * 256 + kc * 32 + lg * 8) ^ ((row & 7) << 3)]);
#pragma unroll 1
        for (int g8 = 0; g8 < 8; g8++)
#pragma unroll
            for (int kc = 0; kc < 4; kc++)
                acc2[g8] = __builtin_amdgcn_mfma_f32_16x16x32_bf16(
                    a3[kc],
                    *reinterpret_cast<const bf16x8*>(&wbuf[(((kc << 2) + lg) * 128 + g8 * 16 + lr) << 3]),
                    acc2[g8], 0, 0, 0);
    }
    __syncthreads();

    // P8: ds_write w2h1
#pragma unroll
    for (int i = 0; i < 8; i++) {
        const int off = i * 2048 + t * 8;
        *reinterpret_cast<u16x8*>(&wbuf[off]) = wst[i];
    }
    __syncthreads();

    // P9: mlp2 K-half1 + epilogue
    {
        bf16x8 a3[4];
#pragma unroll
        for (int kc = 0; kc < 4; kc++)
            a3[kc] = *reinterpret_cast<const bf16x8*>(&tT[(row * 256 + 128 + kc * 32 + lg * 8) ^ ((row & 7) << 3)]);
#pragma unroll 1
        for (int g8 = 0; g8 < 8; g8++)
#pragma unroll
            for (int kc = 0; kc < 4; kc++)
                acc2[g8] = __builtin_amdgcn_mfma_f32_16x16x32_bf16(
                    a3[kc],
                    *reinterpret_cast<const bf16x8*>(&wbuf[(((kc << 2) + lg) * 128 + g8 * 16 + lr) << 3]),
                    acc2[g8], 0, 0, 0);
    }
#pragma unroll
    for (int g8 = 0; g8 < 8; g8++) {
        const float bias = b2[g8 * 16 + lr];
#pragma unroll
        for (int j = 0; j < 4; j++)
            out[(size_t)(rb + m0 + 4 * lg + j) * HH + g8 * 16 + lr] = hv[g8][j] + acc2[g8][j] + bias;
    }
}

extern "C" void kernel_launch(void* const* d_in, const int* in_sizes, int n_in,
                              void* d_out, int out_size, void* d_ws, size_t ws_size,
                              hipStream_t stream) {
    const float* x = (const float*)d_in[0];
    const int* erow = (const int*)d_in[1];
    const int* ecol = (const int*)d_in[2];
    const float* ln1g = (const float*)d_in[3];
    const float* ln1b = (const float*)d_in[4];
    const float* wq = (const float*)d_in[5];
    const float* bq = (const float*)d_in[6];
    const float* wk = (const float*)d_in[7];
    const float* bk = (const float*)d_in[8];
    const float* wv = (const float*)d_in[9];
    const float* bv = (const float*)d_in[10];
    const float* wo = (const float*)d_in[11];
    const float* bo = (const float*)d_in[12];
    const float* ln2g = (const float*)d_in[13];
    const float* ln2b = (const float*)d_in[14];
    const float* w1 = (const float*)d_in[15];
    const float* b1 = (const float*)d_in[16];
    const float* w2 = (const float*)d_in[17];
    const float* b2 = (const float*)d_in[18];
    float* out = (float*)d_out;

    unsigned short* qb = (unsigned short*)d_ws;                        // NN*128 ushort (16 MB)
    unsigned char* kv8 = (unsigned char*)(qb + (size_t)NN * HH);       // NN*256 bytes (16 MB)
    unsigned short* wpack = (unsigned short*)(kv8 + (size_t)NN * 256); // 131072 ushorts (256 KB)
    int* offs = (int*)(wpack + 131072);                                // NN+1 ints
    int* csr_col = offs + NN + 1;                                      // NE ints (4 MB)
    int* gcur = csr_col + NE;                                          // NB ints
    unsigned long long* pairs = (unsigned long long*)(gcur + NB + 2);  // NB*BCAP (12 MB)

    hipMemsetAsync(gcur, 0, NB * sizeof(int), stream);
    k_front<<<768, 256, 0, stream>>>(wq, wk, wv, wo, w1, w2, wpack, erow, ecol, gcur, pairs);
    k_mid<<<768, 256, 0, stream>>>(x, ln1g, ln1b, wpack, bq, bk, bv, qb, kv8,
                                   pairs, gcur, offs, csr_col);
    k_at<<<NN / 64, 256, 0, stream>>>(qb, kv8, offs, csr_col,
                                      wpack + 49152, bo, x, ln2g, ln2b,
                                      wpack + 65536, b1, wpack + 98304, b2, out);
}